// Round 16
// baseline (2554.352 us; speedup 1.0000x reference)
//
#include <hip/hip_runtime.h>
#include <hip/hip_bf16.h>

typedef _Float16 f16x8 __attribute__((ext_vector_type(8)));
typedef _Float16 f16x4 __attribute__((ext_vector_type(4)));
typedef float f32x4 __attribute__((ext_vector_type(4)));
typedef unsigned short us8 __attribute__((ext_vector_type(8)));
typedef unsigned short us4 __attribute__((ext_vector_type(4)));

#define N_ 2048
#define B_ 16
#define T_ 12
#define DH 64
#define CC 65      // DIN + DOUT
#define NC 1040    // B_*CC
#define NCP 1088   // padded col count (17*64)
#define KI 195     // K*CC
#define NKC 25     // kk-chunks of 8 (200 slots, kk>=195 zero)
#define EDIM 10
#define ASCALE 1024.0f
#define AINV (1.0f / 1024.0f)

// ---------------- A = softmax(relu(E E^T)) rowwise, f16 scaled by 1024 ----------------
__global__ __launch_bounds__(256) void k_compA(const float* __restrict__ emb,
                                               _Float16* __restrict__ A) {
    int n = blockIdx.x, tid = threadIdx.x;
    float en[EDIM];
#pragma unroll
    for (int d = 0; d < EDIM; ++d) en[d] = emb[n * EDIM + d];
    float v[8], mx = -1e30f;
#pragma unroll
    for (int j = 0; j < 8; ++j) {
        int m = tid + j * 256;
        float acc = 0.f;
#pragma unroll
        for (int d = 0; d < EDIM; ++d) acc = fmaf(en[d], emb[m * EDIM + d], acc);
        acc = fmaxf(acc, 0.f);
        v[j] = acc; mx = fmaxf(mx, acc);
    }
    __shared__ float red[256];
    red[tid] = mx; __syncthreads();
    for (int s = 128; s > 0; s >>= 1) { if (tid < s) red[tid] = fmaxf(red[tid], red[tid + s]); __syncthreads(); }
    mx = red[0]; __syncthreads();
    float se = 0.f;
#pragma unroll
    for (int j = 0; j < 8; ++j) { v[j] = __expf(v[j] - mx); se += v[j]; }
    red[tid] = se; __syncthreads();
    for (int s = 128; s > 0; s >>= 1) { if (tid < s) red[tid] += red[tid + s]; __syncthreads(); }
    float inv = ASCALE / red[0];
#pragma unroll
    for (int j = 0; j < 8; ++j) A[(long)n * N_ + tid + j * 256] = (_Float16)(v[j] * inv);
}

// ---------------- transpose A -> AT (64x64 LDS tiles) ----------------
__global__ __launch_bounds__(256) void k_transp(const _Float16* __restrict__ A,
                                                _Float16* __restrict__ AT) {
    __shared__ _Float16 tile[64][72];
    int bx = blockIdx.x, by = blockIdx.y;
    int tid = threadIdx.x;
    int r8 = tid >> 3, c8 = (tid & 7) * 8;
#pragma unroll
    for (int p = 0; p < 2; ++p) {
        int r = p * 32 + r8;
        *(f16x8*)&tile[r][c8] = *(const f16x8*)(A + (long)(by * 64 + r) * N_ + bx * 64 + c8);
    }
    __syncthreads();
#pragma unroll
    for (int p = 0; p < 2; ++p) {
        int r = p * 32 + r8;
        f16x8 v;
#pragma unroll
        for (int q = 0; q < 8; ++q) v[q] = tile[c8 + q][r];
        *(f16x8*)(AT + (long)(bx * 64 + r) * N_ + by * 64 + c8) = v;
    }
}

// ---------------- per-node GRU weights, MFMA-fragment order, o-major ----------------
__global__ __launch_bounds__(256) void k_build(const float* __restrict__ emb,
        const float* __restrict__ gw, const float* __restrict__ gb,
        const float* __restrict__ uw, const float* __restrict__ ub,
        _Float16* __restrict__ GwT, float* __restrict__ Gb,
        _Float16* __restrict__ UwT, float* __restrict__ Ub) {
    int bid = blockIdx.x;
    int tid = threadIdx.x;
    if (bid < 800) {
        __shared__ float embs[128][EDIM];
        int isupd = bid >= 400;
        int b2 = isupd ? bid - 400 : bid;
        int kkc = b2 >> 4, nch = b2 & 15;
        for (int idx = tid; idx < 128 * EDIM; idx += 256)
            embs[idx / EDIM][idx % EDIM] = emb[(nch * 128 + idx / EDIM) * EDIM + idx % EDIM];
        __syncthreads();
        if (!isupd) {
            int o = tid >> 1, jh = (tid & 1) * 4;
            float w[EDIM][4];
#pragma unroll
            for (int d = 0; d < EDIM; ++d)
#pragma unroll
                for (int jj = 0; jj < 4; ++jj) {
                    int kk = kkc * 8 + jh + jj;
                    w[d][jj] = (kk < KI) ? gw[(long)d * (KI * 128) + (long)kk * 128 + o] : 0.f;
                }
            for (int i = 0; i < 128; ++i) {
                int n = nch * 128 + i;
                float a0 = 0.f, a1 = 0.f, a2 = 0.f, a3 = 0.f;
#pragma unroll
                for (int d = 0; d < EDIM; ++d) {
                    float ed = embs[i][d];
                    a0 = fmaf(ed, w[d][0], a0); a1 = fmaf(ed, w[d][1], a1);
                    a2 = fmaf(ed, w[d][2], a2); a3 = fmaf(ed, w[d][3], a3);
                }
                us4 pk;
                pk[0] = __builtin_bit_cast(unsigned short, (_Float16)a0);
                pk[1] = __builtin_bit_cast(unsigned short, (_Float16)a1);
                pk[2] = __builtin_bit_cast(unsigned short, (_Float16)a2);
                pk[3] = __builtin_bit_cast(unsigned short, (_Float16)a3);
                *(us4*)(GwT + ((long)n * NKC + kkc) * 1024 + o * 8 + jh) = pk;
            }
        } else {
            int sub = tid >> 7, o = (tid >> 1) & 63, jh = (tid & 1) * 4;
            float w[EDIM][4];
#pragma unroll
            for (int d = 0; d < EDIM; ++d)
#pragma unroll
                for (int jj = 0; jj < 4; ++jj) {
                    int kk = kkc * 8 + jh + jj;
                    w[d][jj] = (kk < KI) ? uw[(long)d * (KI * 64) + (long)kk * 64 + o] : 0.f;
                }
            for (int i = 0; i < 64; ++i) {
                int il = i * 2 + sub;
                int n = nch * 128 + il;
                float a0 = 0.f, a1 = 0.f, a2 = 0.f, a3 = 0.f;
#pragma unroll
                for (int d = 0; d < EDIM; ++d) {
                    float ed = embs[il][d];
                    a0 = fmaf(ed, w[d][0], a0); a1 = fmaf(ed, w[d][1], a1);
                    a2 = fmaf(ed, w[d][2], a2); a3 = fmaf(ed, w[d][3], a3);
                }
                us4 pk;
                pk[0] = __builtin_bit_cast(unsigned short, (_Float16)a0);
                pk[1] = __builtin_bit_cast(unsigned short, (_Float16)a1);
                pk[2] = __builtin_bit_cast(unsigned short, (_Float16)a2);
                pk[3] = __builtin_bit_cast(unsigned short, (_Float16)a3);
                *(us4*)(UwT + ((long)n * NKC + kkc) * 512 + o * 8 + jh) = pk;
            }
        }
    } else {
        int bb = bid - 800;
        const int CHUNK = (2048 * 128 + 2048 * 64) / 16;   // 24576
        for (int idx = bb * CHUNK + tid; idx < (bb + 1) * CHUNK; idx += 256) {
            if (idx < 2048 * 128) {
                int n = idx >> 7, o = idx & 127;
                float a = 0.f;
#pragma unroll
                for (int d = 0; d < EDIM; ++d) a = fmaf(emb[n * EDIM + d], gb[d * 128 + o], a);
                Gb[idx] = a;
            } else {
                int i2 = idx - 2048 * 128;
                int n = i2 >> 6, o = i2 & 63;
                float a = 0.f;
#pragma unroll
                for (int d = 0; d < EDIM; ++d) a = fmaf(emb[n * EDIM + d], ub[d * 64 + o], a);
                Ub[i2] = a;
            }
        }
    }
}

// ---------------- tiny: f16 copies of attn weights ----------------
__global__ __launch_bounds__(256) void k_wcvt(const float* __restrict__ Wi,
        const float* __restrict__ Wo, _Float16* __restrict__ Wi16,
        _Float16* __restrict__ Wo16) {
    int idx = blockIdx.x * 256 + threadIdx.x;
    if (idx < 192 * 64) Wi16[idx] = (_Float16)Wi[idx];
    if (idx < 64 * 64) Wo16[idx] = (_Float16)Wo[idx];
}

// ---------------- tiny: XT x-row for t=0 ----------------
__global__ __launch_bounds__(256) void k_initx(const float* __restrict__ src,
        _Float16* __restrict__ XT) {
    int idx = blockIdx.x * 256 + threadIdx.x;   // b*2048+n
    int b = idx >> 11, n = idx & 2047;
    XT[((long)b * CC) * N_ + n] = (_Float16)src[((long)b * T_) * N_ + n];
}

// ---------------- GEMM core (c-major epilogue, for A2 precompute) ----------------
__device__ __forceinline__ f16x8 lds_frag(const _Float16* base, int r, int kb) {
    int byt = r * 128 + ((kb * 2) ^ ((r & 7) << 4));
    return *(const f16x8*)((const char*)base + byt);
}

__global__ __launch_bounds__(256) void k_gemm(const _Float16* __restrict__ Aop,
        const _Float16* __restrict__ BT, _Float16* __restrict__ DT) {
    __shared__ __align__(16) _Float16 As[3 * 4096];
    __shared__ __align__(16) _Float16 Bs[3 * 4096];
    int bm = blockIdx.x, bc = blockIdx.y, tid = threadIdx.x;
    int wid = tid >> 6, lane = tid & 63;
    int row_g = bm * 64, col_g = bc * 64;
    int r0 = (wid & 1) * 32, c0 = (wid >> 1) * 32;
    int lr8 = lane >> 3;
    int lsw = 8 * ((lane & 7) ^ lr8);
    long aoff[2], boff[2];
    int ldo[2];
#pragma unroll
    for (int i = 0; i < 2; ++i) {
        aoff[i] = (long)(row_g + wid * 16 + i * 8 + lr8) * N_ + lsw;
        boff[i] = (long)(col_g + wid * 16 + i * 8 + lr8) * N_ + lsw;
        ldo[i] = (wid * 16 + i * 8) * 64;
    }
    auto stage = [&](int buf, int kt) {
        int k0 = kt * 64;
#pragma unroll
        for (int i = 0; i < 2; ++i)
            __builtin_amdgcn_global_load_lds(
                (const __attribute__((address_space(1))) void*)(Aop + aoff[i] + k0),
                (__attribute__((address_space(3))) void*)&As[buf * 4096 + ldo[i]], 16, 0, 0);
#pragma unroll
        for (int i = 0; i < 2; ++i)
            __builtin_amdgcn_global_load_lds(
                (const __attribute__((address_space(1))) void*)(BT + boff[i] + k0),
                (__attribute__((address_space(3))) void*)&Bs[buf * 4096 + ldo[i]], 16, 0, 0);
    };
    f32x4 acc[2][2] = {};
    const int NT = 32;
    stage(0, 0); stage(1, 1);
    int buf = 0;
    for (int kt = 0; kt < NT; ++kt) {
        if (kt + 2 < NT) { stage((buf + 2) % 3, kt + 2); asm volatile("s_waitcnt vmcnt(8)" ::: "memory"); }
        else if (kt + 1 < NT) { asm volatile("s_waitcnt vmcnt(4)" ::: "memory"); }
        else { asm volatile("s_waitcnt vmcnt(0)" ::: "memory"); }
        __builtin_amdgcn_s_barrier();
        const _Float16* Ab = As + buf * 4096;
        const _Float16* Bb = Bs + buf * 4096;
#pragma unroll
        for (int kk = 0; kk < 64; kk += 32) {
            int kb = kk + (lane >> 4) * 8;
            f16x8 af0 = lds_frag(Ab, r0 + (lane & 15), kb);
            f16x8 af1 = lds_frag(Ab, r0 + 16 + (lane & 15), kb);
            f16x8 bf0 = lds_frag(Bb, c0 + (lane & 15), kb);
            f16x8 bf1 = lds_frag(Bb, c0 + 16 + (lane & 15), kb);
            acc[0][0] = __builtin_amdgcn_mfma_f32_16x16x32_f16(af0, bf0, acc[0][0], 0, 0, 0);
            acc[0][1] = __builtin_amdgcn_mfma_f32_16x16x32_f16(af0, bf1, acc[0][1], 0, 0, 0);
            acc[1][0] = __builtin_amdgcn_mfma_f32_16x16x32_f16(af1, bf0, acc[1][0], 0, 0, 0);
            acc[1][1] = __builtin_amdgcn_mfma_f32_16x16x32_f16(af1, bf1, acc[1][1], 0, 0, 0);
        }
        asm volatile("s_waitcnt lgkmcnt(0)" ::: "memory");
        __builtin_amdgcn_s_barrier();
        buf = (buf + 1) % 3;
    }
#pragma unroll
    for (int rt = 0; rt < 2; ++rt)
#pragma unroll
        for (int ct = 0; ct < 2; ++ct) {
            int cg = col_g + c0 + ct * 16 + (lane & 15);
            int ng = row_g + r0 + rt * 16 + ((lane >> 4) << 2);
            us4 pk;
#pragma unroll
            for (int q = 0; q < 4; ++q) pk[q] = __builtin_bit_cast(unsigned short, (_Float16)(acc[rt][ct][q] * AINV));
            *(us4*)(DT + (long)cg * N_ + ng) = pk;
        }
}

// fused dual dispatch (z: 0=A->Y1, 1=A2->Y2), NODE-MAJOR epilogue: Y[n*NCP + c]
__global__ __launch_bounds__(256) void k_gemm2(const _Float16* __restrict__ A,
        const _Float16* __restrict__ A2, const _Float16* __restrict__ BT,
        _Float16* __restrict__ Y1, _Float16* __restrict__ Y2) {
    __shared__ __align__(16) _Float16 As[3 * 4096];
    __shared__ __align__(16) _Float16 Bs[3 * 4096];
    const _Float16* Aop = blockIdx.z ? A2 : A;
    _Float16* Yn = blockIdx.z ? Y2 : Y1;
    int bm = blockIdx.x, bc = blockIdx.y, tid = threadIdx.x;
    int wid = tid >> 6, lane = tid & 63;
    int row_g = bm * 64, col_g = bc * 64;
    int r0 = (wid & 1) * 32, c0 = (wid >> 1) * 32;
    int lr8 = lane >> 3;
    int lsw = 8 * ((lane & 7) ^ lr8);
    long aoff[2], boff[2];
    int ldo[2];
#pragma unroll
    for (int i = 0; i < 2; ++i) {
        aoff[i] = (long)(row_g + wid * 16 + i * 8 + lr8) * N_ + lsw;
        boff[i] = (long)(col_g + wid * 16 + i * 8 + lr8) * N_ + lsw;
        ldo[i] = (wid * 16 + i * 8) * 64;
    }
    auto stage = [&](int buf, int kt) {
        int k0 = kt * 64;
#pragma unroll
        for (int i = 0; i < 2; ++i)
            __builtin_amdgcn_global_load_lds(
                (const __attribute__((address_space(1))) void*)(Aop + aoff[i] + k0),
                (__attribute__((address_space(3))) void*)&As[buf * 4096 + ldo[i]], 16, 0, 0);
#pragma unroll
        for (int i = 0; i < 2; ++i)
            __builtin_amdgcn_global_load_lds(
                (const __attribute__((address_space(1))) void*)(BT + boff[i] + k0),
                (__attribute__((address_space(3))) void*)&Bs[buf * 4096 + ldo[i]], 16, 0, 0);
    };
    f32x4 acc[2][2] = {};
    const int NT = 32;
    stage(0, 0); stage(1, 1);
    int buf = 0;
    for (int kt = 0; kt < NT; ++kt) {
        if (kt + 2 < NT) { stage((buf + 2) % 3, kt + 2); asm volatile("s_waitcnt vmcnt(8)" ::: "memory"); }
        else if (kt + 1 < NT) { asm volatile("s_waitcnt vmcnt(4)" ::: "memory"); }
        else { asm volatile("s_waitcnt vmcnt(0)" ::: "memory"); }
        __builtin_amdgcn_s_barrier();
        const _Float16* Ab = As + buf * 4096;
        const _Float16* Bb = Bs + buf * 4096;
#pragma unroll
        for (int kk = 0; kk < 64; kk += 32) {
            int kb = kk + (lane >> 4) * 8;
            f16x8 af0 = lds_frag(Ab, r0 + (lane & 15), kb);
            f16x8 af1 = lds_frag(Ab, r0 + 16 + (lane & 15), kb);
            f16x8 bf0 = lds_frag(Bb, c0 + (lane & 15), kb);
            f16x8 bf1 = lds_frag(Bb, c0 + 16 + (lane & 15), kb);
            acc[0][0] = __builtin_amdgcn_mfma_f32_16x16x32_f16(af0, bf0, acc[0][0], 0, 0, 0);
            acc[0][1] = __builtin_amdgcn_mfma_f32_16x16x32_f16(af0, bf1, acc[0][1], 0, 0, 0);
            acc[1][0] = __builtin_amdgcn_mfma_f32_16x16x32_f16(af1, bf0, acc[1][0], 0, 0, 0);
            acc[1][1] = __builtin_amdgcn_mfma_f32_16x16x32_f16(af1, bf1, acc[1][1], 0, 0, 0);
        }
        asm volatile("s_waitcnt lgkmcnt(0)" ::: "memory");
        __builtin_amdgcn_s_barrier();
        buf = (buf + 1) % 3;
    }
#pragma unroll
    for (int rt = 0; rt < 2; ++rt)
#pragma unroll
        for (int ct = 0; ct < 2; ++ct) {
            int cg = col_g + c0 + ct * 16 + (lane & 15);
            int ng = row_g + r0 + rt * 16 + ((lane >> 4) << 2);
#pragma unroll
            for (int q = 0; q < 4; ++q)
                Yn[(long)(ng + q) * NCP + cg] = (_Float16)(acc[rt][ct][q] * AINV);
        }
}

// ---------------- gate apply: TWO nodes per block, cross-node weight-load overlap ----------------
__global__ __launch_bounds__(256) void k_apply_gate(const float* __restrict__ src,
        const _Float16* __restrict__ h, const _Float16* __restrict__ Y1,
        const _Float16* __restrict__ Y2, const _Float16* __restrict__ GwT,
        const float* __restrict__ Gb, int t,
        _Float16* __restrict__ z, _Float16* __restrict__ r, _Float16* __restrict__ XT,
        const _Float16* __restrict__ zp) {
    int tid = threadIdx.x, wid = tid >> 6, lane = tid & 63;
    int nb = blockIdx.x * 2;
    __shared__ __align__(16) _Float16 xg[2][16][232];
    int cl = lane & 15, q = lane >> 4, k8 = q * 8;
    int o0 = wid * 32 + cl, o1 = o0 + 16;
    // prefetch node-0 weights
    const _Float16* Wp0 = GwT + (long)nb * (NKC * 128 * 8);
    f16x8 bfr0[7], bfr1[7];
#pragma unroll
    for (int ks = 0; ks < 7; ++ks) {
        bool valid = (ks * 4 + q) < NKC;
        bfr0[ks] = *(const f16x8*)(valid ? Wp0 + (long)((ks * 4 + q) * 128 + o0) * 8 : zp + cl * 8);
        bfr1[ks] = *(const f16x8*)(valid ? Wp0 + (long)((ks * 4 + q) * 128 + o1) * 8 : zp + cl * 8 + 128);
    }
    _Float16* xf = &xg[0][0][0];
    for (int idx = tid; idx < 2 * 16 * 232; idx += 256) xf[idx] = (_Float16)0.f;
    __syncthreads();
    // stage xg for both nodes (coalesced node-major Y reads)
    for (int idx = tid; idx < 2 * 16 * KI; idx += 256) {
        int nn = idx / (16 * KI);
        int rem = idx - nn * (16 * KI);
        int b = rem / KI, kk = rem - b * KI;
        int k = kk / CC, i = kk % CC;
        int n = nb + nn;
        int c = b * CC + i;
        float ih = (i == 0) ? src[((long)b * T_ + t) * N_ + n]
                            : (float)h[((long)b * N_ + n) * DH + (i - 1)];
        float val;
        if (k == 0)      val = ih;
        else if (k == 1) val = (float)Y1[(long)n * NCP + c];
        else             val = 2.f * (float)Y2[(long)n * NCP + c] - ih;
        xg[nn][b][kk] = (_Float16)val;
    }
    __syncthreads();
#pragma unroll
    for (int nn = 0; nn < 2; ++nn) {
        int n = nb + nn;
        f32x4 acc0 = {}, acc1 = {};
#pragma unroll
        for (int ks = 0; ks < 7; ++ks) {
            f16x8 af = *(const f16x8*)&xg[nn][cl][ks * 32 + k8];
            acc0 = __builtin_amdgcn_mfma_f32_16x16x32_f16(af, bfr0[ks], acc0, 0, 0, 0);
            acc1 = __builtin_amdgcn_mfma_f32_16x16x32_f16(af, bfr1[ks], acc1, 0, 0, 0);
        }
        if (nn == 0) {
            // issue node-1 weight loads; they overlap the epilogue below
            const _Float16* Wp1 = GwT + (long)(nb + 1) * (NKC * 128 * 8);
#pragma unroll
            for (int ks = 0; ks < 7; ++ks) {
                bool valid = (ks * 4 + q) < NKC;
                bfr0[ks] = *(const f16x8*)(valid ? Wp1 + (long)((ks * 4 + q) * 128 + o0) * 8 : zp + cl * 8);
                bfr1[ks] = *(const f16x8*)(valid ? Wp1 + (long)((ks * 4 + q) * 128 + o1) * 8 : zp + cl * 8 + 128);
            }
        }
#pragma unroll
        for (int tl = 0; tl < 2; ++tl) {
            f32x4 acc = tl ? acc1 : acc0;
            int o = wid * 32 + tl * 16 + cl;
            float bias = Gb[(long)n * 128 + o];
#pragma unroll
            for (int qq = 0; qq < 4; ++qq) {
                int b = q * 4 + qq;
                float sv = 1.f / (1.f + __expf(-(acc[qq] + bias)));
                long base = ((long)b * N_ + n) * DH;
                if (o < 64) {
                    z[base + o] = (_Float16)sv;
                    XT[(long)(b * CC + 1 + o) * N_ + n] = (_Float16)(sv * (float)h[base + o]);
                } else {
                    r[base + (o - 64)] = (_Float16)sv;
                }
            }
        }
    }
}

// ---------------- update apply: TWO nodes per block, cross-node weight-load overlap ----------------
__global__ __launch_bounds__(256) void k_apply_update(const float* __restrict__ src,
        _Float16* __restrict__ h, const _Float16* __restrict__ Y1,
        const _Float16* __restrict__ Y2, const _Float16* __restrict__ UwT,
        const float* __restrict__ Ub, const _Float16* __restrict__ z,
        const _Float16* __restrict__ rb, int t, _Float16* __restrict__ states,
        _Float16* __restrict__ XT, const _Float16* __restrict__ zp) {
    int tid = threadIdx.x, wid = tid >> 6, lane = tid & 63;
    int nb = blockIdx.x * 2;
    __shared__ __align__(16) _Float16 xg[2][16][232];
    int cl = lane & 15, q = lane >> 4, k8 = q * 8;
    int o0 = wid * 16 + cl;
    const _Float16* Wp0 = UwT + (long)nb * (NKC * 64 * 8);
    f16x8 bfr[7];
#pragma unroll
    for (int ks = 0; ks < 7; ++ks) {
        bool valid = (ks * 4 + q) < NKC;
        bfr[ks] = *(const f16x8*)(valid ? Wp0 + (long)((ks * 4 + q) * 64 + o0) * 8 : zp + cl * 8);
    }
    _Float16* xf = &xg[0][0][0];
    for (int idx = tid; idx < 2 * 16 * 232; idx += 256) xf[idx] = (_Float16)0.f;
    __syncthreads();
    for (int idx = tid; idx < 2 * 16 * KI; idx += 256) {
        int nn = idx / (16 * KI);
        int rem = idx - nn * (16 * KI);
        int b = rem / KI, kk = rem - b * KI;
        int k = kk / CC, i = kk % CC;
        int n = nb + nn;
        int c = b * CC + i;
        float ih;
        if (i == 0) ih = src[((long)b * T_ + t) * N_ + n];
        else {
            long base = ((long)b * N_ + n) * DH + (i - 1);
            ih = (float)h[base] * (float)z[base];
        }
        float val;
        if (k == 0)      val = ih;
        else if (k == 1) val = (float)Y1[(long)n * NCP + c];
        else             val = 2.f * (float)Y2[(long)n * NCP + c] - ih;
        xg[nn][b][kk] = (_Float16)val;
    }
    __syncthreads();
#pragma unroll
    for (int nn = 0; nn < 2; ++nn) {
        int n = nb + nn;
        f32x4 acc0 = {};
#pragma unroll
        for (int ks = 0; ks < 7; ++ks) {
            f16x8 af = *(const f16x8*)&xg[nn][cl][ks * 32 + k8];
            acc0 = __builtin_amdgcn_mfma_f32_16x16x32_f16(af, bfr[ks], acc0, 0, 0, 0);
        }
        if (nn == 0) {
            const _Float16* Wp1 = UwT + (long)(nb + 1) * (NKC * 64 * 8);
#pragma unroll
            for (int ks = 0; ks < 7; ++ks) {
                bool valid = (ks * 4 + q) < NKC;
                bfr[ks] = *(const f16x8*)(valid ? Wp1 + (long)((ks * 4 + q) * 64 + o0) * 8 : zp + cl * 8);
            }
        }
        int o = o0;
        float bias = Ub[(long)n * 64 + o];
#pragma unroll
        for (int qq = 0; qq < 4; ++qq) {
            int b = q * 4 + qq;
            long base = ((long)b * N_ + n) * DH + o;
            float hc = tanhf(acc0[qq] + bias);
            float rv = (float)rb[base], hv = (float)h[base];
            float hn = rv * hv + (1.f - rv) * hc;
            _Float16 hn16 = (_Float16)hn;
            h[base] = hn16;
            states[(((long)b * T_ + t) * N_ + n) * DH + o] = hn16;
            XT[(long)(b * CC + 1 + o) * N_ + n] = hn16;
            if (o == 0 && t + 1 < T_)
                XT[(long)(b * CC) * N_ + n] = (_Float16)src[((long)b * T_ + t + 1) * N_ + n];
        }
    }
}

// ---------------- qkv projection (MFMA): KV for all t, Q at t=11 ----------------
__global__ __launch_bounds__(256) void k_qkv(const _Float16* __restrict__ st,
        const _Float16* __restrict__ Wi16, const float* __restrict__ bi,
        _Float16* __restrict__ KV, _Float16* __restrict__ Q) {
    int bt = blockIdx.x;
    int nck = blockIdx.y;
    int b = bt / 12, t = bt % 12;
    int tid = threadIdx.x, wid = tid >> 6, lane = tid & 63;
    __shared__ float pe[64];
    __shared__ __align__(16) _Float16 Xs[128][72];
    if (tid < 64) {
        int e = tid;
        float div = __powf(10000.f, -(float)(e & ~1) / 64.f);
        float ang = (float)t * div;
        pe[e] = (e & 1) ? __cosf(ang) : __sinf(ang);
    }
    __syncthreads();
    const _Float16* srcp = st + ((long)(b * T_ + t) * N_ + nck * 128) * DH;
#pragma unroll
    for (int u = 0; u < 4; ++u) {
        int idx = u * 256 + tid;
        int rr = idx >> 3, e0 = (idx & 7) * 8;
        f16x8 v = *(const f16x8*)(srcp + rr * DH + e0);
        f16x8 ov;
#pragma unroll
        for (int q = 0; q < 8; ++q) ov[q] = (_Float16)((float)v[q] + pe[e0 + q]);
        *(f16x8*)&Xs[rr][e0] = ov;
    }
    __syncthreads();
    int cl = lane & 15, ks8 = (lane >> 4) * 8;
    f16x8 bfrag[3][2];
    float bias[3];
#pragma unroll
    for (int j = 0; j < 3; ++j) {
        int c = (wid * 3 + j) * 16 + cl;
#pragma unroll
        for (int ks = 0; ks < 2; ++ks)
            bfrag[j][ks] = *(const f16x8*)(Wi16 + c * 64 + ks * 32 + ks8);
        bias[j] = bi[c];
    }
    f32x4 acc[8][3] = {};
#pragma unroll
    for (int rt = 0; rt < 8; ++rt) {
#pragma unroll
        for (int ks = 0; ks < 2; ++ks) {
            f16x8 af = *(const f16x8*)&Xs[rt * 16 + cl][ks * 32 + ks8];
#pragma unroll
            for (int j = 0; j < 3; ++j)
                acc[rt][j] = __builtin_amdgcn_mfma_f32_16x16x32_f16(af, bfrag[j][ks], acc[rt][j], 0, 0, 0);
        }
    }
    int rowq = (lane >> 4) * 4;
#pragma unroll
    for (int rt = 0; rt < 8; ++rt)
#pragma unroll
        for (int j = 0; j < 3; ++j) {
            int c = (wid * 3 + j) * 16 + cl;
#pragma unroll
            for (int q = 0; q < 4; ++q) {
                int n = nck * 128 + rt * 16 + rowq + q;
                float val = acc[rt][j][q] + bias[j];
                if (c >= 64)
                    KV[(((long)b * N_ + n) * T_ + t) * 128 + (c - 64)] = (_Float16)val;
                else if (t == 11)
                    Q[((long)b * N_ + n) * 64 + c] = (_Float16)val;
            }
        }
}

// ---------------- attention + out-proj: 16 pairs/block, 16 threads/pair ----------------
__global__ __launch_bounds__(256) void k_attn2(const _Float16* __restrict__ KV,
        const _Float16* __restrict__ Q, const _Float16* __restrict__ Wo16,
        const float* __restrict__ bo, float* __restrict__ o1) {
    __shared__ _Float16 kvs[16 * 1544];
    __shared__ float qs[16][64];
    __shared__ float Wos[64][64];
    __shared__ float outb[16][64];
    __shared__ float bos[64];
    int tid = threadIdx.x;
    long pair0 = (long)blockIdx.x * 16;
#pragma unroll
    for (int u = 0; u < 12; ++u) {
        int idx = u * 256 + tid;
        int p = idx / 192, off8 = (idx % 192) * 8;
        *(f16x8*)&kvs[p * 1544 + off8] = *(const f16x8*)(KV + (pair0 + p) * 1536 + off8);
    }
    if (tid < 64) bos[tid] = bo[tid];
    for (int idx = tid; idx < 1024; idx += 256) {
        int p = idx >> 6, j = idx & 63;
        qs[p][j] = (float)Q[(pair0 + p) * 64 + j];
    }
    for (int idx = tid; idx < 4096; idx += 256) {
        int c = idx >> 6, j = idx & 63;
        Wos[c][j] = (float)Wo16[j * 64 + c];
    }
    __syncthreads();
    int p = tid >> 4, i = tid & 15;
    int h = i >> 2, sg = i & 3;
    const _Float16* kvp = &kvs[p * 1544];
    float att3[3], mx = -1e30f;
#pragma unroll
    for (int j = 0; j < 3; ++j) {
        int s = sg + 4 * j;
        float sc = 0.f;
#pragma unroll
        for (int d = 0; d < 16; ++d)
            sc = fmaf(qs[p][h * 16 + d], (float)kvp[s * 128 + h * 16 + d], sc);
        att3[j] = sc * 0.25f;
        mx = fmaxf(mx, att3[j]);
    }
    mx = fmaxf(mx, __shfl_xor(mx, 1));
    mx = fmaxf(mx, __shfl_xor(mx, 2));
    float se = 0.f;
#pragma unroll
    for (int j = 0; j < 3; ++j) { att3[j] = __expf(att3[j] - mx); se += att3[j]; }
    se += __shfl_xor(se, 1);
    se += __shfl_xor(se, 2);
    float inv = 1.f / se;
#pragma unroll
    for (int j = 0; j < 3; ++j) att3[j] *= inv;
    int c0 = i * 4;
    float out4[4] = {0.f, 0.f, 0.f, 0.f};
#pragma unroll
    for (int m = 0; m < 4; ++m) {
        float a0 = __shfl_xor(att3[0], m);
        float a1 = __shfl_xor(att3[1], m);
        float a2 = __shfl_xor(att3[2], m);
        int sb = sg ^ m;
        float aj[3] = {a0, a1, a2};
#pragma unroll
        for (int j = 0; j < 3; ++j) {
            int s = sb + 4 * j;
            f16x4 vv = *(const f16x4*)&kvp[s * 128 + 64 + c0];
#pragma unroll
            for (int q = 0; q < 4; ++q) out4[q] = fmaf(aj[j], (float)vv[q], out4[q]);
        }
    }
    *(float4*)&outb[p][c0] = *(float4*)out4;
    __syncthreads();
    float res[4];
#pragma unroll
    for (int q = 0; q < 4; ++q) res[q] = bos[c0 + q];
    for (int c = 0; c < 64; ++c) {
        float oc = outb[p][c];
        float4 wv = *(const float4*)&Wos[c][c0];
        res[0] = fmaf(oc, wv.x, res[0]);
        res[1] = fmaf(oc, wv.y, res[1]);
        res[2] = fmaf(oc, wv.z, res[2]);
        res[3] = fmaf(oc, wv.w, res[3]);
    }
    *(float4*)&o1[(pair0 + p) * 64 + c0] = make_float4(res[0], res[1], res[2], res[3]);
}

// ---------------- output head ----------------
__global__ __launch_bounds__(256) void k_final(const float* __restrict__ o1,
        const _Float16* __restrict__ hT, const float* __restrict__ cw,
        const float* __restrict__ convw, const float* __restrict__ convb,
        float* __restrict__ out) {
    __shared__ float Ws[12 * 3 * 64];
    __shared__ float cbs[12];
    int tid = threadIdx.x;
    for (int idx = tid; idx < 12 * 3 * 64; idx += 256) Ws[idx] = convw[idx];
    if (tid < 12) cbs[tid] = convb[tid];
    __syncthreads();
    float c0 = cw[0], c1 = cw[1], c2 = cw[2];
    int g = tid >> 6, j = tid & 63;
    int bn = blockIdx.x * 4 + g;
    int b = bn >> 11, n = bn & 2047;
    float x1 = o1[(long)bn * DH + j];
    float x3 = (float)hT[(long)bn * DH + j];
    float myout = 0.f;
#pragma unroll
    for (int oc = 0; oc < 12; ++oc) {
        float p = x1 * c0 * Ws[(oc * 3 + 0) * 64 + j]
                + x3 * (c1 * Ws[(oc * 3 + 1) * 64 + j] + c2 * Ws[(oc * 3 + 2) * 64 + j]);
        p += __shfl_xor(p, 1); p += __shfl_xor(p, 2); p += __shfl_xor(p, 4);
        p += __shfl_xor(p, 8); p += __shfl_xor(p, 16); p += __shfl_xor(p, 32);
        if (j == oc) myout = p + cbs[oc];
    }
    if (j < 12) out[((long)b * 12 + j) * N_ + n] = myout;
}

extern "C" void kernel_launch(void* const* d_in, const int* in_sizes, int n_in,
                              void* d_out, int out_size, void* d_ws, size_t ws_size,
                              hipStream_t stream) {
    const float* src    = (const float*)d_in[0];
    const float* emb    = (const float*)d_in[2];
    const float* gate_w = (const float*)d_in[3];
    const float* gate_b = (const float*)d_in[4];
    const float* upd_w  = (const float*)d_in[5];
    const float* upd_b  = (const float*)d_in[6];
    const float* a_in_w = (const float*)d_in[7];
    const float* a_in_b = (const float*)d_in[8];
    const float* a_out_w= (const float*)d_in[9];
    const float* a_out_b= (const float*)d_in[10];
    const float* chan_w = (const float*)d_in[11];
    const float* conv_w = (const float*)d_in[12];
    const float* conv_b = (const float*)d_in[13];
    float* out = (float*)d_out;

    char* ws = (char*)d_ws;
    size_t off = 0;
    auto alloc = [&](size_t bytes) { char* p = ws + off; off += (bytes + 255) & ~size_t(255); return p; };
    _Float16* A    = (_Float16*)alloc((size_t)N_ * N_ * 2);
    _Float16* A2   = (_Float16*)alloc((size_t)N_ * N_ * 2);
    _Float16* GwT  = (_Float16*)alloc((size_t)N_ * NKC * 128 * 8 * 2);   // 104.9 MB
    float*  Gb     = (float*) alloc((size_t)N_ * 128 * 4);
    _Float16* UwT  = (_Float16*)alloc((size_t)N_ * NKC * 64 * 8 * 2);    // 52.4 MB
    float*  Ub     = (float*) alloc((size_t)N_ * 64 * 4);
    _Float16* XT   = (_Float16*)alloc((size_t)NCP * N_ * 2);
    _Float16* Y1   = (_Float16*)alloc((size_t)N_ * NCP * 2);   // node-major [n][c]
    _Float16* Y2   = (_Float16*)alloc((size_t)N_ * NCP * 2);   // node-major [n][c]
    _Float16* h    = (_Float16*)alloc((size_t)B_ * N_ * DH * 2);
    _Float16* zbuf = (_Float16*)alloc((size_t)B_ * N_ * DH * 2);
    _Float16* rbuf = (_Float16*)alloc((size_t)B_ * N_ * DH * 2);
    _Float16* stt  = (_Float16*)alloc((size_t)B_ * T_ * N_ * DH * 2);
    _Float16* Wi16 = (_Float16*)alloc(192 * 64 * 2);
    _Float16* Wo16 = (_Float16*)alloc(64 * 64 * 2);
    _Float16* zp   = (_Float16*)alloc(512);
    if (off > ws_size) return;   // ~252 MB total

    // transient/dead-region aliases
    _Float16* AT = stt;                            // 8.4 MB scratch (stt unwritten at setup)
    _Float16* KV = GwT;                            // 100.7 MB into GwT's 104.9 MB
    _Float16* Qb = UwT;                            // 4.2 MB at UwT start
    float*    o1 = (float*)((char*)UwT + (8u << 20)); // 8.4 MB at UwT+8MB

    hipMemsetAsync(h, 0, (size_t)B_ * N_ * DH * 2, stream);
    hipMemsetAsync(XT, 0, (size_t)NCP * N_ * 2, stream);
    hipMemsetAsync(zp, 0, 512, stream);
    k_compA<<<N_, 256, 0, stream>>>(emb, A);
    dim3 tgrid(32, 32);
    k_transp<<<tgrid, 256, 0, stream>>>(A, AT);
    k_gemm<<<tgrid, 256, 0, stream>>>(AT, A, A2);   // A2 = (1024*A^2), Aop=AT BT=A
    k_build<<<816, 256, 0, stream>>>(emb, gate_w, gate_b, upd_w, upd_b, GwT, Gb, UwT, Ub);
    k_wcvt<<<48, 256, 0, stream>>>(a_in_w, a_out_w, Wi16, Wo16);
    k_initx<<<128, 256, 0, stream>>>(src, XT);

    dim3 ggrid(32, 17, 2);
    for (int t = 0; t < T_; ++t) {
        k_gemm2<<<ggrid, 256, 0, stream>>>(A, A2, XT, Y1, Y2);
        k_apply_gate<<<1024, 256, 0, stream>>>(src, h, Y1, Y2, GwT, Gb, t, zbuf, rbuf, XT, zp);
        k_gemm2<<<ggrid, 256, 0, stream>>>(A, A2, XT, Y1, Y2);
        k_apply_update<<<1024, 256, 0, stream>>>(src, h, Y1, Y2, UwT, Ub, zbuf, rbuf, t, stt, XT, zp);
    }
    dim3 qgrid(192, 16);
    k_qkv<<<qgrid, 256, 0, stream>>>(stt, Wi16, a_in_b, KV, Qb);
    k_attn2<<<2048, 256, 0, stream>>>(KV, Qb, Wo16, a_out_b, o1);
    k_final<<<8192, 256, 0, stream>>>(o1, h, chan_w, conv_w, conv_b, out);
}

// Round 17
// 2235.260 us; speedup vs baseline: 1.1428x; 1.1428x over previous
//
#include <hip/hip_runtime.h>
#include <hip/hip_bf16.h>

typedef _Float16 f16x8 __attribute__((ext_vector_type(8)));
typedef _Float16 f16x4 __attribute__((ext_vector_type(4)));
typedef float f32x4 __attribute__((ext_vector_type(4)));
typedef unsigned short us8 __attribute__((ext_vector_type(8)));
typedef unsigned short us4 __attribute__((ext_vector_type(4)));

#define N_ 2048
#define B_ 16
#define T_ 12
#define DH 64
#define CC 65      // DIN + DOUT
#define NC 1040    // B_*CC
#define NCP 1088   // padded col count (17*64)
#define KI 195     // K*CC
#define NKC 25     // kk-chunks of 8 (200 slots, kk>=195 zero)
#define EDIM 10
#define ASCALE 1024.0f
#define AINV (1.0f / 1024.0f)

// ---------------- A = softmax(relu(E E^T)) rowwise, f16 scaled by 1024 ----------------
__global__ __launch_bounds__(256) void k_compA(const float* __restrict__ emb,
                                               _Float16* __restrict__ A) {
    int n = blockIdx.x, tid = threadIdx.x;
    float en[EDIM];
#pragma unroll
    for (int d = 0; d < EDIM; ++d) en[d] = emb[n * EDIM + d];
    float v[8], mx = -1e30f;
#pragma unroll
    for (int j = 0; j < 8; ++j) {
        int m = tid + j * 256;
        float acc = 0.f;
#pragma unroll
        for (int d = 0; d < EDIM; ++d) acc = fmaf(en[d], emb[m * EDIM + d], acc);
        acc = fmaxf(acc, 0.f);
        v[j] = acc; mx = fmaxf(mx, acc);
    }
    __shared__ float red[256];
    red[tid] = mx; __syncthreads();
    for (int s = 128; s > 0; s >>= 1) { if (tid < s) red[tid] = fmaxf(red[tid], red[tid + s]); __syncthreads(); }
    mx = red[0]; __syncthreads();
    float se = 0.f;
#pragma unroll
    for (int j = 0; j < 8; ++j) { v[j] = __expf(v[j] - mx); se += v[j]; }
    red[tid] = se; __syncthreads();
    for (int s = 128; s > 0; s >>= 1) { if (tid < s) red[tid] += red[tid + s]; __syncthreads(); }
    float inv = ASCALE / red[0];
#pragma unroll
    for (int j = 0; j < 8; ++j) A[(long)n * N_ + tid + j * 256] = (_Float16)(v[j] * inv);
}

// ---------------- transpose A -> AT (64x64 LDS tiles) ----------------
__global__ __launch_bounds__(256) void k_transp(const _Float16* __restrict__ A,
                                                _Float16* __restrict__ AT) {
    __shared__ _Float16 tile[64][72];
    int bx = blockIdx.x, by = blockIdx.y;
    int tid = threadIdx.x;
    int r8 = tid >> 3, c8 = (tid & 7) * 8;
#pragma unroll
    for (int p = 0; p < 2; ++p) {
        int r = p * 32 + r8;
        *(f16x8*)&tile[r][c8] = *(const f16x8*)(A + (long)(by * 64 + r) * N_ + bx * 64 + c8);
    }
    __syncthreads();
#pragma unroll
    for (int p = 0; p < 2; ++p) {
        int r = p * 32 + r8;
        f16x8 v;
#pragma unroll
        for (int q = 0; q < 8; ++q) v[q] = tile[c8 + q][r];
        *(f16x8*)(AT + (long)(bx * 64 + r) * N_ + by * 64 + c8) = v;
    }
}

// ---------------- per-node GRU weights, MFMA-fragment order, o-major ----------------
__global__ __launch_bounds__(256) void k_build(const float* __restrict__ emb,
        const float* __restrict__ gw, const float* __restrict__ gb,
        const float* __restrict__ uw, const float* __restrict__ ub,
        _Float16* __restrict__ GwT, float* __restrict__ Gb,
        _Float16* __restrict__ UwT, float* __restrict__ Ub) {
    int bid = blockIdx.x;
    int tid = threadIdx.x;
    if (bid < 800) {
        __shared__ float embs[128][EDIM];
        int isupd = bid >= 400;
        int b2 = isupd ? bid - 400 : bid;
        int kkc = b2 >> 4, nch = b2 & 15;
        for (int idx = tid; idx < 128 * EDIM; idx += 256)
            embs[idx / EDIM][idx % EDIM] = emb[(nch * 128 + idx / EDIM) * EDIM + idx % EDIM];
        __syncthreads();
        if (!isupd) {
            int o = tid >> 1, jh = (tid & 1) * 4;
            float w[EDIM][4];
#pragma unroll
            for (int d = 0; d < EDIM; ++d)
#pragma unroll
                for (int jj = 0; jj < 4; ++jj) {
                    int kk = kkc * 8 + jh + jj;
                    w[d][jj] = (kk < KI) ? gw[(long)d * (KI * 128) + (long)kk * 128 + o] : 0.f;
                }
            for (int i = 0; i < 128; ++i) {
                int n = nch * 128 + i;
                float a0 = 0.f, a1 = 0.f, a2 = 0.f, a3 = 0.f;
#pragma unroll
                for (int d = 0; d < EDIM; ++d) {
                    float ed = embs[i][d];
                    a0 = fmaf(ed, w[d][0], a0); a1 = fmaf(ed, w[d][1], a1);
                    a2 = fmaf(ed, w[d][2], a2); a3 = fmaf(ed, w[d][3], a3);
                }
                us4 pk;
                pk[0] = __builtin_bit_cast(unsigned short, (_Float16)a0);
                pk[1] = __builtin_bit_cast(unsigned short, (_Float16)a1);
                pk[2] = __builtin_bit_cast(unsigned short, (_Float16)a2);
                pk[3] = __builtin_bit_cast(unsigned short, (_Float16)a3);
                *(us4*)(GwT + ((long)n * NKC + kkc) * 1024 + o * 8 + jh) = pk;
            }
        } else {
            int sub = tid >> 7, o = (tid >> 1) & 63, jh = (tid & 1) * 4;
            float w[EDIM][4];
#pragma unroll
            for (int d = 0; d < EDIM; ++d)
#pragma unroll
                for (int jj = 0; jj < 4; ++jj) {
                    int kk = kkc * 8 + jh + jj;
                    w[d][jj] = (kk < KI) ? uw[(long)d * (KI * 64) + (long)kk * 64 + o] : 0.f;
                }
            for (int i = 0; i < 64; ++i) {
                int il = i * 2 + sub;
                int n = nch * 128 + il;
                float a0 = 0.f, a1 = 0.f, a2 = 0.f, a3 = 0.f;
#pragma unroll
                for (int d = 0; d < EDIM; ++d) {
                    float ed = embs[il][d];
                    a0 = fmaf(ed, w[d][0], a0); a1 = fmaf(ed, w[d][1], a1);
                    a2 = fmaf(ed, w[d][2], a2); a3 = fmaf(ed, w[d][3], a3);
                }
                us4 pk;
                pk[0] = __builtin_bit_cast(unsigned short, (_Float16)a0);
                pk[1] = __builtin_bit_cast(unsigned short, (_Float16)a1);
                pk[2] = __builtin_bit_cast(unsigned short, (_Float16)a2);
                pk[3] = __builtin_bit_cast(unsigned short, (_Float16)a3);
                *(us4*)(UwT + ((long)n * NKC + kkc) * 512 + o * 8 + jh) = pk;
            }
        }
    } else {
        int bb = bid - 800;
        const int CHUNK = (2048 * 128 + 2048 * 64) / 16;   // 24576
        for (int idx = bb * CHUNK + tid; idx < (bb + 1) * CHUNK; idx += 256) {
            if (idx < 2048 * 128) {
                int n = idx >> 7, o = idx & 127;
                float a = 0.f;
#pragma unroll
                for (int d = 0; d < EDIM; ++d) a = fmaf(emb[n * EDIM + d], gb[d * 128 + o], a);
                Gb[idx] = a;
            } else {
                int i2 = idx - 2048 * 128;
                int n = i2 >> 6, o = i2 & 63;
                float a = 0.f;
#pragma unroll
                for (int d = 0; d < EDIM; ++d) a = fmaf(emb[n * EDIM + d], ub[d * 64 + o], a);
                Ub[i2] = a;
            }
        }
    }
}

// ---------------- tiny: f16 copies of attn weights ----------------
__global__ __launch_bounds__(256) void k_wcvt(const float* __restrict__ Wi,
        const float* __restrict__ Wo, _Float16* __restrict__ Wi16,
        _Float16* __restrict__ Wo16) {
    int idx = blockIdx.x * 256 + threadIdx.x;
    if (idx < 192 * 64) Wi16[idx] = (_Float16)Wi[idx];
    if (idx < 64 * 64) Wo16[idx] = (_Float16)Wo[idx];
}

// ---------------- tiny: XT x-row for t=0 ----------------
__global__ __launch_bounds__(256) void k_initx(const float* __restrict__ src,
        _Float16* __restrict__ XT) {
    int idx = blockIdx.x * 256 + threadIdx.x;   // b*2048+n
    int b = idx >> 11, n = idx & 2047;
    XT[((long)b * CC) * N_ + n] = (_Float16)src[((long)b * T_) * N_ + n];
}

// ---------------- GEMM core (c-major epilogue, for A2 precompute) ----------------
__device__ __forceinline__ f16x8 lds_frag(const _Float16* base, int r, int kb) {
    int byt = r * 128 + ((kb * 2) ^ ((r & 7) << 4));
    return *(const f16x8*)((const char*)base + byt);
}

__global__ __launch_bounds__(256) void k_gemm(const _Float16* __restrict__ Aop,
        const _Float16* __restrict__ BT, _Float16* __restrict__ DT) {
    __shared__ __align__(16) _Float16 As[3 * 4096];
    __shared__ __align__(16) _Float16 Bs[3 * 4096];
    int bm = blockIdx.x, bc = blockIdx.y, tid = threadIdx.x;
    int wid = tid >> 6, lane = tid & 63;
    int row_g = bm * 64, col_g = bc * 64;
    int r0 = (wid & 1) * 32, c0 = (wid >> 1) * 32;
    int lr8 = lane >> 3;
    int lsw = 8 * ((lane & 7) ^ lr8);
    long aoff[2], boff[2];
    int ldo[2];
#pragma unroll
    for (int i = 0; i < 2; ++i) {
        aoff[i] = (long)(row_g + wid * 16 + i * 8 + lr8) * N_ + lsw;
        boff[i] = (long)(col_g + wid * 16 + i * 8 + lr8) * N_ + lsw;
        ldo[i] = (wid * 16 + i * 8) * 64;
    }
    auto stage = [&](int buf, int kt) {
        int k0 = kt * 64;
#pragma unroll
        for (int i = 0; i < 2; ++i)
            __builtin_amdgcn_global_load_lds(
                (const __attribute__((address_space(1))) void*)(Aop + aoff[i] + k0),
                (__attribute__((address_space(3))) void*)&As[buf * 4096 + ldo[i]], 16, 0, 0);
#pragma unroll
        for (int i = 0; i < 2; ++i)
            __builtin_amdgcn_global_load_lds(
                (const __attribute__((address_space(1))) void*)(BT + boff[i] + k0),
                (__attribute__((address_space(3))) void*)&Bs[buf * 4096 + ldo[i]], 16, 0, 0);
    };
    f32x4 acc[2][2] = {};
    const int NT = 32;
    stage(0, 0); stage(1, 1);
    int buf = 0;
    for (int kt = 0; kt < NT; ++kt) {
        if (kt + 2 < NT) { stage((buf + 2) % 3, kt + 2); asm volatile("s_waitcnt vmcnt(8)" ::: "memory"); }
        else if (kt + 1 < NT) { asm volatile("s_waitcnt vmcnt(4)" ::: "memory"); }
        else { asm volatile("s_waitcnt vmcnt(0)" ::: "memory"); }
        __builtin_amdgcn_s_barrier();
        const _Float16* Ab = As + buf * 4096;
        const _Float16* Bb = Bs + buf * 4096;
#pragma unroll
        for (int kk = 0; kk < 64; kk += 32) {
            int kb = kk + (lane >> 4) * 8;
            f16x8 af0 = lds_frag(Ab, r0 + (lane & 15), kb);
            f16x8 af1 = lds_frag(Ab, r0 + 16 + (lane & 15), kb);
            f16x8 bf0 = lds_frag(Bb, c0 + (lane & 15), kb);
            f16x8 bf1 = lds_frag(Bb, c0 + 16 + (lane & 15), kb);
            acc[0][0] = __builtin_amdgcn_mfma_f32_16x16x32_f16(af0, bf0, acc[0][0], 0, 0, 0);
            acc[0][1] = __builtin_amdgcn_mfma_f32_16x16x32_f16(af0, bf1, acc[0][1], 0, 0, 0);
            acc[1][0] = __builtin_amdgcn_mfma_f32_16x16x32_f16(af1, bf0, acc[1][0], 0, 0, 0);
            acc[1][1] = __builtin_amdgcn_mfma_f32_16x16x32_f16(af1, bf1, acc[1][1], 0, 0, 0);
        }
        asm volatile("s_waitcnt lgkmcnt(0)" ::: "memory");
        __builtin_amdgcn_s_barrier();
        buf = (buf + 1) % 3;
    }
#pragma unroll
    for (int rt = 0; rt < 2; ++rt)
#pragma unroll
        for (int ct = 0; ct < 2; ++ct) {
            int cg = col_g + c0 + ct * 16 + (lane & 15);
            int ng = row_g + r0 + rt * 16 + ((lane >> 4) << 2);
            us4 pk;
#pragma unroll
            for (int q = 0; q < 4; ++q) pk[q] = __builtin_bit_cast(unsigned short, (_Float16)(acc[rt][ct][q] * AINV));
            *(us4*)(DT + (long)cg * N_ + ng) = pk;
        }
}

// fused dual dispatch (z: 0=A->Y1, 1=A2->Y2), NODE-MAJOR epilogue: Y[n*NCP + c]
__global__ __launch_bounds__(256) void k_gemm2(const _Float16* __restrict__ A,
        const _Float16* __restrict__ A2, const _Float16* __restrict__ BT,
        _Float16* __restrict__ Y1, _Float16* __restrict__ Y2) {
    __shared__ __align__(16) _Float16 As[3 * 4096];
    __shared__ __align__(16) _Float16 Bs[3 * 4096];
    const _Float16* Aop = blockIdx.z ? A2 : A;
    _Float16* Yn = blockIdx.z ? Y2 : Y1;
    int bm = blockIdx.x, bc = blockIdx.y, tid = threadIdx.x;
    int wid = tid >> 6, lane = tid & 63;
    int row_g = bm * 64, col_g = bc * 64;
    int r0 = (wid & 1) * 32, c0 = (wid >> 1) * 32;
    int lr8 = lane >> 3;
    int lsw = 8 * ((lane & 7) ^ lr8);
    long aoff[2], boff[2];
    int ldo[2];
#pragma unroll
    for (int i = 0; i < 2; ++i) {
        aoff[i] = (long)(row_g + wid * 16 + i * 8 + lr8) * N_ + lsw;
        boff[i] = (long)(col_g + wid * 16 + i * 8 + lr8) * N_ + lsw;
        ldo[i] = (wid * 16 + i * 8) * 64;
    }
    auto stage = [&](int buf, int kt) {
        int k0 = kt * 64;
#pragma unroll
        for (int i = 0; i < 2; ++i)
            __builtin_amdgcn_global_load_lds(
                (const __attribute__((address_space(1))) void*)(Aop + aoff[i] + k0),
                (__attribute__((address_space(3))) void*)&As[buf * 4096 + ldo[i]], 16, 0, 0);
#pragma unroll
        for (int i = 0; i < 2; ++i)
            __builtin_amdgcn_global_load_lds(
                (const __attribute__((address_space(1))) void*)(BT + boff[i] + k0),
                (__attribute__((address_space(3))) void*)&Bs[buf * 4096 + ldo[i]], 16, 0, 0);
    };
    f32x4 acc[2][2] = {};
    const int NT = 32;
    stage(0, 0); stage(1, 1);
    int buf = 0;
    for (int kt = 0; kt < NT; ++kt) {
        if (kt + 2 < NT) { stage((buf + 2) % 3, kt + 2); asm volatile("s_waitcnt vmcnt(8)" ::: "memory"); }
        else if (kt + 1 < NT) { asm volatile("s_waitcnt vmcnt(4)" ::: "memory"); }
        else { asm volatile("s_waitcnt vmcnt(0)" ::: "memory"); }
        __builtin_amdgcn_s_barrier();
        const _Float16* Ab = As + buf * 4096;
        const _Float16* Bb = Bs + buf * 4096;
#pragma unroll
        for (int kk = 0; kk < 64; kk += 32) {
            int kb = kk + (lane >> 4) * 8;
            f16x8 af0 = lds_frag(Ab, r0 + (lane & 15), kb);
            f16x8 af1 = lds_frag(Ab, r0 + 16 + (lane & 15), kb);
            f16x8 bf0 = lds_frag(Bb, c0 + (lane & 15), kb);
            f16x8 bf1 = lds_frag(Bb, c0 + 16 + (lane & 15), kb);
            acc[0][0] = __builtin_amdgcn_mfma_f32_16x16x32_f16(af0, bf0, acc[0][0], 0, 0, 0);
            acc[0][1] = __builtin_amdgcn_mfma_f32_16x16x32_f16(af0, bf1, acc[0][1], 0, 0, 0);
            acc[1][0] = __builtin_amdgcn_mfma_f32_16x16x32_f16(af1, bf0, acc[1][0], 0, 0, 0);
            acc[1][1] = __builtin_amdgcn_mfma_f32_16x16x32_f16(af1, bf1, acc[1][1], 0, 0, 0);
        }
        asm volatile("s_waitcnt lgkmcnt(0)" ::: "memory");
        __builtin_amdgcn_s_barrier();
        buf = (buf + 1) % 3;
    }
#pragma unroll
    for (int rt = 0; rt < 2; ++rt)
#pragma unroll
        for (int ct = 0; ct < 2; ++ct) {
            int cg = col_g + c0 + ct * 16 + (lane & 15);
            int ng = row_g + r0 + rt * 16 + ((lane >> 4) << 2);
#pragma unroll
            for (int q = 0; q < 4; ++q)
                Yn[(long)(ng + q) * NCP + cg] = (_Float16)(acc[rt][ct][q] * AINV);
        }
}

// ---------------- gate apply (coalesced node-major staging) ----------------
__global__ __launch_bounds__(256) void k_apply_gate(const float* __restrict__ src,
        const _Float16* __restrict__ h, const _Float16* __restrict__ Y1,
        const _Float16* __restrict__ Y2, const _Float16* __restrict__ GwT,
        const float* __restrict__ Gb, int t,
        _Float16* __restrict__ z, _Float16* __restrict__ r, _Float16* __restrict__ XT,
        const _Float16* __restrict__ zp) {
    int n = blockIdx.x, tid = threadIdx.x, wid = tid >> 6, lane = tid & 63;
    __shared__ __align__(16) _Float16 xg[16][232];
    const _Float16* Wp = GwT + (long)n * (NKC * 128 * 8);
    int cl = lane & 15, q = lane >> 4, k8 = q * 8;
    int o0 = wid * 32 + cl, o1 = o0 + 16;
    f16x8 bfr0[7], bfr1[7];
#pragma unroll
    for (int ks = 0; ks < 7; ++ks) {
        bool valid = (ks * 4 + q) < NKC;
        const _Float16* p0 = valid ? Wp + (long)((ks * 4 + q) * 128 + o0) * 8 : zp + cl * 8;
        const _Float16* p1 = valid ? Wp + (long)((ks * 4 + q) * 128 + o1) * 8 : zp + cl * 8 + 128;
        bfr0[ks] = *(const f16x8*)p0;
        bfr1[ks] = *(const f16x8*)p1;
    }
    _Float16* xf = &xg[0][0];
    for (int idx = tid; idx < 16 * 232; idx += 256) xf[idx] = (_Float16)0.f;
    __syncthreads();
    const _Float16* y1p = Y1 + (long)n * NCP;
    const _Float16* y2p = Y2 + (long)n * NCP;
    for (int idx = tid; idx < 16 * KI; idx += 256) {
        int b = idx / KI, kk = idx % KI;
        int k = kk / CC, i = kk % CC;
        int c = b * CC + i;
        float ih = (i == 0) ? src[((long)b * T_ + t) * N_ + n]
                            : (float)h[((long)b * N_ + n) * DH + (i - 1)];
        float val;
        if (k == 0)      val = ih;
        else if (k == 1) val = (float)y1p[c];
        else             val = 2.f * (float)y2p[c] - ih;
        xg[b][kk] = (_Float16)val;
    }
    __syncthreads();
    f32x4 acc0 = {}, acc1 = {};
#pragma unroll
    for (int ks = 0; ks < 7; ++ks) {
        f16x8 af = *(const f16x8*)&xg[cl][ks * 32 + k8];
        acc0 = __builtin_amdgcn_mfma_f32_16x16x32_f16(af, bfr0[ks], acc0, 0, 0, 0);
        acc1 = __builtin_amdgcn_mfma_f32_16x16x32_f16(af, bfr1[ks], acc1, 0, 0, 0);
    }
#pragma unroll
    for (int tl = 0; tl < 2; ++tl) {
        f32x4 acc = tl ? acc1 : acc0;
        int o = wid * 32 + tl * 16 + cl;
        float bias = Gb[(long)n * 128 + o];
#pragma unroll
        for (int qq = 0; qq < 4; ++qq) {
            int b = q * 4 + qq;
            float sv = 1.f / (1.f + __expf(-(acc[qq] + bias)));
            long base = ((long)b * N_ + n) * DH;
            if (o < 64) {
                z[base + o] = (_Float16)sv;
                XT[(long)(b * CC + 1 + o) * N_ + n] = (_Float16)(sv * (float)h[base + o]);
            } else {
                r[base + (o - 64)] = (_Float16)sv;
            }
        }
    }
}

// ---------------- update apply (coalesced node-major staging) ----------------
__global__ __launch_bounds__(256) void k_apply_update(const float* __restrict__ src,
        _Float16* __restrict__ h, const _Float16* __restrict__ Y1,
        const _Float16* __restrict__ Y2, const _Float16* __restrict__ UwT,
        const float* __restrict__ Ub, const _Float16* __restrict__ z,
        const _Float16* __restrict__ rb, int t, _Float16* __restrict__ states,
        _Float16* __restrict__ XT, const _Float16* __restrict__ zp) {
    int n = blockIdx.x, tid = threadIdx.x, wid = tid >> 6, lane = tid & 63;
    __shared__ __align__(16) _Float16 xg[16][232];
    const _Float16* Wp = UwT + (long)n * (NKC * 64 * 8);
    int cl = lane & 15, q = lane >> 4, k8 = q * 8;
    int o0 = wid * 16 + cl;
    f16x8 bfr[7];
#pragma unroll
    for (int ks = 0; ks < 7; ++ks) {
        bool valid = (ks * 4 + q) < NKC;
        const _Float16* p0 = valid ? Wp + (long)((ks * 4 + q) * 64 + o0) * 8 : zp + cl * 8;
        bfr[ks] = *(const f16x8*)p0;
    }
    _Float16* xf = &xg[0][0];
    for (int idx = tid; idx < 16 * 232; idx += 256) xf[idx] = (_Float16)0.f;
    __syncthreads();
    const _Float16* y1p = Y1 + (long)n * NCP;
    const _Float16* y2p = Y2 + (long)n * NCP;
    for (int idx = tid; idx < 16 * KI; idx += 256) {
        int b = idx / KI, kk = idx % KI;
        int k = kk / CC, i = kk % CC;
        int c = b * CC + i;
        float ih;
        if (i == 0) ih = src[((long)b * T_ + t) * N_ + n];
        else {
            long base = ((long)b * N_ + n) * DH + (i - 1);
            ih = (float)h[base] * (float)z[base];
        }
        float val;
        if (k == 0)      val = ih;
        else if (k == 1) val = (float)y1p[c];
        else             val = 2.f * (float)y2p[c] - ih;
        xg[b][kk] = (_Float16)val;
    }
    __syncthreads();
    f32x4 acc0 = {};
#pragma unroll
    for (int ks = 0; ks < 7; ++ks) {
        f16x8 af = *(const f16x8*)&xg[cl][ks * 32 + k8];
        acc0 = __builtin_amdgcn_mfma_f32_16x16x32_f16(af, bfr[ks], acc0, 0, 0, 0);
    }
    int o = o0;
    float bias = Ub[(long)n * 64 + o];
#pragma unroll
    for (int qq = 0; qq < 4; ++qq) {
        int b = q * 4 + qq;
        long base = ((long)b * N_ + n) * DH + o;
        float hc = tanhf(acc0[qq] + bias);
        float rv = (float)rb[base], hv = (float)h[base];
        float hn = rv * hv + (1.f - rv) * hc;
        _Float16 hn16 = (_Float16)hn;
        h[base] = hn16;
        states[(((long)b * T_ + t) * N_ + n) * DH + o] = hn16;
        XT[(long)(b * CC + 1 + o) * N_ + n] = hn16;
        if (o == 0 && t + 1 < T_)
            XT[(long)(b * CC) * N_ + n] = (_Float16)src[((long)b * T_ + t + 1) * N_ + n];
    }
}

// ---------------- qkv projection (MFMA): KV for all t, Q at t=11 ----------------
__global__ __launch_bounds__(256) void k_qkv(const _Float16* __restrict__ st,
        const _Float16* __restrict__ Wi16, const float* __restrict__ bi,
        _Float16* __restrict__ KV, _Float16* __restrict__ Q) {
    int bt = blockIdx.x;
    int nck = blockIdx.y;
    int b = bt / 12, t = bt % 12;
    int tid = threadIdx.x, wid = tid >> 6, lane = tid & 63;
    __shared__ float pe[64];
    __shared__ __align__(16) _Float16 Xs[128][72];
    if (tid < 64) {
        int e = tid;
        float div = __powf(10000.f, -(float)(e & ~1) / 64.f);
        float ang = (float)t * div;
        pe[e] = (e & 1) ? __cosf(ang) : __sinf(ang);
    }
    __syncthreads();
    const _Float16* srcp = st + ((long)(b * T_ + t) * N_ + nck * 128) * DH;
#pragma unroll
    for (int u = 0; u < 4; ++u) {
        int idx = u * 256 + tid;
        int rr = idx >> 3, e0 = (idx & 7) * 8;
        f16x8 v = *(const f16x8*)(srcp + rr * DH + e0);
        f16x8 ov;
#pragma unroll
        for (int q = 0; q < 8; ++q) ov[q] = (_Float16)((float)v[q] + pe[e0 + q]);
        *(f16x8*)&Xs[rr][e0] = ov;
    }
    __syncthreads();
    int cl = lane & 15, ks8 = (lane >> 4) * 8;
    f16x8 bfrag[3][2];
    float bias[3];
#pragma unroll
    for (int j = 0; j < 3; ++j) {
        int c = (wid * 3 + j) * 16 + cl;
#pragma unroll
        for (int ks = 0; ks < 2; ++ks)
            bfrag[j][ks] = *(const f16x8*)(Wi16 + c * 64 + ks * 32 + ks8);
        bias[j] = bi[c];
    }
    f32x4 acc[8][3] = {};
#pragma unroll
    for (int rt = 0; rt < 8; ++rt) {
#pragma unroll
        for (int ks = 0; ks < 2; ++ks) {
            f16x8 af = *(const f16x8*)&Xs[rt * 16 + cl][ks * 32 + ks8];
#pragma unroll
            for (int j = 0; j < 3; ++j)
                acc[rt][j] = __builtin_amdgcn_mfma_f32_16x16x32_f16(af, bfrag[j][ks], acc[rt][j], 0, 0, 0);
        }
    }
    int rowq = (lane >> 4) * 4;
#pragma unroll
    for (int rt = 0; rt < 8; ++rt)
#pragma unroll
        for (int j = 0; j < 3; ++j) {
            int c = (wid * 3 + j) * 16 + cl;
#pragma unroll
            for (int q = 0; q < 4; ++q) {
                int n = nck * 128 + rt * 16 + rowq + q;
                float val = acc[rt][j][q] + bias[j];
                if (c >= 64)
                    KV[(((long)b * N_ + n) * T_ + t) * 128 + (c - 64)] = (_Float16)val;
                else if (t == 11)
                    Q[((long)b * N_ + n) * 64 + c] = (_Float16)val;
            }
        }
}

// ---------------- attention + out-proj: 16 pairs/block, 16 threads/pair ----------------
__global__ __launch_bounds__(256) void k_attn2(const _Float16* __restrict__ KV,
        const _Float16* __restrict__ Q, const _Float16* __restrict__ Wo16,
        const float* __restrict__ bo, float* __restrict__ o1) {
    __shared__ _Float16 kvs[16 * 1544];
    __shared__ float qs[16][64];
    __shared__ float Wos[64][64];
    __shared__ float outb[16][64];
    __shared__ float bos[64];
    int tid = threadIdx.x;
    long pair0 = (long)blockIdx.x * 16;
#pragma unroll
    for (int u = 0; u < 12; ++u) {
        int idx = u * 256 + tid;
        int p = idx / 192, off8 = (idx % 192) * 8;
        *(f16x8*)&kvs[p * 1544 + off8] = *(const f16x8*)(KV + (pair0 + p) * 1536 + off8);
    }
    if (tid < 64) bos[tid] = bo[tid];
    for (int idx = tid; idx < 1024; idx += 256) {
        int p = idx >> 6, j = idx & 63;
        qs[p][j] = (float)Q[(pair0 + p) * 64 + j];
    }
    for (int idx = tid; idx < 4096; idx += 256) {
        int c = idx >> 6, j = idx & 63;
        Wos[c][j] = (float)Wo16[j * 64 + c];
    }
    __syncthreads();
    int p = tid >> 4, i = tid & 15;
    int h = i >> 2, sg = i & 3;
    const _Float16* kvp = &kvs[p * 1544];
    float att3[3], mx = -1e30f;
#pragma unroll
    for (int j = 0; j < 3; ++j) {
        int s = sg + 4 * j;
        float sc = 0.f;
#pragma unroll
        for (int d = 0; d < 16; ++d)
            sc = fmaf(qs[p][h * 16 + d], (float)kvp[s * 128 + h * 16 + d], sc);
        att3[j] = sc * 0.25f;
        mx = fmaxf(mx, att3[j]);
    }
    mx = fmaxf(mx, __shfl_xor(mx, 1));
    mx = fmaxf(mx, __shfl_xor(mx, 2));
    float se = 0.f;
#pragma unroll
    for (int j = 0; j < 3; ++j) { att3[j] = __expf(att3[j] - mx); se += att3[j]; }
    se += __shfl_xor(se, 1);
    se += __shfl_xor(se, 2);
    float inv = 1.f / se;
#pragma unroll
    for (int j = 0; j < 3; ++j) att3[j] *= inv;
    int c0 = i * 4;
    float out4[4] = {0.f, 0.f, 0.f, 0.f};
#pragma unroll
    for (int m = 0; m < 4; ++m) {
        float a0 = __shfl_xor(att3[0], m);
        float a1 = __shfl_xor(att3[1], m);
        float a2 = __shfl_xor(att3[2], m);
        int sb = sg ^ m;
        float aj[3] = {a0, a1, a2};
#pragma unroll
        for (int j = 0; j < 3; ++j) {
            int s = sb + 4 * j;
            f16x4 vv = *(const f16x4*)&kvp[s * 128 + 64 + c0];
#pragma unroll
            for (int q = 0; q < 4; ++q) out4[q] = fmaf(aj[j], (float)vv[q], out4[q]);
        }
    }
    *(float4*)&outb[p][c0] = *(float4*)out4;
    __syncthreads();
    float res[4];
#pragma unroll
    for (int q = 0; q < 4; ++q) res[q] = bos[c0 + q];
    for (int c = 0; c < 64; ++c) {
        float oc = outb[p][c];
        float4 wv = *(const float4*)&Wos[c][c0];
        res[0] = fmaf(oc, wv.x, res[0]);
        res[1] = fmaf(oc, wv.y, res[1]);
        res[2] = fmaf(oc, wv.z, res[2]);
        res[3] = fmaf(oc, wv.w, res[3]);
    }
    *(float4*)&o1[(pair0 + p) * 64 + c0] = make_float4(res[0], res[1], res[2], res[3]);
}

// ---------------- output head ----------------
__global__ __launch_bounds__(256) void k_final(const float* __restrict__ o1,
        const _Float16* __restrict__ hT, const float* __restrict__ cw,
        const float* __restrict__ convw, const float* __restrict__ convb,
        float* __restrict__ out) {
    __shared__ float Ws[12 * 3 * 64];
    __shared__ float cbs[12];
    int tid = threadIdx.x;
    for (int idx = tid; idx < 12 * 3 * 64; idx += 256) Ws[idx] = convw[idx];
    if (tid < 12) cbs[tid] = convb[tid];
    __syncthreads();
    float c0 = cw[0], c1 = cw[1], c2 = cw[2];
    int g = tid >> 6, j = tid & 63;
    int bn = blockIdx.x * 4 + g;
    int b = bn >> 11, n = bn & 2047;
    float x1 = o1[(long)bn * DH + j];
    float x3 = (float)hT[(long)bn * DH + j];
    float myout = 0.f;
#pragma unroll
    for (int oc = 0; oc < 12; ++oc) {
        float p = x1 * c0 * Ws[(oc * 3 + 0) * 64 + j]
                + x3 * (c1 * Ws[(oc * 3 + 1) * 64 + j] + c2 * Ws[(oc * 3 + 2) * 64 + j]);
        p += __shfl_xor(p, 1); p += __shfl_xor(p, 2); p += __shfl_xor(p, 4);
        p += __shfl_xor(p, 8); p += __shfl_xor(p, 16); p += __shfl_xor(p, 32);
        if (j == oc) myout = p + cbs[oc];
    }
    if (j < 12) out[((long)b * 12 + j) * N_ + n] = myout;
}

extern "C" void kernel_launch(void* const* d_in, const int* in_sizes, int n_in,
                              void* d_out, int out_size, void* d_ws, size_t ws_size,
                              hipStream_t stream) {
    const float* src    = (const float*)d_in[0];
    const float* emb    = (const float*)d_in[2];
    const float* gate_w = (const float*)d_in[3];
    const float* gate_b = (const float*)d_in[4];
    const float* upd_w  = (const float*)d_in[5];
    const float* upd_b  = (const float*)d_in[6];
    const float* a_in_w = (const float*)d_in[7];
    const float* a_in_b = (const float*)d_in[8];
    const float* a_out_w= (const float*)d_in[9];
    const float* a_out_b= (const float*)d_in[10];
    const float* chan_w = (const float*)d_in[11];
    const float* conv_w = (const float*)d_in[12];
    const float* conv_b = (const float*)d_in[13];
    float* out = (float*)d_out;

    char* ws = (char*)d_ws;
    size_t off = 0;
    auto alloc = [&](size_t bytes) { char* p = ws + off; off += (bytes + 255) & ~size_t(255); return p; };
    _Float16* A    = (_Float16*)alloc((size_t)N_ * N_ * 2);
    _Float16* A2   = (_Float16*)alloc((size_t)N_ * N_ * 2);
    _Float16* GwT  = (_Float16*)alloc((size_t)N_ * NKC * 128 * 8 * 2);   // 104.9 MB
    float*  Gb     = (float*) alloc((size_t)N_ * 128 * 4);
    _Float16* UwT  = (_Float16*)alloc((size_t)N_ * NKC * 64 * 8 * 2);    // 52.4 MB
    float*  Ub     = (float*) alloc((size_t)N_ * 64 * 4);
    _Float16* XT   = (_Float16*)alloc((size_t)NCP * N_ * 2);
    _Float16* Y1   = (_Float16*)alloc((size_t)N_ * NCP * 2);   // node-major [n][c]
    _Float16* Y2   = (_Float16*)alloc((size_t)N_ * NCP * 2);   // node-major [n][c]
    _Float16* h    = (_Float16*)alloc((size_t)B_ * N_ * DH * 2);
    _Float16* zbuf = (_Float16*)alloc((size_t)B_ * N_ * DH * 2);
    _Float16* rbuf = (_Float16*)alloc((size_t)B_ * N_ * DH * 2);
    _Float16* stt  = (_Float16*)alloc((size_t)B_ * T_ * N_ * DH * 2);
    _Float16* Wi16 = (_Float16*)alloc(192 * 64 * 2);
    _Float16* Wo16 = (_Float16*)alloc(64 * 64 * 2);
    _Float16* zp   = (_Float16*)alloc(512);
    if (off > ws_size) return;   // ~252 MB total

    // transient/dead-region aliases
    _Float16* AT = stt;                            // 8.4 MB scratch (stt unwritten at setup)
    _Float16* KV = GwT;                            // 100.7 MB into GwT's 104.9 MB
    _Float16* Qb = UwT;                            // 4.2 MB at UwT start
    float*    o1 = (float*)((char*)UwT + (8u << 20)); // 8.4 MB at UwT+8MB

    hipMemsetAsync(h, 0, (size_t)B_ * N_ * DH * 2, stream);
    hipMemsetAsync(XT, 0, (size_t)NCP * N_ * 2, stream);
    hipMemsetAsync(zp, 0, 512, stream);
    k_compA<<<N_, 256, 0, stream>>>(emb, A);
    dim3 tgrid(32, 32);
    k_transp<<<tgrid, 256, 0, stream>>>(A, AT);
    k_gemm<<<tgrid, 256, 0, stream>>>(AT, A, A2);   // A2 = (1024*A^2), Aop=AT BT=A
    k_build<<<816, 256, 0, stream>>>(emb, gate_w, gate_b, upd_w, upd_b, GwT, Gb, UwT, Ub);
    k_wcvt<<<48, 256, 0, stream>>>(a_in_w, a_out_w, Wi16, Wo16);
    k_initx<<<128, 256, 0, stream>>>(src, XT);

    dim3 ggrid(32, 17, 2);
    for (int t = 0; t < T_; ++t) {
        k_gemm2<<<ggrid, 256, 0, stream>>>(A, A2, XT, Y1, Y2);
        k_apply_gate<<<N_, 256, 0, stream>>>(src, h, Y1, Y2, GwT, Gb, t, zbuf, rbuf, XT, zp);
        k_gemm2<<<ggrid, 256, 0, stream>>>(A, A2, XT, Y1, Y2);
        k_apply_update<<<N_, 256, 0, stream>>>(src, h, Y1, Y2, UwT, Ub, zbuf, rbuf, t, stt, XT, zp);
    }
    dim3 qgrid(192, 16);
    k_qkv<<<qgrid, 256, 0, stream>>>(stt, Wi16, a_in_b, KV, Qb);
    k_attn2<<<2048, 256, 0, stream>>>(KV, Qb, Wo16, a_out_b, o1);
    k_final<<<8192, 256, 0, stream>>>(o1, h, chan_w, conv_w, conv_b, out);
}

// Round 18
// 1949.402 us; speedup vs baseline: 1.3103x; 1.1466x over previous
//
#include <hip/hip_runtime.h>
#include <hip/hip_bf16.h>

typedef _Float16 f16x8 __attribute__((ext_vector_type(8)));
typedef _Float16 f16x4 __attribute__((ext_vector_type(4)));
typedef float f32x4 __attribute__((ext_vector_type(4)));
typedef unsigned short us8 __attribute__((ext_vector_type(8)));
typedef unsigned short us4 __attribute__((ext_vector_type(4)));

#define N_ 2048
#define B_ 16
#define T_ 12
#define DH 64
#define CC 65      // DIN + DOUT
#define NC 1040    // B_*CC
#define NCP 1088   // padded col count (17*64)
#define KI 195     // K*CC
#define NKC 25     // kk-chunks of 8 (200 slots, kk>=195 zero)
#define EDIM 10
#define ASCALE 1024.0f
#define AINV (1.0f / 1024.0f)

// ---------------- A = softmax(relu(E E^T)) rowwise, f16 scaled by 1024 ----------------
__global__ __launch_bounds__(256) void k_compA(const float* __restrict__ emb,
                                               _Float16* __restrict__ A) {
    int n = blockIdx.x, tid = threadIdx.x;
    float en[EDIM];
#pragma unroll
    for (int d = 0; d < EDIM; ++d) en[d] = emb[n * EDIM + d];
    float v[8], mx = -1e30f;
#pragma unroll
    for (int j = 0; j < 8; ++j) {
        int m = tid + j * 256;
        float acc = 0.f;
#pragma unroll
        for (int d = 0; d < EDIM; ++d) acc = fmaf(en[d], emb[m * EDIM + d], acc);
        acc = fmaxf(acc, 0.f);
        v[j] = acc; mx = fmaxf(mx, acc);
    }
    __shared__ float red[256];
    red[tid] = mx; __syncthreads();
    for (int s = 128; s > 0; s >>= 1) { if (tid < s) red[tid] = fmaxf(red[tid], red[tid + s]); __syncthreads(); }
    mx = red[0]; __syncthreads();
    float se = 0.f;
#pragma unroll
    for (int j = 0; j < 8; ++j) { v[j] = __expf(v[j] - mx); se += v[j]; }
    red[tid] = se; __syncthreads();
    for (int s = 128; s > 0; s >>= 1) { if (tid < s) red[tid] += red[tid + s]; __syncthreads(); }
    float inv = ASCALE / red[0];
#pragma unroll
    for (int j = 0; j < 8; ++j) A[(long)n * N_ + tid + j * 256] = (_Float16)(v[j] * inv);
}

// ---------------- transpose A -> AT (64x64 LDS tiles) ----------------
__global__ __launch_bounds__(256) void k_transp(const _Float16* __restrict__ A,
                                                _Float16* __restrict__ AT) {
    __shared__ _Float16 tile[64][72];
    int bx = blockIdx.x, by = blockIdx.y;
    int tid = threadIdx.x;
    int r8 = tid >> 3, c8 = (tid & 7) * 8;
#pragma unroll
    for (int p = 0; p < 2; ++p) {
        int r = p * 32 + r8;
        *(f16x8*)&tile[r][c8] = *(const f16x8*)(A + (long)(by * 64 + r) * N_ + bx * 64 + c8);
    }
    __syncthreads();
#pragma unroll
    for (int p = 0; p < 2; ++p) {
        int r = p * 32 + r8;
        f16x8 v;
#pragma unroll
        for (int q = 0; q < 8; ++q) v[q] = tile[c8 + q][r];
        *(f16x8*)(AT + (long)(bx * 64 + r) * N_ + by * 64 + c8) = v;
    }
}

// ---------------- per-node GRU weights, MFMA-fragment order, o-major ----------------
__global__ __launch_bounds__(256) void k_build(const float* __restrict__ emb,
        const float* __restrict__ gw, const float* __restrict__ gb,
        const float* __restrict__ uw, const float* __restrict__ ub,
        _Float16* __restrict__ GwT, float* __restrict__ Gb,
        _Float16* __restrict__ UwT, float* __restrict__ Ub) {
    int bid = blockIdx.x;
    int tid = threadIdx.x;
    if (bid < 800) {
        __shared__ float embs[128][EDIM];
        int isupd = bid >= 400;
        int b2 = isupd ? bid - 400 : bid;
        int kkc = b2 >> 4, nch = b2 & 15;
        for (int idx = tid; idx < 128 * EDIM; idx += 256)
            embs[idx / EDIM][idx % EDIM] = emb[(nch * 128 + idx / EDIM) * EDIM + idx % EDIM];
        __syncthreads();
        if (!isupd) {
            int o = tid >> 1, jh = (tid & 1) * 4;
            float w[EDIM][4];
#pragma unroll
            for (int d = 0; d < EDIM; ++d)
#pragma unroll
                for (int jj = 0; jj < 4; ++jj) {
                    int kk = kkc * 8 + jh + jj;
                    w[d][jj] = (kk < KI) ? gw[(long)d * (KI * 128) + (long)kk * 128 + o] : 0.f;
                }
            for (int i = 0; i < 128; ++i) {
                int n = nch * 128 + i;
                float a0 = 0.f, a1 = 0.f, a2 = 0.f, a3 = 0.f;
#pragma unroll
                for (int d = 0; d < EDIM; ++d) {
                    float ed = embs[i][d];
                    a0 = fmaf(ed, w[d][0], a0); a1 = fmaf(ed, w[d][1], a1);
                    a2 = fmaf(ed, w[d][2], a2); a3 = fmaf(ed, w[d][3], a3);
                }
                us4 pk;
                pk[0] = __builtin_bit_cast(unsigned short, (_Float16)a0);
                pk[1] = __builtin_bit_cast(unsigned short, (_Float16)a1);
                pk[2] = __builtin_bit_cast(unsigned short, (_Float16)a2);
                pk[3] = __builtin_bit_cast(unsigned short, (_Float16)a3);
                *(us4*)(GwT + ((long)n * NKC + kkc) * 1024 + o * 8 + jh) = pk;
            }
        } else {
            int sub = tid >> 7, o = (tid >> 1) & 63, jh = (tid & 1) * 4;
            float w[EDIM][4];
#pragma unroll
            for (int d = 0; d < EDIM; ++d)
#pragma unroll
                for (int jj = 0; jj < 4; ++jj) {
                    int kk = kkc * 8 + jh + jj;
                    w[d][jj] = (kk < KI) ? uw[(long)d * (KI * 64) + (long)kk * 64 + o] : 0.f;
                }
            for (int i = 0; i < 64; ++i) {
                int il = i * 2 + sub;
                int n = nch * 128 + il;
                float a0 = 0.f, a1 = 0.f, a2 = 0.f, a3 = 0.f;
#pragma unroll
                for (int d = 0; d < EDIM; ++d) {
                    float ed = embs[il][d];
                    a0 = fmaf(ed, w[d][0], a0); a1 = fmaf(ed, w[d][1], a1);
                    a2 = fmaf(ed, w[d][2], a2); a3 = fmaf(ed, w[d][3], a3);
                }
                us4 pk;
                pk[0] = __builtin_bit_cast(unsigned short, (_Float16)a0);
                pk[1] = __builtin_bit_cast(unsigned short, (_Float16)a1);
                pk[2] = __builtin_bit_cast(unsigned short, (_Float16)a2);
                pk[3] = __builtin_bit_cast(unsigned short, (_Float16)a3);
                *(us4*)(UwT + ((long)n * NKC + kkc) * 512 + o * 8 + jh) = pk;
            }
        }
    } else {
        int bb = bid - 800;
        const int CHUNK = (2048 * 128 + 2048 * 64) / 16;   // 24576
        for (int idx = bb * CHUNK + tid; idx < (bb + 1) * CHUNK; idx += 256) {
            if (idx < 2048 * 128) {
                int n = idx >> 7, o = idx & 127;
                float a = 0.f;
#pragma unroll
                for (int d = 0; d < EDIM; ++d) a = fmaf(emb[n * EDIM + d], gb[d * 128 + o], a);
                Gb[idx] = a;
            } else {
                int i2 = idx - 2048 * 128;
                int n = i2 >> 6, o = i2 & 63;
                float a = 0.f;
#pragma unroll
                for (int d = 0; d < EDIM; ++d) a = fmaf(emb[n * EDIM + d], ub[d * 64 + o], a);
                Ub[i2] = a;
            }
        }
    }
}

// ---------------- tiny: f16 copies of attn weights ----------------
__global__ __launch_bounds__(256) void k_wcvt(const float* __restrict__ Wi,
        const float* __restrict__ Wo, _Float16* __restrict__ Wi16,
        _Float16* __restrict__ Wo16) {
    int idx = blockIdx.x * 256 + threadIdx.x;
    if (idx < 192 * 64) Wi16[idx] = (_Float16)Wi[idx];
    if (idx < 64 * 64) Wo16[idx] = (_Float16)Wo[idx];
}

// ---------------- tiny: XT x-row for t=0 ----------------
__global__ __launch_bounds__(256) void k_initx(const float* __restrict__ src,
        _Float16* __restrict__ XT) {
    int idx = blockIdx.x * 256 + threadIdx.x;   // b*2048+n
    int b = idx >> 11, n = idx & 2047;
    XT[((long)b * CC) * N_ + n] = (_Float16)src[((long)b * T_) * N_ + n];
}

// ---------------- GEMM core (c-major epilogue, for A2 precompute) ----------------
__device__ __forceinline__ f16x8 lds_frag(const _Float16* base, int r, int kb) {
    int byt = r * 128 + ((kb * 2) ^ ((r & 7) << 4));
    return *(const f16x8*)((const char*)base + byt);
}

__global__ __launch_bounds__(256) void k_gemm(const _Float16* __restrict__ Aop,
        const _Float16* __restrict__ BT, _Float16* __restrict__ DT) {
    __shared__ __align__(16) _Float16 As[3 * 4096];
    __shared__ __align__(16) _Float16 Bs[3 * 4096];
    int bm = blockIdx.x, bc = blockIdx.y, tid = threadIdx.x;
    int wid = tid >> 6, lane = tid & 63;
    int row_g = bm * 64, col_g = bc * 64;
    int r0 = (wid & 1) * 32, c0 = (wid >> 1) * 32;
    int lr8 = lane >> 3;
    int lsw = 8 * ((lane & 7) ^ lr8);
    long aoff[2], boff[2];
    int ldo[2];
#pragma unroll
    for (int i = 0; i < 2; ++i) {
        aoff[i] = (long)(row_g + wid * 16 + i * 8 + lr8) * N_ + lsw;
        boff[i] = (long)(col_g + wid * 16 + i * 8 + lr8) * N_ + lsw;
        ldo[i] = (wid * 16 + i * 8) * 64;
    }
    auto stage = [&](int buf, int kt) {
        int k0 = kt * 64;
#pragma unroll
        for (int i = 0; i < 2; ++i)
            __builtin_amdgcn_global_load_lds(
                (const __attribute__((address_space(1))) void*)(Aop + aoff[i] + k0),
                (__attribute__((address_space(3))) void*)&As[buf * 4096 + ldo[i]], 16, 0, 0);
#pragma unroll
        for (int i = 0; i < 2; ++i)
            __builtin_amdgcn_global_load_lds(
                (const __attribute__((address_space(1))) void*)(BT + boff[i] + k0),
                (__attribute__((address_space(3))) void*)&Bs[buf * 4096 + ldo[i]], 16, 0, 0);
    };
    f32x4 acc[2][2] = {};
    const int NT = 32;
    stage(0, 0); stage(1, 1);
    int buf = 0;
    for (int kt = 0; kt < NT; ++kt) {
        if (kt + 2 < NT) { stage((buf + 2) % 3, kt + 2); asm volatile("s_waitcnt vmcnt(8)" ::: "memory"); }
        else if (kt + 1 < NT) { asm volatile("s_waitcnt vmcnt(4)" ::: "memory"); }
        else { asm volatile("s_waitcnt vmcnt(0)" ::: "memory"); }
        __builtin_amdgcn_s_barrier();
        const _Float16* Ab = As + buf * 4096;
        const _Float16* Bb = Bs + buf * 4096;
#pragma unroll
        for (int kk = 0; kk < 64; kk += 32) {
            int kb = kk + (lane >> 4) * 8;
            f16x8 af0 = lds_frag(Ab, r0 + (lane & 15), kb);
            f16x8 af1 = lds_frag(Ab, r0 + 16 + (lane & 15), kb);
            f16x8 bf0 = lds_frag(Bb, c0 + (lane & 15), kb);
            f16x8 bf1 = lds_frag(Bb, c0 + 16 + (lane & 15), kb);
            acc[0][0] = __builtin_amdgcn_mfma_f32_16x16x32_f16(af0, bf0, acc[0][0], 0, 0, 0);
            acc[0][1] = __builtin_amdgcn_mfma_f32_16x16x32_f16(af0, bf1, acc[0][1], 0, 0, 0);
            acc[1][0] = __builtin_amdgcn_mfma_f32_16x16x32_f16(af1, bf0, acc[1][0], 0, 0, 0);
            acc[1][1] = __builtin_amdgcn_mfma_f32_16x16x32_f16(af1, bf1, acc[1][1], 0, 0, 0);
        }
        asm volatile("s_waitcnt lgkmcnt(0)" ::: "memory");
        __builtin_amdgcn_s_barrier();
        buf = (buf + 1) % 3;
    }
#pragma unroll
    for (int rt = 0; rt < 2; ++rt)
#pragma unroll
        for (int ct = 0; ct < 2; ++ct) {
            int cg = col_g + c0 + ct * 16 + (lane & 15);
            int ng = row_g + r0 + rt * 16 + ((lane >> 4) << 2);
            us4 pk;
#pragma unroll
            for (int q = 0; q < 4; ++q) pk[q] = __builtin_bit_cast(unsigned short, (_Float16)(acc[rt][ct][q] * AINV));
            *(us4*)(DT + (long)cg * N_ + ng) = pk;
        }
}

// fused dual dispatch, 128-ROW tile (z: 0=A->Y1, 1=A2->Y2), node-major epilogue
// grid (16, 17, 2) = 544 blocks; LDS 48KB (2-buf); 16 MFMA/wave/K-step
__global__ __launch_bounds__(256) void k_gemm2(const _Float16* __restrict__ A,
        const _Float16* __restrict__ A2, const _Float16* __restrict__ BT,
        _Float16* __restrict__ Y1, _Float16* __restrict__ Y2) {
    __shared__ __align__(16) _Float16 As[2 * 8192];
    __shared__ __align__(16) _Float16 Bs[2 * 4096];
    const _Float16* Aop = blockIdx.z ? A2 : A;
    _Float16* Yn = blockIdx.z ? Y2 : Y1;
    int bm = blockIdx.x, bc = blockIdx.y, tid = threadIdx.x;
    int wid = tid >> 6, lane = tid & 63;
    int row_g = bm * 128, col_g = bc * 64;
    int r0 = (wid & 1) * 64, c0 = (wid >> 1) * 32;
    int lr8 = lane >> 3;
    int lsw = 8 * ((lane & 7) ^ lr8);
    long aoff[4], boff[2];
    int lao[4], lbo[2];
#pragma unroll
    for (int i = 0; i < 4; ++i) {
        aoff[i] = (long)(row_g + wid * 32 + i * 8 + lr8) * N_ + lsw;
        lao[i] = (wid * 32 + i * 8) * 64;
    }
#pragma unroll
    for (int i = 0; i < 2; ++i) {
        boff[i] = (long)(col_g + wid * 16 + i * 8 + lr8) * N_ + lsw;
        lbo[i] = (wid * 16 + i * 8) * 64;
    }
    auto stage = [&](int buf, int kt) {
        int k0 = kt * 64;
#pragma unroll
        for (int i = 0; i < 4; ++i)
            __builtin_amdgcn_global_load_lds(
                (const __attribute__((address_space(1))) void*)(Aop + aoff[i] + k0),
                (__attribute__((address_space(3))) void*)&As[buf * 8192 + lao[i]], 16, 0, 0);
#pragma unroll
        for (int i = 0; i < 2; ++i)
            __builtin_amdgcn_global_load_lds(
                (const __attribute__((address_space(1))) void*)(BT + boff[i] + k0),
                (__attribute__((address_space(3))) void*)&Bs[buf * 4096 + lbo[i]], 16, 0, 0);
    };
    f32x4 acc[4][2] = {};
    const int NT = 32;
    stage(0, 0);
    for (int kt = 0; kt < NT; ++kt) {
        int buf = kt & 1;
        if (kt + 1 < NT) {
            stage(buf ^ 1, kt + 1);
            asm volatile("s_waitcnt vmcnt(6)" ::: "memory");
        } else {
            asm volatile("s_waitcnt vmcnt(0)" ::: "memory");
        }
        __builtin_amdgcn_s_barrier();
        const _Float16* Ab = As + buf * 8192;
        const _Float16* Bb = Bs + buf * 4096;
#pragma unroll
        for (int kk = 0; kk < 64; kk += 32) {
            int kb = kk + (lane >> 4) * 8;
            f16x8 bf0 = lds_frag(Bb, c0 + (lane & 15), kb);
            f16x8 bf1 = lds_frag(Bb, c0 + 16 + (lane & 15), kb);
#pragma unroll
            for (int rt = 0; rt < 4; ++rt) {
                f16x8 af = lds_frag(Ab, r0 + rt * 16 + (lane & 15), kb);
                acc[rt][0] = __builtin_amdgcn_mfma_f32_16x16x32_f16(af, bf0, acc[rt][0], 0, 0, 0);
                acc[rt][1] = __builtin_amdgcn_mfma_f32_16x16x32_f16(af, bf1, acc[rt][1], 0, 0, 0);
            }
        }
        asm volatile("s_waitcnt lgkmcnt(0)" ::: "memory");
        __builtin_amdgcn_s_barrier();
    }
#pragma unroll
    for (int rt = 0; rt < 4; ++rt)
#pragma unroll
        for (int ct = 0; ct < 2; ++ct) {
            int cg = col_g + c0 + ct * 16 + (lane & 15);
            int ng = row_g + r0 + rt * 16 + ((lane >> 4) << 2);
#pragma unroll
            for (int q = 0; q < 4; ++q)
                Yn[(long)(ng + q) * NCP + cg] = (_Float16)(acc[rt][ct][q] * AINV);
        }
}

// ---------------- gate apply (coalesced node-major staging) ----------------
__global__ __launch_bounds__(256) void k_apply_gate(const float* __restrict__ src,
        const _Float16* __restrict__ h, const _Float16* __restrict__ Y1,
        const _Float16* __restrict__ Y2, const _Float16* __restrict__ GwT,
        const float* __restrict__ Gb, int t,
        _Float16* __restrict__ z, _Float16* __restrict__ r, _Float16* __restrict__ XT,
        const _Float16* __restrict__ zp) {
    int n = blockIdx.x, tid = threadIdx.x, wid = tid >> 6, lane = tid & 63;
    __shared__ __align__(16) _Float16 xg[16][232];
    const _Float16* Wp = GwT + (long)n * (NKC * 128 * 8);
    int cl = lane & 15, q = lane >> 4, k8 = q * 8;
    int o0 = wid * 32 + cl, o1 = o0 + 16;
    f16x8 bfr0[7], bfr1[7];
#pragma unroll
    for (int ks = 0; ks < 7; ++ks) {
        bool valid = (ks * 4 + q) < NKC;
        const _Float16* p0 = valid ? Wp + (long)((ks * 4 + q) * 128 + o0) * 8 : zp + cl * 8;
        const _Float16* p1 = valid ? Wp + (long)((ks * 4 + q) * 128 + o1) * 8 : zp + cl * 8 + 128;
        bfr0[ks] = *(const f16x8*)p0;
        bfr1[ks] = *(const f16x8*)p1;
    }
    _Float16* xf = &xg[0][0];
    for (int idx = tid; idx < 16 * 232; idx += 256) xf[idx] = (_Float16)0.f;
    __syncthreads();
    const _Float16* y1p = Y1 + (long)n * NCP;
    const _Float16* y2p = Y2 + (long)n * NCP;
    for (int idx = tid; idx < 16 * KI; idx += 256) {
        int b = idx / KI, kk = idx % KI;
        int k = kk / CC, i = kk % CC;
        int c = b * CC + i;
        float ih = (i == 0) ? src[((long)b * T_ + t) * N_ + n]
                            : (float)h[((long)b * N_ + n) * DH + (i - 1)];
        float val;
        if (k == 0)      val = ih;
        else if (k == 1) val = (float)y1p[c];
        else             val = 2.f * (float)y2p[c] - ih;
        xg[b][kk] = (_Float16)val;
    }
    __syncthreads();
    f32x4 acc0 = {}, acc1 = {};
#pragma unroll
    for (int ks = 0; ks < 7; ++ks) {
        f16x8 af = *(const f16x8*)&xg[cl][ks * 32 + k8];
        acc0 = __builtin_amdgcn_mfma_f32_16x16x32_f16(af, bfr0[ks], acc0, 0, 0, 0);
        acc1 = __builtin_amdgcn_mfma_f32_16x16x32_f16(af, bfr1[ks], acc1, 0, 0, 0);
    }
#pragma unroll
    for (int tl = 0; tl < 2; ++tl) {
        f32x4 acc = tl ? acc1 : acc0;
        int o = wid * 32 + tl * 16 + cl;
        float bias = Gb[(long)n * 128 + o];
#pragma unroll
        for (int qq = 0; qq < 4; ++qq) {
            int b = q * 4 + qq;
            float sv = 1.f / (1.f + __expf(-(acc[qq] + bias)));
            long base = ((long)b * N_ + n) * DH;
            if (o < 64) {
                z[base + o] = (_Float16)sv;
                XT[(long)(b * CC + 1 + o) * N_ + n] = (_Float16)(sv * (float)h[base + o]);
            } else {
                r[base + (o - 64)] = (_Float16)sv;
            }
        }
    }
}

// ---------------- update apply (coalesced node-major staging) ----------------
__global__ __launch_bounds__(256) void k_apply_update(const float* __restrict__ src,
        _Float16* __restrict__ h, const _Float16* __restrict__ Y1,
        const _Float16* __restrict__ Y2, const _Float16* __restrict__ UwT,
        const float* __restrict__ Ub, const _Float16* __restrict__ z,
        const _Float16* __restrict__ rb, int t, _Float16* __restrict__ states,
        _Float16* __restrict__ XT, const _Float16* __restrict__ zp) {
    int n = blockIdx.x, tid = threadIdx.x, wid = tid >> 6, lane = tid & 63;
    __shared__ __align__(16) _Float16 xg[16][232];
    const _Float16* Wp = UwT + (long)n * (NKC * 64 * 8);
    int cl = lane & 15, q = lane >> 4, k8 = q * 8;
    int o0 = wid * 16 + cl;
    f16x8 bfr[7];
#pragma unroll
    for (int ks = 0; ks < 7; ++ks) {
        bool valid = (ks * 4 + q) < NKC;
        const _Float16* p0 = valid ? Wp + (long)((ks * 4 + q) * 64 + o0) * 8 : zp + cl * 8;
        bfr[ks] = *(const f16x8*)p0;
    }
    _Float16* xf = &xg[0][0];
    for (int idx = tid; idx < 16 * 232; idx += 256) xf[idx] = (_Float16)0.f;
    __syncthreads();
    const _Float16* y1p = Y1 + (long)n * NCP;
    const _Float16* y2p = Y2 + (long)n * NCP;
    for (int idx = tid; idx < 16 * KI; idx += 256) {
        int b = idx / KI, kk = idx % KI;
        int k = kk / CC, i = kk % CC;
        int c = b * CC + i;
        float ih;
        if (i == 0) ih = src[((long)b * T_ + t) * N_ + n];
        else {
            long base = ((long)b * N_ + n) * DH + (i - 1);
            ih = (float)h[base] * (float)z[base];
        }
        float val;
        if (k == 0)      val = ih;
        else if (k == 1) val = (float)y1p[c];
        else             val = 2.f * (float)y2p[c] - ih;
        xg[b][kk] = (_Float16)val;
    }
    __syncthreads();
    f32x4 acc0 = {};
#pragma unroll
    for (int ks = 0; ks < 7; ++ks) {
        f16x8 af = *(const f16x8*)&xg[cl][ks * 32 + k8];
        acc0 = __builtin_amdgcn_mfma_f32_16x16x32_f16(af, bfr[ks], acc0, 0, 0, 0);
    }
    int o = o0;
    float bias = Ub[(long)n * 64 + o];
#pragma unroll
    for (int qq = 0; qq < 4; ++qq) {
        int b = q * 4 + qq;
        long base = ((long)b * N_ + n) * DH + o;
        float hc = tanhf(acc0[qq] + bias);
        float rv = (float)rb[base], hv = (float)h[base];
        float hn = rv * hv + (1.f - rv) * hc;
        _Float16 hn16 = (_Float16)hn;
        h[base] = hn16;
        states[(((long)b * T_ + t) * N_ + n) * DH + o] = hn16;
        XT[(long)(b * CC + 1 + o) * N_ + n] = hn16;
        if (o == 0 && t + 1 < T_)
            XT[(long)(b * CC) * N_ + n] = (_Float16)src[((long)b * T_ + t + 1) * N_ + n];
    }
}

// ---------------- qkv projection (MFMA): KV for all t, Q at t=11 ----------------
__global__ __launch_bounds__(256) void k_qkv(const _Float16* __restrict__ st,
        const _Float16* __restrict__ Wi16, const float* __restrict__ bi,
        _Float16* __restrict__ KV, _Float16* __restrict__ Q) {
    int bt = blockIdx.x;
    int nck = blockIdx.y;
    int b = bt / 12, t = bt % 12;
    int tid = threadIdx.x, wid = tid >> 6, lane = tid & 63;
    __shared__ float pe[64];
    __shared__ __align__(16) _Float16 Xs[128][72];
    if (tid < 64) {
        int e = tid;
        float div = __powf(10000.f, -(float)(e & ~1) / 64.f);
        float ang = (float)t * div;
        pe[e] = (e & 1) ? __cosf(ang) : __sinf(ang);
    }
    __syncthreads();
    const _Float16* srcp = st + ((long)(b * T_ + t) * N_ + nck * 128) * DH;
#pragma unroll
    for (int u = 0; u < 4; ++u) {
        int idx = u * 256 + tid;
        int rr = idx >> 3, e0 = (idx & 7) * 8;
        f16x8 v = *(const f16x8*)(srcp + rr * DH + e0);
        f16x8 ov;
#pragma unroll
        for (int q = 0; q < 8; ++q) ov[q] = (_Float16)((float)v[q] + pe[e0 + q]);
        *(f16x8*)&Xs[rr][e0] = ov;
    }
    __syncthreads();
    int cl = lane & 15, ks8 = (lane >> 4) * 8;
    f16x8 bfrag[3][2];
    float bias[3];
#pragma unroll
    for (int j = 0; j < 3; ++j) {
        int c = (wid * 3 + j) * 16 + cl;
#pragma unroll
        for (int ks = 0; ks < 2; ++ks)
            bfrag[j][ks] = *(const f16x8*)(Wi16 + c * 64 + ks * 32 + ks8);
        bias[j] = bi[c];
    }
    f32x4 acc[8][3] = {};
#pragma unroll
    for (int rt = 0; rt < 8; ++rt) {
#pragma unroll
        for (int ks = 0; ks < 2; ++ks) {
            f16x8 af = *(const f16x8*)&Xs[rt * 16 + cl][ks * 32 + ks8];
#pragma unroll
            for (int j = 0; j < 3; ++j)
                acc[rt][j] = __builtin_amdgcn_mfma_f32_16x16x32_f16(af, bfrag[j][ks], acc[rt][j], 0, 0, 0);
        }
    }
    int rowq = (lane >> 4) * 4;
#pragma unroll
    for (int rt = 0; rt < 8; ++rt)
#pragma unroll
        for (int j = 0; j < 3; ++j) {
            int c = (wid * 3 + j) * 16 + cl;
#pragma unroll
            for (int q = 0; q < 4; ++q) {
                int n = nck * 128 + rt * 16 + rowq + q;
                float val = acc[rt][j][q] + bias[j];
                if (c >= 64)
                    KV[(((long)b * N_ + n) * T_ + t) * 128 + (c - 64)] = (_Float16)val;
                else if (t == 11)
                    Q[((long)b * N_ + n) * 64 + c] = (_Float16)val;
            }
        }
}

// ---------------- attention + out-proj: 16 pairs/block, 16 threads/pair ----------------
__global__ __launch_bounds__(256) void k_attn2(const _Float16* __restrict__ KV,
        const _Float16* __restrict__ Q, const _Float16* __restrict__ Wo16,
        const float* __restrict__ bo, float* __restrict__ o1) {
    __shared__ _Float16 kvs[16 * 1544];
    __shared__ float qs[16][64];
    __shared__ float Wos[64][64];
    __shared__ float outb[16][64];
    __shared__ float bos[64];
    int tid = threadIdx.x;
    long pair0 = (long)blockIdx.x * 16;
#pragma unroll
    for (int u = 0; u < 12; ++u) {
        int idx = u * 256 + tid;
        int p = idx / 192, off8 = (idx % 192) * 8;
        *(f16x8*)&kvs[p * 1544 + off8] = *(const f16x8*)(KV + (pair0 + p) * 1536 + off8);
    }
    if (tid < 64) bos[tid] = bo[tid];
    for (int idx = tid; idx < 1024; idx += 256) {
        int p = idx >> 6, j = idx & 63;
        qs[p][j] = (float)Q[(pair0 + p) * 64 + j];
    }
    for (int idx = tid; idx < 4096; idx += 256) {
        int c = idx >> 6, j = idx & 63;
        Wos[c][j] = (float)Wo16[j * 64 + c];
    }
    __syncthreads();
    int p = tid >> 4, i = tid & 15;
    int h = i >> 2, sg = i & 3;
    const _Float16* kvp = &kvs[p * 1544];
    float att3[3], mx = -1e30f;
#pragma unroll
    for (int j = 0; j < 3; ++j) {
        int s = sg + 4 * j;
        float sc = 0.f;
#pragma unroll
        for (int d = 0; d < 16; ++d)
            sc = fmaf(qs[p][h * 16 + d], (float)kvp[s * 128 + h * 16 + d], sc);
        att3[j] = sc * 0.25f;
        mx = fmaxf(mx, att3[j]);
    }
    mx = fmaxf(mx, __shfl_xor(mx, 1));
    mx = fmaxf(mx, __shfl_xor(mx, 2));
    float se = 0.f;
#pragma unroll
    for (int j = 0; j < 3; ++j) { att3[j] = __expf(att3[j] - mx); se += att3[j]; }
    se += __shfl_xor(se, 1);
    se += __shfl_xor(se, 2);
    float inv = 1.f / se;
#pragma unroll
    for (int j = 0; j < 3; ++j) att3[j] *= inv;
    int c0 = i * 4;
    float out4[4] = {0.f, 0.f, 0.f, 0.f};
#pragma unroll
    for (int m = 0; m < 4; ++m) {
        float a0 = __shfl_xor(att3[0], m);
        float a1 = __shfl_xor(att3[1], m);
        float a2 = __shfl_xor(att3[2], m);
        int sb = sg ^ m;
        float aj[3] = {a0, a1, a2};
#pragma unroll
        for (int j = 0; j < 3; ++j) {
            int s = sb + 4 * j;
            f16x4 vv = *(const f16x4*)&kvp[s * 128 + 64 + c0];
#pragma unroll
            for (int q = 0; q < 4; ++q) out4[q] = fmaf(aj[j], (float)vv[q], out4[q]);
        }
    }
    *(float4*)&outb[p][c0] = *(float4*)out4;
    __syncthreads();
    float res[4];
#pragma unroll
    for (int q = 0; q < 4; ++q) res[q] = bos[c0 + q];
    for (int c = 0; c < 64; ++c) {
        float oc = outb[p][c];
        float4 wv = *(const float4*)&Wos[c][c0];
        res[0] = fmaf(oc, wv.x, res[0]);
        res[1] = fmaf(oc, wv.y, res[1]);
        res[2] = fmaf(oc, wv.z, res[2]);
        res[3] = fmaf(oc, wv.w, res[3]);
    }
    *(float4*)&o1[(pair0 + p) * 64 + c0] = make_float4(res[0], res[1], res[2], res[3]);
}

// ---------------- output head ----------------
__global__ __launch_bounds__(256) void k_final(const float* __restrict__ o1,
        const _Float16* __restrict__ hT, const float* __restrict__ cw,
        const float* __restrict__ convw, const float* __restrict__ convb,
        float* __restrict__ out) {
    __shared__ float Ws[12 * 3 * 64];
    __shared__ float cbs[12];
    int tid = threadIdx.x;
    for (int idx = tid; idx < 12 * 3 * 64; idx += 256) Ws[idx] = convw[idx];
    if (tid < 12) cbs[tid] = convb[tid];
    __syncthreads();
    float c0 = cw[0], c1 = cw[1], c2 = cw[2];
    int g = tid >> 6, j = tid & 63;
    int bn = blockIdx.x * 4 + g;
    int b = bn >> 11, n = bn & 2047;
    float x1 = o1[(long)bn * DH + j];
    float x3 = (float)hT[(long)bn * DH + j];
    float myout = 0.f;
#pragma unroll
    for (int oc = 0; oc < 12; ++oc) {
        float p = x1 * c0 * Ws[(oc * 3 + 0) * 64 + j]
                + x3 * (c1 * Ws[(oc * 3 + 1) * 64 + j] + c2 * Ws[(oc * 3 + 2) * 64 + j]);
        p += __shfl_xor(p, 1); p += __shfl_xor(p, 2); p += __shfl_xor(p, 4);
        p += __shfl_xor(p, 8); p += __shfl_xor(p, 16); p += __shfl_xor(p, 32);
        if (j == oc) myout = p + cbs[oc];
    }
    if (j < 12) out[((long)b * 12 + j) * N_ + n] = myout;
}

extern "C" void kernel_launch(void* const* d_in, const int* in_sizes, int n_in,
                              void* d_out, int out_size, void* d_ws, size_t ws_size,
                              hipStream_t stream) {
    const float* src    = (const float*)d_in[0];
    const float* emb    = (const float*)d_in[2];
    const float* gate_w = (const float*)d_in[3];
    const float* gate_b = (const float*)d_in[4];
    const float* upd_w  = (const float*)d_in[5];
    const float* upd_b  = (const float*)d_in[6];
    const float* a_in_w = (const float*)d_in[7];
    const float* a_in_b = (const float*)d_in[8];
    const float* a_out_w= (const float*)d_in[9];
    const float* a_out_b= (const float*)d_in[10];
    const float* chan_w = (const float*)d_in[11];
    const float* conv_w = (const float*)d_in[12];
    const float* conv_b = (const float*)d_in[13];
    float* out = (float*)d_out;

    char* ws = (char*)d_ws;
    size_t off = 0;
    auto alloc = [&](size_t bytes) { char* p = ws + off; off += (bytes + 255) & ~size_t(255); return p; };
    _Float16* A    = (_Float16*)alloc((size_t)N_ * N_ * 2);
    _Float16* A2   = (_Float16*)alloc((size_t)N_ * N_ * 2);
    _Float16* GwT  = (_Float16*)alloc((size_t)N_ * NKC * 128 * 8 * 2);   // 104.9 MB
    float*  Gb     = (float*) alloc((size_t)N_ * 128 * 4);
    _Float16* UwT  = (_Float16*)alloc((size_t)N_ * NKC * 64 * 8 * 2);    // 52.4 MB
    float*  Ub     = (float*) alloc((size_t)N_ * 64 * 4);
    _Float16* XT   = (_Float16*)alloc((size_t)NCP * N_ * 2);
    _Float16* Y1   = (_Float16*)alloc((size_t)N_ * NCP * 2);   // node-major [n][c]
    _Float16* Y2   = (_Float16*)alloc((size_t)N_ * NCP * 2);   // node-major [n][c]
    _Float16* h    = (_Float16*)alloc((size_t)B_ * N_ * DH * 2);
    _Float16* zbuf = (_Float16*)alloc((size_t)B_ * N_ * DH * 2);
    _Float16* rbuf = (_Float16*)alloc((size_t)B_ * N_ * DH * 2);
    _Float16* stt  = (_Float16*)alloc((size_t)B_ * T_ * N_ * DH * 2);
    _Float16* Wi16 = (_Float16*)alloc(192 * 64 * 2);
    _Float16* Wo16 = (_Float16*)alloc(64 * 64 * 2);
    _Float16* zp   = (_Float16*)alloc(512);
    if (off > ws_size) return;   // ~252 MB total

    // transient/dead-region aliases
    _Float16* AT = stt;                            // 8.4 MB scratch (stt unwritten at setup)
    _Float16* KV = GwT;                            // 100.7 MB into GwT's 104.9 MB
    _Float16* Qb = UwT;                            // 4.2 MB at UwT start
    float*    o1 = (float*)((char*)UwT + (8u << 20)); // 8.4 MB at UwT+8MB

    hipMemsetAsync(h, 0, (size_t)B_ * N_ * DH * 2, stream);
    hipMemsetAsync(XT, 0, (size_t)NCP * N_ * 2, stream);
    hipMemsetAsync(zp, 0, 512, stream);
    k_compA<<<N_, 256, 0, stream>>>(emb, A);
    dim3 tgrid(32, 32);
    k_transp<<<tgrid, 256, 0, stream>>>(A, AT);
    k_gemm<<<tgrid, 256, 0, stream>>>(AT, A, A2);   // A2 = (1024*A^2), Aop=AT BT=A
    k_build<<<816, 256, 0, stream>>>(emb, gate_w, gate_b, upd_w, upd_b, GwT, Gb, UwT, Ub);
    k_wcvt<<<48, 256, 0, stream>>>(a_in_w, a_out_w, Wi16, Wo16);
    k_initx<<<128, 256, 0, stream>>>(src, XT);

    dim3 ggrid(16, 17, 2);
    for (int t = 0; t < T_; ++t) {
        k_gemm2<<<ggrid, 256, 0, stream>>>(A, A2, XT, Y1, Y2);
        k_apply_gate<<<N_, 256, 0, stream>>>(src, h, Y1, Y2, GwT, Gb, t, zbuf, rbuf, XT, zp);
        k_gemm2<<<ggrid, 256, 0, stream>>>(A, A2, XT, Y1, Y2);
        k_apply_update<<<N_, 256, 0, stream>>>(src, h, Y1, Y2, UwT, Ub, zbuf, rbuf, t, stt, XT, zp);
    }
    dim3 qgrid(192, 16);
    k_qkv<<<qgrid, 256, 0, stream>>>(stt, Wi16, a_in_b, KV, Qb);
    k_attn2<<<2048, 256, 0, stream>>>(KV, Qb, Wo16, a_out_b, o1);
    k_final<<<8192, 256, 0, stream>>>(o1, h, chan_w, conv_w, conv_b, out);
}

// Round 19
// 1945.942 us; speedup vs baseline: 1.3127x; 1.0018x over previous
//
#include <hip/hip_runtime.h>
#include <hip/hip_bf16.h>

typedef _Float16 f16x8 __attribute__((ext_vector_type(8)));
typedef _Float16 f16x4 __attribute__((ext_vector_type(4)));
typedef float f32x4 __attribute__((ext_vector_type(4)));
typedef unsigned short us8 __attribute__((ext_vector_type(8)));
typedef unsigned short us4 __attribute__((ext_vector_type(4)));

#define N_ 2048
#define B_ 16
#define T_ 12
#define DH 64
#define CC 65      // DIN + DOUT
#define NC 1040    // B_*CC
#define NCP 1088   // padded col count (17*64)
#define KI 195     // K*CC
#define NKC 25     // kk-chunks of 8 (200 slots, kk>=195 zero)
#define EDIM 10
#define ASCALE 1024.0f
#define AINV (1.0f / 1024.0f)

// ---------------- A = softmax(relu(E E^T)) rowwise, f16 scaled by 1024 ----------------
__global__ __launch_bounds__(256) void k_compA(const float* __restrict__ emb,
                                               _Float16* __restrict__ A) {
    int n = blockIdx.x, tid = threadIdx.x;
    float en[EDIM];
#pragma unroll
    for (int d = 0; d < EDIM; ++d) en[d] = emb[n * EDIM + d];
    float v[8], mx = -1e30f;
#pragma unroll
    for (int j = 0; j < 8; ++j) {
        int m = tid + j * 256;
        float acc = 0.f;
#pragma unroll
        for (int d = 0; d < EDIM; ++d) acc = fmaf(en[d], emb[m * EDIM + d], acc);
        acc = fmaxf(acc, 0.f);
        v[j] = acc; mx = fmaxf(mx, acc);
    }
    __shared__ float red[256];
    red[tid] = mx; __syncthreads();
    for (int s = 128; s > 0; s >>= 1) { if (tid < s) red[tid] = fmaxf(red[tid], red[tid + s]); __syncthreads(); }
    mx = red[0]; __syncthreads();
    float se = 0.f;
#pragma unroll
    for (int j = 0; j < 8; ++j) { v[j] = __expf(v[j] - mx); se += v[j]; }
    red[tid] = se; __syncthreads();
    for (int s = 128; s > 0; s >>= 1) { if (tid < s) red[tid] += red[tid + s]; __syncthreads(); }
    float inv = ASCALE / red[0];
#pragma unroll
    for (int j = 0; j < 8; ++j) A[(long)n * N_ + tid + j * 256] = (_Float16)(v[j] * inv);
}

// ---------------- transpose A -> AT (64x64 LDS tiles) ----------------
__global__ __launch_bounds__(256) void k_transp(const _Float16* __restrict__ A,
                                                _Float16* __restrict__ AT) {
    __shared__ _Float16 tile[64][72];
    int bx = blockIdx.x, by = blockIdx.y;
    int tid = threadIdx.x;
    int r8 = tid >> 3, c8 = (tid & 7) * 8;
#pragma unroll
    for (int p = 0; p < 2; ++p) {
        int r = p * 32 + r8;
        *(f16x8*)&tile[r][c8] = *(const f16x8*)(A + (long)(by * 64 + r) * N_ + bx * 64 + c8);
    }
    __syncthreads();
#pragma unroll
    for (int p = 0; p < 2; ++p) {
        int r = p * 32 + r8;
        f16x8 v;
#pragma unroll
        for (int q = 0; q < 8; ++q) v[q] = tile[c8 + q][r];
        *(f16x8*)(AT + (long)(bx * 64 + r) * N_ + by * 64 + c8) = v;
    }
}

// ---------------- per-node GRU weights, MFMA-fragment order, o-major ----------------
__global__ __launch_bounds__(256) void k_build(const float* __restrict__ emb,
        const float* __restrict__ gw, const float* __restrict__ gb,
        const float* __restrict__ uw, const float* __restrict__ ub,
        _Float16* __restrict__ GwT, float* __restrict__ Gb,
        _Float16* __restrict__ UwT, float* __restrict__ Ub) {
    int bid = blockIdx.x;
    int tid = threadIdx.x;
    if (bid < 800) {
        __shared__ float embs[128][EDIM];
        int isupd = bid >= 400;
        int b2 = isupd ? bid - 400 : bid;
        int kkc = b2 >> 4, nch = b2 & 15;
        for (int idx = tid; idx < 128 * EDIM; idx += 256)
            embs[idx / EDIM][idx % EDIM] = emb[(nch * 128 + idx / EDIM) * EDIM + idx % EDIM];
        __syncthreads();
        if (!isupd) {
            int o = tid >> 1, jh = (tid & 1) * 4;
            float w[EDIM][4];
#pragma unroll
            for (int d = 0; d < EDIM; ++d)
#pragma unroll
                for (int jj = 0; jj < 4; ++jj) {
                    int kk = kkc * 8 + jh + jj;
                    w[d][jj] = (kk < KI) ? gw[(long)d * (KI * 128) + (long)kk * 128 + o] : 0.f;
                }
            for (int i = 0; i < 128; ++i) {
                int n = nch * 128 + i;
                float a0 = 0.f, a1 = 0.f, a2 = 0.f, a3 = 0.f;
#pragma unroll
                for (int d = 0; d < EDIM; ++d) {
                    float ed = embs[i][d];
                    a0 = fmaf(ed, w[d][0], a0); a1 = fmaf(ed, w[d][1], a1);
                    a2 = fmaf(ed, w[d][2], a2); a3 = fmaf(ed, w[d][3], a3);
                }
                us4 pk;
                pk[0] = __builtin_bit_cast(unsigned short, (_Float16)a0);
                pk[1] = __builtin_bit_cast(unsigned short, (_Float16)a1);
                pk[2] = __builtin_bit_cast(unsigned short, (_Float16)a2);
                pk[3] = __builtin_bit_cast(unsigned short, (_Float16)a3);
                *(us4*)(GwT + ((long)n * NKC + kkc) * 1024 + o * 8 + jh) = pk;
            }
        } else {
            int sub = tid >> 7, o = (tid >> 1) & 63, jh = (tid & 1) * 4;
            float w[EDIM][4];
#pragma unroll
            for (int d = 0; d < EDIM; ++d)
#pragma unroll
                for (int jj = 0; jj < 4; ++jj) {
                    int kk = kkc * 8 + jh + jj;
                    w[d][jj] = (kk < KI) ? uw[(long)d * (KI * 64) + (long)kk * 64 + o] : 0.f;
                }
            for (int i = 0; i < 64; ++i) {
                int il = i * 2 + sub;
                int n = nch * 128 + il;
                float a0 = 0.f, a1 = 0.f, a2 = 0.f, a3 = 0.f;
#pragma unroll
                for (int d = 0; d < EDIM; ++d) {
                    float ed = embs[il][d];
                    a0 = fmaf(ed, w[d][0], a0); a1 = fmaf(ed, w[d][1], a1);
                    a2 = fmaf(ed, w[d][2], a2); a3 = fmaf(ed, w[d][3], a3);
                }
                us4 pk;
                pk[0] = __builtin_bit_cast(unsigned short, (_Float16)a0);
                pk[1] = __builtin_bit_cast(unsigned short, (_Float16)a1);
                pk[2] = __builtin_bit_cast(unsigned short, (_Float16)a2);
                pk[3] = __builtin_bit_cast(unsigned short, (_Float16)a3);
                *(us4*)(UwT + ((long)n * NKC + kkc) * 512 + o * 8 + jh) = pk;
            }
        }
    } else {
        int bb = bid - 800;
        const int CHUNK = (2048 * 128 + 2048 * 64) / 16;   // 24576
        for (int idx = bb * CHUNK + tid; idx < (bb + 1) * CHUNK; idx += 256) {
            if (idx < 2048 * 128) {
                int n = idx >> 7, o = idx & 127;
                float a = 0.f;
#pragma unroll
                for (int d = 0; d < EDIM; ++d) a = fmaf(emb[n * EDIM + d], gb[d * 128 + o], a);
                Gb[idx] = a;
            } else {
                int i2 = idx - 2048 * 128;
                int n = i2 >> 6, o = i2 & 63;
                float a = 0.f;
#pragma unroll
                for (int d = 0; d < EDIM; ++d) a = fmaf(emb[n * EDIM + d], ub[d * 64 + o], a);
                Ub[i2] = a;
            }
        }
    }
}

// ---------------- tiny: f16 copies of attn weights ----------------
__global__ __launch_bounds__(256) void k_wcvt(const float* __restrict__ Wi,
        const float* __restrict__ Wo, _Float16* __restrict__ Wi16,
        _Float16* __restrict__ Wo16) {
    int idx = blockIdx.x * 256 + threadIdx.x;
    if (idx < 192 * 64) Wi16[idx] = (_Float16)Wi[idx];
    if (idx < 64 * 64) Wo16[idx] = (_Float16)Wo[idx];
}

// ---------------- tiny: XT x-row for t=0 ----------------
__global__ __launch_bounds__(256) void k_initx(const float* __restrict__ src,
        _Float16* __restrict__ XT) {
    int idx = blockIdx.x * 256 + threadIdx.x;   // b*2048+n
    int b = idx >> 11, n = idx & 2047;
    XT[((long)b * CC) * N_ + n] = (_Float16)src[((long)b * T_) * N_ + n];
}

// ---------------- GEMM core (c-major epilogue, for A2 precompute) ----------------
__device__ __forceinline__ f16x8 lds_frag(const _Float16* base, int r, int kb) {
    int byt = r * 128 + ((kb * 2) ^ ((r & 7) << 4));
    return *(const f16x8*)((const char*)base + byt);
}

__global__ __launch_bounds__(256) void k_gemm(const _Float16* __restrict__ Aop,
        const _Float16* __restrict__ BT, _Float16* __restrict__ DT) {
    __shared__ __align__(16) _Float16 As[3 * 4096];
    __shared__ __align__(16) _Float16 Bs[3 * 4096];
    int bm = blockIdx.x, bc = blockIdx.y, tid = threadIdx.x;
    int wid = tid >> 6, lane = tid & 63;
    int row_g = bm * 64, col_g = bc * 64;
    int r0 = (wid & 1) * 32, c0 = (wid >> 1) * 32;
    int lr8 = lane >> 3;
    int lsw = 8 * ((lane & 7) ^ lr8);
    long aoff[2], boff[2];
    int ldo[2];
#pragma unroll
    for (int i = 0; i < 2; ++i) {
        aoff[i] = (long)(row_g + wid * 16 + i * 8 + lr8) * N_ + lsw;
        boff[i] = (long)(col_g + wid * 16 + i * 8 + lr8) * N_ + lsw;
        ldo[i] = (wid * 16 + i * 8) * 64;
    }
    auto stage = [&](int buf, int kt) {
        int k0 = kt * 64;
#pragma unroll
        for (int i = 0; i < 2; ++i)
            __builtin_amdgcn_global_load_lds(
                (const __attribute__((address_space(1))) void*)(Aop + aoff[i] + k0),
                (__attribute__((address_space(3))) void*)&As[buf * 4096 + ldo[i]], 16, 0, 0);
#pragma unroll
        for (int i = 0; i < 2; ++i)
            __builtin_amdgcn_global_load_lds(
                (const __attribute__((address_space(1))) void*)(BT + boff[i] + k0),
                (__attribute__((address_space(3))) void*)&Bs[buf * 4096 + ldo[i]], 16, 0, 0);
    };
    f32x4 acc[2][2] = {};
    const int NT = 32;
    stage(0, 0); stage(1, 1);
    int buf = 0;
    for (int kt = 0; kt < NT; ++kt) {
        if (kt + 2 < NT) { stage((buf + 2) % 3, kt + 2); asm volatile("s_waitcnt vmcnt(8)" ::: "memory"); }
        else if (kt + 1 < NT) { asm volatile("s_waitcnt vmcnt(4)" ::: "memory"); }
        else { asm volatile("s_waitcnt vmcnt(0)" ::: "memory"); }
        __builtin_amdgcn_s_barrier();
        const _Float16* Ab = As + buf * 4096;
        const _Float16* Bb = Bs + buf * 4096;
#pragma unroll
        for (int kk = 0; kk < 64; kk += 32) {
            int kb = kk + (lane >> 4) * 8;
            f16x8 af0 = lds_frag(Ab, r0 + (lane & 15), kb);
            f16x8 af1 = lds_frag(Ab, r0 + 16 + (lane & 15), kb);
            f16x8 bf0 = lds_frag(Bb, c0 + (lane & 15), kb);
            f16x8 bf1 = lds_frag(Bb, c0 + 16 + (lane & 15), kb);
            acc[0][0] = __builtin_amdgcn_mfma_f32_16x16x32_f16(af0, bf0, acc[0][0], 0, 0, 0);
            acc[0][1] = __builtin_amdgcn_mfma_f32_16x16x32_f16(af0, bf1, acc[0][1], 0, 0, 0);
            acc[1][0] = __builtin_amdgcn_mfma_f32_16x16x32_f16(af1, bf0, acc[1][0], 0, 0, 0);
            acc[1][1] = __builtin_amdgcn_mfma_f32_16x16x32_f16(af1, bf1, acc[1][1], 0, 0, 0);
        }
        asm volatile("s_waitcnt lgkmcnt(0)" ::: "memory");
        __builtin_amdgcn_s_barrier();
        buf = (buf + 1) % 3;
    }
#pragma unroll
    for (int rt = 0; rt < 2; ++rt)
#pragma unroll
        for (int ct = 0; ct < 2; ++ct) {
            int cg = col_g + c0 + ct * 16 + (lane & 15);
            int ng = row_g + r0 + rt * 16 + ((lane >> 4) << 2);
            us4 pk;
#pragma unroll
            for (int q = 0; q < 4; ++q) pk[q] = __builtin_bit_cast(unsigned short, (_Float16)(acc[rt][ct][q] * AINV));
            *(us4*)(DT + (long)cg * N_ + ng) = pk;
        }
}

// fused dual dispatch, 128-ROW tile (z: 0=A->Y1, 1=A2->Y2), node-major epilogue
// grid (16, 17, 2) = 544 blocks; LDS 48KB (2-buf); 16 MFMA/wave/K-step
// epilogue staged through LDS for full-128B-line stores
__global__ __launch_bounds__(256) void k_gemm2(const _Float16* __restrict__ A,
        const _Float16* __restrict__ A2, const _Float16* __restrict__ BT,
        _Float16* __restrict__ Y1, _Float16* __restrict__ Y2) {
    __shared__ __align__(16) _Float16 As[2 * 8192];
    __shared__ __align__(16) _Float16 Bs[2 * 4096];
    const _Float16* Aop = blockIdx.z ? A2 : A;
    _Float16* Yn = blockIdx.z ? Y2 : Y1;
    int bm = blockIdx.x, bc = blockIdx.y, tid = threadIdx.x;
    int wid = tid >> 6, lane = tid & 63;
    int row_g = bm * 128, col_g = bc * 64;
    int r0 = (wid & 1) * 64, c0 = (wid >> 1) * 32;
    int lr8 = lane >> 3;
    int lsw = 8 * ((lane & 7) ^ lr8);
    long aoff[4], boff[2];
    int lao[4], lbo[2];
#pragma unroll
    for (int i = 0; i < 4; ++i) {
        aoff[i] = (long)(row_g + wid * 32 + i * 8 + lr8) * N_ + lsw;
        lao[i] = (wid * 32 + i * 8) * 64;
    }
#pragma unroll
    for (int i = 0; i < 2; ++i) {
        boff[i] = (long)(col_g + wid * 16 + i * 8 + lr8) * N_ + lsw;
        lbo[i] = (wid * 16 + i * 8) * 64;
    }
    auto stage = [&](int buf, int kt) {
        int k0 = kt * 64;
#pragma unroll
        for (int i = 0; i < 4; ++i)
            __builtin_amdgcn_global_load_lds(
                (const __attribute__((address_space(1))) void*)(Aop + aoff[i] + k0),
                (__attribute__((address_space(3))) void*)&As[buf * 8192 + lao[i]], 16, 0, 0);
#pragma unroll
        for (int i = 0; i < 2; ++i)
            __builtin_amdgcn_global_load_lds(
                (const __attribute__((address_space(1))) void*)(BT + boff[i] + k0),
                (__attribute__((address_space(3))) void*)&Bs[buf * 4096 + lbo[i]], 16, 0, 0);
    };
    f32x4 acc[4][2] = {};
    const int NT = 32;
    stage(0, 0);
    for (int kt = 0; kt < NT; ++kt) {
        int buf = kt & 1;
        if (kt + 1 < NT) {
            stage(buf ^ 1, kt + 1);
            asm volatile("s_waitcnt vmcnt(6)" ::: "memory");
        } else {
            asm volatile("s_waitcnt vmcnt(0)" ::: "memory");
        }
        __builtin_amdgcn_s_barrier();
        const _Float16* Ab = As + buf * 8192;
        const _Float16* Bb = Bs + buf * 4096;
#pragma unroll
        for (int kk = 0; kk < 64; kk += 32) {
            int kb = kk + (lane >> 4) * 8;
            f16x8 bf0 = lds_frag(Bb, c0 + (lane & 15), kb);
            f16x8 bf1 = lds_frag(Bb, c0 + 16 + (lane & 15), kb);
#pragma unroll
            for (int rt = 0; rt < 4; ++rt) {
                f16x8 af = lds_frag(Ab, r0 + rt * 16 + (lane & 15), kb);
                acc[rt][0] = __builtin_amdgcn_mfma_f32_16x16x32_f16(af, bf0, acc[rt][0], 0, 0, 0);
                acc[rt][1] = __builtin_amdgcn_mfma_f32_16x16x32_f16(af, bf1, acc[rt][1], 0, 0, 0);
            }
        }
        asm volatile("s_waitcnt lgkmcnt(0)" ::: "memory");
        __builtin_amdgcn_s_barrier();
    }
    // epilogue: stage C into LDS (reuse As; safe after final barrier), then
    // 128B-coalesced node-major stores: each row's 64 f16 = 128B by 8 lanes
    _Float16* Cs = As;                  // 128 x 72 pad = 18.4KB
#pragma unroll
    for (int rt = 0; rt < 4; ++rt)
#pragma unroll
        for (int ct = 0; ct < 2; ++ct) {
            int cl2 = c0 + ct * 16 + (lane & 15);
            int nl = r0 + rt * 16 + ((lane >> 4) << 2);
#pragma unroll
            for (int q = 0; q < 4; ++q)
                Cs[(nl + q) * 72 + cl2] = (_Float16)(acc[rt][ct][q] * AINV);
        }
    __syncthreads();
#pragma unroll
    for (int pass = 0; pass < 4; ++pass) {
        int row = pass * 32 + (tid >> 3);
        int col8 = (tid & 7) * 8;
        *(f16x8*)(Yn + (long)(row_g + row) * NCP + col_g + col8) =
            *(const f16x8*)&Cs[row * 72 + col8];
    }
}

// ---------------- gate apply (coalesced node-major staging) ----------------
__global__ __launch_bounds__(256) void k_apply_gate(const float* __restrict__ src,
        const _Float16* __restrict__ h, const _Float16* __restrict__ Y1,
        const _Float16* __restrict__ Y2, const _Float16* __restrict__ GwT,
        const float* __restrict__ Gb, int t,
        _Float16* __restrict__ z, _Float16* __restrict__ r, _Float16* __restrict__ XT,
        const _Float16* __restrict__ zp) {
    int n = blockIdx.x, tid = threadIdx.x, wid = tid >> 6, lane = tid & 63;
    __shared__ __align__(16) _Float16 xg[16][232];
    const _Float16* Wp = GwT + (long)n * (NKC * 128 * 8);
    int cl = lane & 15, q = lane >> 4, k8 = q * 8;
    int o0 = wid * 32 + cl, o1 = o0 + 16;
    f16x8 bfr0[7], bfr1[7];
#pragma unroll
    for (int ks = 0; ks < 7; ++ks) {
        bool valid = (ks * 4 + q) < NKC;
        const _Float16* p0 = valid ? Wp + (long)((ks * 4 + q) * 128 + o0) * 8 : zp + cl * 8;
        const _Float16* p1 = valid ? Wp + (long)((ks * 4 + q) * 128 + o1) * 8 : zp + cl * 8 + 128;
        bfr0[ks] = *(const f16x8*)p0;
        bfr1[ks] = *(const f16x8*)p1;
    }
    _Float16* xf = &xg[0][0];
    for (int idx = tid; idx < 16 * 232; idx += 256) xf[idx] = (_Float16)0.f;
    __syncthreads();
    const _Float16* y1p = Y1 + (long)n * NCP;
    const _Float16* y2p = Y2 + (long)n * NCP;
    for (int idx = tid; idx < 16 * KI; idx += 256) {
        int b = idx / KI, kk = idx % KI;
        int k = kk / CC, i = kk % CC;
        int c = b * CC + i;
        float ih = (i == 0) ? src[((long)b * T_ + t) * N_ + n]
                            : (float)h[((long)b * N_ + n) * DH + (i - 1)];
        float val;
        if (k == 0)      val = ih;
        else if (k == 1) val = (float)y1p[c];
        else             val = 2.f * (float)y2p[c] - ih;
        xg[b][kk] = (_Float16)val;
    }
    __syncthreads();
    f32x4 acc0 = {}, acc1 = {};
#pragma unroll
    for (int ks = 0; ks < 7; ++ks) {
        f16x8 af = *(const f16x8*)&xg[cl][ks * 32 + k8];
        acc0 = __builtin_amdgcn_mfma_f32_16x16x32_f16(af, bfr0[ks], acc0, 0, 0, 0);
        acc1 = __builtin_amdgcn_mfma_f32_16x16x32_f16(af, bfr1[ks], acc1, 0, 0, 0);
    }
#pragma unroll
    for (int tl = 0; tl < 2; ++tl) {
        f32x4 acc = tl ? acc1 : acc0;
        int o = wid * 32 + tl * 16 + cl;
        float bias = Gb[(long)n * 128 + o];
#pragma unroll
        for (int qq = 0; qq < 4; ++qq) {
            int b = q * 4 + qq;
            float sv = 1.f / (1.f + __expf(-(acc[qq] + bias)));
            long base = ((long)b * N_ + n) * DH;
            if (o < 64) {
                z[base + o] = (_Float16)sv;
                XT[(long)(b * CC + 1 + o) * N_ + n] = (_Float16)(sv * (float)h[base + o]);
            } else {
                r[base + (o - 64)] = (_Float16)sv;
            }
        }
    }
}

// ---------------- update apply (coalesced node-major staging) ----------------
__global__ __launch_bounds__(256) void k_apply_update(const float* __restrict__ src,
        _Float16* __restrict__ h, const _Float16* __restrict__ Y1,
        const _Float16* __restrict__ Y2, const _Float16* __restrict__ UwT,
        const float* __restrict__ Ub, const _Float16* __restrict__ z,
        const _Float16* __restrict__ rb, int t, _Float16* __restrict__ states,
        _Float16* __restrict__ XT, const _Float16* __restrict__ zp) {
    int n = blockIdx.x, tid = threadIdx.x, wid = tid >> 6, lane = tid & 63;
    __shared__ __align__(16) _Float16 xg[16][232];
    const _Float16* Wp = UwT + (long)n * (NKC * 64 * 8);
    int cl = lane & 15, q = lane >> 4, k8 = q * 8;
    int o0 = wid * 16 + cl;
    f16x8 bfr[7];
#pragma unroll
    for (int ks = 0; ks < 7; ++ks) {
        bool valid = (ks * 4 + q) < NKC;
        const _Float16* p0 = valid ? Wp + (long)((ks * 4 + q) * 64 + o0) * 8 : zp + cl * 8;
        bfr[ks] = *(const f16x8*)p0;
    }
    _Float16* xf = &xg[0][0];
    for (int idx = tid; idx < 16 * 232; idx += 256) xf[idx] = (_Float16)0.f;
    __syncthreads();
    const _Float16* y1p = Y1 + (long)n * NCP;
    const _Float16* y2p = Y2 + (long)n * NCP;
    for (int idx = tid; idx < 16 * KI; idx += 256) {
        int b = idx / KI, kk = idx % KI;
        int k = kk / CC, i = kk % CC;
        int c = b * CC + i;
        float ih;
        if (i == 0) ih = src[((long)b * T_ + t) * N_ + n];
        else {
            long base = ((long)b * N_ + n) * DH + (i - 1);
            ih = (float)h[base] * (float)z[base];
        }
        float val;
        if (k == 0)      val = ih;
        else if (k == 1) val = (float)y1p[c];
        else             val = 2.f * (float)y2p[c] - ih;
        xg[b][kk] = (_Float16)val;
    }
    __syncthreads();
    f32x4 acc0 = {};
#pragma unroll
    for (int ks = 0; ks < 7; ++ks) {
        f16x8 af = *(const f16x8*)&xg[cl][ks * 32 + k8];
        acc0 = __builtin_amdgcn_mfma_f32_16x16x32_f16(af, bfr[ks], acc0, 0, 0, 0);
    }
    int o = o0;
    float bias = Ub[(long)n * 64 + o];
#pragma unroll
    for (int qq = 0; qq < 4; ++qq) {
        int b = q * 4 + qq;
        long base = ((long)b * N_ + n) * DH + o;
        float hc = tanhf(acc0[qq] + bias);
        float rv = (float)rb[base], hv = (float)h[base];
        float hn = rv * hv + (1.f - rv) * hc;
        _Float16 hn16 = (_Float16)hn;
        h[base] = hn16;
        states[(((long)b * T_ + t) * N_ + n) * DH + o] = hn16;
        XT[(long)(b * CC + 1 + o) * N_ + n] = hn16;
        if (o == 0 && t + 1 < T_)
            XT[(long)(b * CC) * N_ + n] = (_Float16)src[((long)b * T_ + t + 1) * N_ + n];
    }
}

// ---------------- qkv projection (MFMA): KV for all t, Q at t=11 ----------------
__global__ __launch_bounds__(256) void k_qkv(const _Float16* __restrict__ st,
        const _Float16* __restrict__ Wi16, const float* __restrict__ bi,
        _Float16* __restrict__ KV, _Float16* __restrict__ Q) {
    int bt = blockIdx.x;
    int nck = blockIdx.y;
    int b = bt / 12, t = bt % 12;
    int tid = threadIdx.x, wid = tid >> 6, lane = tid & 63;
    __shared__ float pe[64];
    __shared__ __align__(16) _Float16 Xs[128][72];
    if (tid < 64) {
        int e = tid;
        float div = __powf(10000.f, -(float)(e & ~1) / 64.f);
        float ang = (float)t * div;
        pe[e] = (e & 1) ? __cosf(ang) : __sinf(ang);
    }
    __syncthreads();
    const _Float16* srcp = st + ((long)(b * T_ + t) * N_ + nck * 128) * DH;
#pragma unroll
    for (int u = 0; u < 4; ++u) {
        int idx = u * 256 + tid;
        int rr = idx >> 3, e0 = (idx & 7) * 8;
        f16x8 v = *(const f16x8*)(srcp + rr * DH + e0);
        f16x8 ov;
#pragma unroll
        for (int q = 0; q < 8; ++q) ov[q] = (_Float16)((float)v[q] + pe[e0 + q]);
        *(f16x8*)&Xs[rr][e0] = ov;
    }
    __syncthreads();
    int cl = lane & 15, ks8 = (lane >> 4) * 8;
    f16x8 bfrag[3][2];
    float bias[3];
#pragma unroll
    for (int j = 0; j < 3; ++j) {
        int c = (wid * 3 + j) * 16 + cl;
#pragma unroll
        for (int ks = 0; ks < 2; ++ks)
            bfrag[j][ks] = *(const f16x8*)(Wi16 + c * 64 + ks * 32 + ks8);
        bias[j] = bi[c];
    }
    f32x4 acc[8][3] = {};
#pragma unroll
    for (int rt = 0; rt < 8; ++rt) {
#pragma unroll
        for (int ks = 0; ks < 2; ++ks) {
            f16x8 af = *(const f16x8*)&Xs[rt * 16 + cl][ks * 32 + ks8];
#pragma unroll
            for (int j = 0; j < 3; ++j)
                acc[rt][j] = __builtin_amdgcn_mfma_f32_16x16x32_f16(af, bfrag[j][ks], acc[rt][j], 0, 0, 0);
        }
    }
    int rowq = (lane >> 4) * 4;
#pragma unroll
    for (int rt = 0; rt < 8; ++rt)
#pragma unroll
        for (int j = 0; j < 3; ++j) {
            int c = (wid * 3 + j) * 16 + cl;
#pragma unroll
            for (int q = 0; q < 4; ++q) {
                int n = nck * 128 + rt * 16 + rowq + q;
                float val = acc[rt][j][q] + bias[j];
                if (c >= 64)
                    KV[(((long)b * N_ + n) * T_ + t) * 128 + (c - 64)] = (_Float16)val;
                else if (t == 11)
                    Q[((long)b * N_ + n) * 64 + c] = (_Float16)val;
            }
        }
}

// ---------------- attention + out-proj: 16 pairs/block, 16 threads/pair ----------------
__global__ __launch_bounds__(256) void k_attn2(const _Float16* __restrict__ KV,
        const _Float16* __restrict__ Q, const _Float16* __restrict__ Wo16,
        const float* __restrict__ bo, float* __restrict__ o1) {
    __shared__ _Float16 kvs[16 * 1544];
    __shared__ float qs[16][64];
    __shared__ float Wos[64][64];
    __shared__ float outb[16][64];
    __shared__ float bos[64];
    int tid = threadIdx.x;
    long pair0 = (long)blockIdx.x * 16;
#pragma unroll
    for (int u = 0; u < 12; ++u) {
        int idx = u * 256 + tid;
        int p = idx / 192, off8 = (idx % 192) * 8;
        *(f16x8*)&kvs[p * 1544 + off8] = *(const f16x8*)(KV + (pair0 + p) * 1536 + off8);
    }
    if (tid < 64) bos[tid] = bo[tid];
    for (int idx = tid; idx < 1024; idx += 256) {
        int p = idx >> 6, j = idx & 63;
        qs[p][j] = (float)Q[(pair0 + p) * 64 + j];
    }
    for (int idx = tid; idx < 4096; idx += 256) {
        int c = idx >> 6, j = idx & 63;
        Wos[c][j] = (float)Wo16[j * 64 + c];
    }
    __syncthreads();
    int p = tid >> 4, i = tid & 15;
    int h = i >> 2, sg = i & 3;
    const _Float16* kvp = &kvs[p * 1544];
    float att3[3], mx = -1e30f;
#pragma unroll
    for (int j = 0; j < 3; ++j) {
        int s = sg + 4 * j;
        float sc = 0.f;
#pragma unroll
        for (int d = 0; d < 16; ++d)
            sc = fmaf(qs[p][h * 16 + d], (float)kvp[s * 128 + h * 16 + d], sc);
        att3[j] = sc * 0.25f;
        mx = fmaxf(mx, att3[j]);
    }
    mx = fmaxf(mx, __shfl_xor(mx, 1));
    mx = fmaxf(mx, __shfl_xor(mx, 2));
    float se = 0.f;
#pragma unroll
    for (int j = 0; j < 3; ++j) { att3[j] = __expf(att3[j] - mx); se += att3[j]; }
    se += __shfl_xor(se, 1);
    se += __shfl_xor(se, 2);
    float inv = 1.f / se;
#pragma unroll
    for (int j = 0; j < 3; ++j) att3[j] *= inv;
    int c0 = i * 4;
    float out4[4] = {0.f, 0.f, 0.f, 0.f};
#pragma unroll
    for (int m = 0; m < 4; ++m) {
        float a0 = __shfl_xor(att3[0], m);
        float a1 = __shfl_xor(att3[1], m);
        float a2 = __shfl_xor(att3[2], m);
        int sb = sg ^ m;
        float aj[3] = {a0, a1, a2};
#pragma unroll
        for (int j = 0; j < 3; ++j) {
            int s = sb + 4 * j;
            f16x4 vv = *(const f16x4*)&kvp[s * 128 + 64 + c0];
#pragma unroll
            for (int q = 0; q < 4; ++q) out4[q] = fmaf(aj[j], (float)vv[q], out4[q]);
        }
    }
    *(float4*)&outb[p][c0] = *(float4*)out4;
    __syncthreads();
    float res[4];
#pragma unroll
    for (int q = 0; q < 4; ++q) res[q] = bos[c0 + q];
    for (int c = 0; c < 64; ++c) {
        float oc = outb[p][c];
        float4 wv = *(const float4*)&Wos[c][c0];
        res[0] = fmaf(oc, wv.x, res[0]);
        res[1] = fmaf(oc, wv.y, res[1]);
        res[2] = fmaf(oc, wv.z, res[2]);
        res[3] = fmaf(oc, wv.w, res[3]);
    }
    *(float4*)&o1[(pair0 + p) * 64 + c0] = make_float4(res[0], res[1], res[2], res[3]);
}

// ---------------- output head ----------------
__global__ __launch_bounds__(256) void k_final(const float* __restrict__ o1,
        const _Float16* __restrict__ hT, const float* __restrict__ cw,
        const float* __restrict__ convw, const float* __restrict__ convb,
        float* __restrict__ out) {
    __shared__ float Ws[12 * 3 * 64];
    __shared__ float cbs[12];
    int tid = threadIdx.x;
    for (int idx = tid; idx < 12 * 3 * 64; idx += 256) Ws[idx] = convw[idx];
    if (tid < 12) cbs[tid] = convb[tid];
    __syncthreads();
    float c0 = cw[0], c1 = cw[1], c2 = cw[2];
    int g = tid >> 6, j = tid & 63;
    int bn = blockIdx.x * 4 + g;
    int b = bn >> 11, n = bn & 2047;
    float x1 = o1[(long)bn * DH + j];
    float x3 = (float)hT[(long)bn * DH + j];
    float myout = 0.f;
#pragma unroll
    for (int oc = 0; oc < 12; ++oc) {
        float p = x1 * c0 * Ws[(oc * 3 + 0) * 64 + j]
                + x3 * (c1 * Ws[(oc * 3 + 1) * 64 + j] + c2 * Ws[(oc * 3 + 2) * 64 + j]);
        p += __shfl_xor(p, 1); p += __shfl_xor(p, 2); p += __shfl_xor(p, 4);
        p += __shfl_xor(p, 8); p += __shfl_xor(p, 16); p += __shfl_xor(p, 32);
        if (j == oc) myout = p + cbs[oc];
    }
    if (j < 12) out[((long)b * 12 + j) * N_ + n] = myout;
}

extern "C" void kernel_launch(void* const* d_in, const int* in_sizes, int n_in,
                              void* d_out, int out_size, void* d_ws, size_t ws_size,
                              hipStream_t stream) {
    const float* src    = (const float*)d_in[0];
    const float* emb    = (const float*)d_in[2];
    const float* gate_w = (const float*)d_in[3];
    const float* gate_b = (const float*)d_in[4];
    const float* upd_w  = (const float*)d_in[5];
    const float* upd_b  = (const float*)d_in[6];
    const float* a_in_w = (const float*)d_in[7];
    const float* a_in_b = (const float*)d_in[8];
    const float* a_out_w= (const float*)d_in[9];
    const float* a_out_b= (const float*)d_in[10];
    const float* chan_w = (const float*)d_in[11];
    const float* conv_w = (const float*)d_in[12];
    const float* conv_b = (const float*)d_in[13];
    float* out = (float*)d_out;

    char* ws = (char*)d_ws;
    size_t off = 0;
    auto alloc = [&](size_t bytes) { char* p = ws + off; off += (bytes + 255) & ~size_t(255); return p; };
    _Float16* A    = (_Float16*)alloc((size_t)N_ * N_ * 2);
    _Float16* A2   = (_Float16*)alloc((size_t)N_ * N_ * 2);
    _Float16* GwT  = (_Float16*)alloc((size_t)N_ * NKC * 128 * 8 * 2);   // 104.9 MB
    float*  Gb     = (float*) alloc((size_t)N_ * 128 * 4);
    _Float16* UwT  = (_Float16*)alloc((size_t)N_ * NKC * 64 * 8 * 2);    // 52.4 MB
    float*  Ub     = (float*) alloc((size_t)N_ * 64 * 4);
    _Float16* XT   = (_Float16*)alloc((size_t)NCP * N_ * 2);
    _Float16* Y1   = (_Float16*)alloc((size_t)N_ * NCP * 2);   // node-major [n][c]
    _Float16* Y2   = (_Float16*)alloc((size_t)N_ * NCP * 2);   // node-major [n][c]
    _Float16* h    = (_Float16*)alloc((size_t)B_ * N_ * DH * 2);
    _Float16* zbuf = (_Float16*)alloc((size_t)B_ * N_ * DH * 2);
    _Float16* rbuf = (_Float16*)alloc((size_t)B_ * N_ * DH * 2);
    _Float16* stt  = (_Float16*)alloc((size_t)B_ * T_ * N_ * DH * 2);
    _Float16* Wi16 = (_Float16*)alloc(192 * 64 * 2);
    _Float16* Wo16 = (_Float16*)alloc(64 * 64 * 2);
    _Float16* zp   = (_Float16*)alloc(512);
    if (off > ws_size) return;   // ~252 MB total

    // transient/dead-region aliases
    _Float16* AT = stt;                            // 8.4 MB scratch (stt unwritten at setup)
    _Float16* KV = GwT;                            // 100.7 MB into GwT's 104.9 MB
    _Float16* Qb = UwT;                            // 4.2 MB at UwT start
    float*    o1 = (float*)((char*)UwT + (8u << 20)); // 8.4 MB at UwT+8MB

    hipMemsetAsync(h, 0, (size_t)B_ * N_ * DH * 2, stream);
    hipMemsetAsync(XT, 0, (size_t)NCP * N_ * 2, stream);
    hipMemsetAsync(zp, 0, 512, stream);
    k_compA<<<N_, 256, 0, stream>>>(emb, A);
    dim3 tgrid(32, 32);
    k_transp<<<tgrid, 256, 0, stream>>>(A, AT);
    k_gemm<<<tgrid, 256, 0, stream>>>(AT, A, A2);   // A2 = (1024*A^2), Aop=AT BT=A
    k_build<<<816, 256, 0, stream>>>(emb, gate_w, gate_b, upd_w, upd_b, GwT, Gb, UwT, Ub);
    k_wcvt<<<48, 256, 0, stream>>>(a_in_w, a_out_w, Wi16, Wo16);
    k_initx<<<128, 256, 0, stream>>>(src, XT);

    dim3 ggrid(16, 17, 2);
    for (int t = 0; t < T_; ++t) {
        k_gemm2<<<ggrid, 256, 0, stream>>>(A, A2, XT, Y1, Y2);
        k_apply_gate<<<N_, 256, 0, stream>>>(src, h, Y1, Y2, GwT, Gb, t, zbuf, rbuf, XT, zp);
        k_gemm2<<<ggrid, 256, 0, stream>>>(A, A2, XT, Y1, Y2);
        k_apply_update<<<N_, 256, 0, stream>>>(src, h, Y1, Y2, UwT, Ub, zbuf, rbuf, t, stt, XT, zp);
    }
    dim3 qgrid(192, 16);
    k_qkv<<<qgrid, 256, 0, stream>>>(stt, Wi16, a_in_b, KV, Qb);
    k_attn2<<<2048, 256, 0, stream>>>(KV, Qb, Wo16, a_out_b, o1);
    k_final<<<8192, 256, 0, stream>>>(o1, h, chan_w, conv_w, conv_b, out);
}

// Round 20
// 1936.022 us; speedup vs baseline: 1.3194x; 1.0051x over previous
//
#include <hip/hip_runtime.h>
#include <hip/hip_bf16.h>

typedef _Float16 f16x8 __attribute__((ext_vector_type(8)));
typedef _Float16 f16x4 __attribute__((ext_vector_type(4)));
typedef float f32x4 __attribute__((ext_vector_type(4)));
typedef unsigned short us8 __attribute__((ext_vector_type(8)));
typedef unsigned short us4 __attribute__((ext_vector_type(4)));

#define N_ 2048
#define B_ 16
#define T_ 12
#define DH 64
#define CC 65      // DIN + DOUT
#define NC 1040    // B_*CC
#define NCP 1088   // padded col count (17*64)
#define KI 195     // K*CC
#define NKC 25     // kk-chunks of 8 (200 slots, kk>=195 zero)
#define EDIM 10
#define ASCALE 1024.0f
#define AINV (1.0f / 1024.0f)

// ---------------- A = softmax(relu(E E^T)) rowwise, f16 scaled by 1024 ----------------
__global__ __launch_bounds__(256) void k_compA(const float* __restrict__ emb,
                                               _Float16* __restrict__ A) {
    int n = blockIdx.x, tid = threadIdx.x;
    float en[EDIM];
#pragma unroll
    for (int d = 0; d < EDIM; ++d) en[d] = emb[n * EDIM + d];
    float v[8], mx = -1e30f;
#pragma unroll
    for (int j = 0; j < 8; ++j) {
        int m = tid + j * 256;
        float acc = 0.f;
#pragma unroll
        for (int d = 0; d < EDIM; ++d) acc = fmaf(en[d], emb[m * EDIM + d], acc);
        acc = fmaxf(acc, 0.f);
        v[j] = acc; mx = fmaxf(mx, acc);
    }
    __shared__ float red[256];
    red[tid] = mx; __syncthreads();
    for (int s = 128; s > 0; s >>= 1) { if (tid < s) red[tid] = fmaxf(red[tid], red[tid + s]); __syncthreads(); }
    mx = red[0]; __syncthreads();
    float se = 0.f;
#pragma unroll
    for (int j = 0; j < 8; ++j) { v[j] = __expf(v[j] - mx); se += v[j]; }
    red[tid] = se; __syncthreads();
    for (int s = 128; s > 0; s >>= 1) { if (tid < s) red[tid] += red[tid + s]; __syncthreads(); }
    float inv = ASCALE / red[0];
#pragma unroll
    for (int j = 0; j < 8; ++j) A[(long)n * N_ + tid + j * 256] = (_Float16)(v[j] * inv);
}

// ---------------- transpose A -> AT (64x64 LDS tiles) ----------------
__global__ __launch_bounds__(256) void k_transp(const _Float16* __restrict__ A,
                                                _Float16* __restrict__ AT) {
    __shared__ _Float16 tile[64][72];
    int bx = blockIdx.x, by = blockIdx.y;
    int tid = threadIdx.x;
    int r8 = tid >> 3, c8 = (tid & 7) * 8;
#pragma unroll
    for (int p = 0; p < 2; ++p) {
        int r = p * 32 + r8;
        *(f16x8*)&tile[r][c8] = *(const f16x8*)(A + (long)(by * 64 + r) * N_ + bx * 64 + c8);
    }
    __syncthreads();
#pragma unroll
    for (int p = 0; p < 2; ++p) {
        int r = p * 32 + r8;
        f16x8 v;
#pragma unroll
        for (int q = 0; q < 8; ++q) v[q] = tile[c8 + q][r];
        *(f16x8*)(AT + (long)(bx * 64 + r) * N_ + by * 64 + c8) = v;
    }
}

// ---------------- per-node GRU weights, MFMA-fragment order, o-major ----------------
__global__ __launch_bounds__(256) void k_build(const float* __restrict__ emb,
        const float* __restrict__ gw, const float* __restrict__ gb,
        const float* __restrict__ uw, const float* __restrict__ ub,
        _Float16* __restrict__ GwT, float* __restrict__ Gb,
        _Float16* __restrict__ UwT, float* __restrict__ Ub) {
    int bid = blockIdx.x;
    int tid = threadIdx.x;
    if (bid < 800) {
        __shared__ float embs[128][EDIM];
        int isupd = bid >= 400;
        int b2 = isupd ? bid - 400 : bid;
        int kkc = b2 >> 4, nch = b2 & 15;
        for (int idx = tid; idx < 128 * EDIM; idx += 256)
            embs[idx / EDIM][idx % EDIM] = emb[(nch * 128 + idx / EDIM) * EDIM + idx % EDIM];
        __syncthreads();
        if (!isupd) {
            int o = tid >> 1, jh = (tid & 1) * 4;
            float w[EDIM][4];
#pragma unroll
            for (int d = 0; d < EDIM; ++d)
#pragma unroll
                for (int jj = 0; jj < 4; ++jj) {
                    int kk = kkc * 8 + jh + jj;
                    w[d][jj] = (kk < KI) ? gw[(long)d * (KI * 128) + (long)kk * 128 + o] : 0.f;
                }
            for (int i = 0; i < 128; ++i) {
                int n = nch * 128 + i;
                float a0 = 0.f, a1 = 0.f, a2 = 0.f, a3 = 0.f;
#pragma unroll
                for (int d = 0; d < EDIM; ++d) {
                    float ed = embs[i][d];
                    a0 = fmaf(ed, w[d][0], a0); a1 = fmaf(ed, w[d][1], a1);
                    a2 = fmaf(ed, w[d][2], a2); a3 = fmaf(ed, w[d][3], a3);
                }
                us4 pk;
                pk[0] = __builtin_bit_cast(unsigned short, (_Float16)a0);
                pk[1] = __builtin_bit_cast(unsigned short, (_Float16)a1);
                pk[2] = __builtin_bit_cast(unsigned short, (_Float16)a2);
                pk[3] = __builtin_bit_cast(unsigned short, (_Float16)a3);
                *(us4*)(GwT + ((long)n * NKC + kkc) * 1024 + o * 8 + jh) = pk;
            }
        } else {
            int sub = tid >> 7, o = (tid >> 1) & 63, jh = (tid & 1) * 4;
            float w[EDIM][4];
#pragma unroll
            for (int d = 0; d < EDIM; ++d)
#pragma unroll
                for (int jj = 0; jj < 4; ++jj) {
                    int kk = kkc * 8 + jh + jj;
                    w[d][jj] = (kk < KI) ? uw[(long)d * (KI * 64) + (long)kk * 64 + o] : 0.f;
                }
            for (int i = 0; i < 64; ++i) {
                int il = i * 2 + sub;
                int n = nch * 128 + il;
                float a0 = 0.f, a1 = 0.f, a2 = 0.f, a3 = 0.f;
#pragma unroll
                for (int d = 0; d < EDIM; ++d) {
                    float ed = embs[il][d];
                    a0 = fmaf(ed, w[d][0], a0); a1 = fmaf(ed, w[d][1], a1);
                    a2 = fmaf(ed, w[d][2], a2); a3 = fmaf(ed, w[d][3], a3);
                }
                us4 pk;
                pk[0] = __builtin_bit_cast(unsigned short, (_Float16)a0);
                pk[1] = __builtin_bit_cast(unsigned short, (_Float16)a1);
                pk[2] = __builtin_bit_cast(unsigned short, (_Float16)a2);
                pk[3] = __builtin_bit_cast(unsigned short, (_Float16)a3);
                *(us4*)(UwT + ((long)n * NKC + kkc) * 512 + o * 8 + jh) = pk;
            }
        }
    } else {
        int bb = bid - 800;
        const int CHUNK = (2048 * 128 + 2048 * 64) / 16;   // 24576
        for (int idx = bb * CHUNK + tid; idx < (bb + 1) * CHUNK; idx += 256) {
            if (idx < 2048 * 128) {
                int n = idx >> 7, o = idx & 127;
                float a = 0.f;
#pragma unroll
                for (int d = 0; d < EDIM; ++d) a = fmaf(emb[n * EDIM + d], gb[d * 128 + o], a);
                Gb[idx] = a;
            } else {
                int i2 = idx - 2048 * 128;
                int n = i2 >> 6, o = i2 & 63;
                float a = 0.f;
#pragma unroll
                for (int d = 0; d < EDIM; ++d) a = fmaf(emb[n * EDIM + d], ub[d * 64 + o], a);
                Ub[i2] = a;
            }
        }
    }
}

// ---------------- tiny: f16 copies of attn weights ----------------
__global__ __launch_bounds__(256) void k_wcvt(const float* __restrict__ Wi,
        const float* __restrict__ Wo, _Float16* __restrict__ Wi16,
        _Float16* __restrict__ Wo16) {
    int idx = blockIdx.x * 256 + threadIdx.x;
    if (idx < 192 * 64) Wi16[idx] = (_Float16)Wi[idx];
    if (idx < 64 * 64) Wo16[idx] = (_Float16)Wo[idx];
}

// ---------------- tiny: XT x-row for t=0 ----------------
__global__ __launch_bounds__(256) void k_initx(const float* __restrict__ src,
        _Float16* __restrict__ XT) {
    int idx = blockIdx.x * 256 + threadIdx.x;   // b*2048+n
    int b = idx >> 11, n = idx & 2047;
    XT[((long)b * CC) * N_ + n] = (_Float16)src[((long)b * T_) * N_ + n];
}

// ---------------- GEMM core (c-major epilogue, for A2 precompute) ----------------
__device__ __forceinline__ f16x8 lds_frag(const _Float16* base, int r, int kb) {
    int byt = r * 128 + ((kb * 2) ^ ((r & 7) << 4));
    return *(const f16x8*)((const char*)base + byt);
}

__global__ __launch_bounds__(256) void k_gemm(const _Float16* __restrict__ Aop,
        const _Float16* __restrict__ BT, _Float16* __restrict__ DT) {
    __shared__ __align__(16) _Float16 As[3 * 4096];
    __shared__ __align__(16) _Float16 Bs[3 * 4096];
    int bm = blockIdx.x, bc = blockIdx.y, tid = threadIdx.x;
    int wid = tid >> 6, lane = tid & 63;
    int row_g = bm * 64, col_g = bc * 64;
    int r0 = (wid & 1) * 32, c0 = (wid >> 1) * 32;
    int lr8 = lane >> 3;
    int lsw = 8 * ((lane & 7) ^ lr8);
    long aoff[2], boff[2];
    int ldo[2];
#pragma unroll
    for (int i = 0; i < 2; ++i) {
        aoff[i] = (long)(row_g + wid * 16 + i * 8 + lr8) * N_ + lsw;
        boff[i] = (long)(col_g + wid * 16 + i * 8 + lr8) * N_ + lsw;
        ldo[i] = (wid * 16 + i * 8) * 64;
    }
    auto stage = [&](int buf, int kt) {
        int k0 = kt * 64;
#pragma unroll
        for (int i = 0; i < 2; ++i)
            __builtin_amdgcn_global_load_lds(
                (const __attribute__((address_space(1))) void*)(Aop + aoff[i] + k0),
                (__attribute__((address_space(3))) void*)&As[buf * 4096 + ldo[i]], 16, 0, 0);
#pragma unroll
        for (int i = 0; i < 2; ++i)
            __builtin_amdgcn_global_load_lds(
                (const __attribute__((address_space(1))) void*)(BT + boff[i] + k0),
                (__attribute__((address_space(3))) void*)&Bs[buf * 4096 + ldo[i]], 16, 0, 0);
    };
    f32x4 acc[2][2] = {};
    const int NT = 32;
    stage(0, 0); stage(1, 1);
    int buf = 0;
    for (int kt = 0; kt < NT; ++kt) {
        if (kt + 2 < NT) { stage((buf + 2) % 3, kt + 2); asm volatile("s_waitcnt vmcnt(8)" ::: "memory"); }
        else if (kt + 1 < NT) { asm volatile("s_waitcnt vmcnt(4)" ::: "memory"); }
        else { asm volatile("s_waitcnt vmcnt(0)" ::: "memory"); }
        __builtin_amdgcn_s_barrier();
        const _Float16* Ab = As + buf * 4096;
        const _Float16* Bb = Bs + buf * 4096;
#pragma unroll
        for (int kk = 0; kk < 64; kk += 32) {
            int kb = kk + (lane >> 4) * 8;
            f16x8 af0 = lds_frag(Ab, r0 + (lane & 15), kb);
            f16x8 af1 = lds_frag(Ab, r0 + 16 + (lane & 15), kb);
            f16x8 bf0 = lds_frag(Bb, c0 + (lane & 15), kb);
            f16x8 bf1 = lds_frag(Bb, c0 + 16 + (lane & 15), kb);
            acc[0][0] = __builtin_amdgcn_mfma_f32_16x16x32_f16(af0, bf0, acc[0][0], 0, 0, 0);
            acc[0][1] = __builtin_amdgcn_mfma_f32_16x16x32_f16(af0, bf1, acc[0][1], 0, 0, 0);
            acc[1][0] = __builtin_amdgcn_mfma_f32_16x16x32_f16(af1, bf0, acc[1][0], 0, 0, 0);
            acc[1][1] = __builtin_amdgcn_mfma_f32_16x16x32_f16(af1, bf1, acc[1][1], 0, 0, 0);
        }
        asm volatile("s_waitcnt lgkmcnt(0)" ::: "memory");
        __builtin_amdgcn_s_barrier();
        buf = (buf + 1) % 3;
    }
#pragma unroll
    for (int rt = 0; rt < 2; ++rt)
#pragma unroll
        for (int ct = 0; ct < 2; ++ct) {
            int cg = col_g + c0 + ct * 16 + (lane & 15);
            int ng = row_g + r0 + rt * 16 + ((lane >> 4) << 2);
            us4 pk;
#pragma unroll
            for (int q = 0; q < 4; ++q) pk[q] = __builtin_bit_cast(unsigned short, (_Float16)(acc[rt][ct][q] * AINV));
            *(us4*)(DT + (long)cg * N_ + ng) = pk;
        }
}

// fused dual dispatch, 128-ROW tile (z: 0=A->Y1, 1=A2->Y2), node-major epilogue
// grid (16, 17, 2) = 544 blocks; LDS 48KB (2-buf); 16 MFMA/wave/K-step
// epilogue staged through LDS for full-128B-line stores
__global__ __launch_bounds__(256) void k_gemm2(const _Float16* __restrict__ A,
        const _Float16* __restrict__ A2, const _Float16* __restrict__ BT,
        _Float16* __restrict__ Y1, _Float16* __restrict__ Y2) {
    __shared__ __align__(16) _Float16 As[2 * 8192];
    __shared__ __align__(16) _Float16 Bs[2 * 4096];
    const _Float16* Aop = blockIdx.z ? A2 : A;
    _Float16* Yn = blockIdx.z ? Y2 : Y1;
    int bm = blockIdx.x, bc = blockIdx.y, tid = threadIdx.x;
    int wid = tid >> 6, lane = tid & 63;
    int row_g = bm * 128, col_g = bc * 64;
    int r0 = (wid & 1) * 64, c0 = (wid >> 1) * 32;
    int lr8 = lane >> 3;
    int lsw = 8 * ((lane & 7) ^ lr8);
    long aoff[4], boff[2];
    int lao[4], lbo[2];
#pragma unroll
    for (int i = 0; i < 4; ++i) {
        aoff[i] = (long)(row_g + wid * 32 + i * 8 + lr8) * N_ + lsw;
        lao[i] = (wid * 32 + i * 8) * 64;
    }
#pragma unroll
    for (int i = 0; i < 2; ++i) {
        boff[i] = (long)(col_g + wid * 16 + i * 8 + lr8) * N_ + lsw;
        lbo[i] = (wid * 16 + i * 8) * 64;
    }
    auto stage = [&](int buf, int kt) {
        int k0 = kt * 64;
#pragma unroll
        for (int i = 0; i < 4; ++i)
            __builtin_amdgcn_global_load_lds(
                (const __attribute__((address_space(1))) void*)(Aop + aoff[i] + k0),
                (__attribute__((address_space(3))) void*)&As[buf * 8192 + lao[i]], 16, 0, 0);
#pragma unroll
        for (int i = 0; i < 2; ++i)
            __builtin_amdgcn_global_load_lds(
                (const __attribute__((address_space(1))) void*)(BT + boff[i] + k0),
                (__attribute__((address_space(3))) void*)&Bs[buf * 4096 + lbo[i]], 16, 0, 0);
    };
    f32x4 acc[4][2] = {};
    const int NT = 32;
    stage(0, 0);
    for (int kt = 0; kt < NT; ++kt) {
        int buf = kt & 1;
        if (kt + 1 < NT) {
            stage(buf ^ 1, kt + 1);
            asm volatile("s_waitcnt vmcnt(6)" ::: "memory");
        } else {
            asm volatile("s_waitcnt vmcnt(0)" ::: "memory");
        }
        __builtin_amdgcn_s_barrier();
        const _Float16* Ab = As + buf * 8192;
        const _Float16* Bb = Bs + buf * 4096;
#pragma unroll
        for (int kk = 0; kk < 64; kk += 32) {
            int kb = kk + (lane >> 4) * 8;
            f16x8 bf0 = lds_frag(Bb, c0 + (lane & 15), kb);
            f16x8 bf1 = lds_frag(Bb, c0 + 16 + (lane & 15), kb);
#pragma unroll
            for (int rt = 0; rt < 4; ++rt) {
                f16x8 af = lds_frag(Ab, r0 + rt * 16 + (lane & 15), kb);
                acc[rt][0] = __builtin_amdgcn_mfma_f32_16x16x32_f16(af, bf0, acc[rt][0], 0, 0, 0);
                acc[rt][1] = __builtin_amdgcn_mfma_f32_16x16x32_f16(af, bf1, acc[rt][1], 0, 0, 0);
            }
        }
        asm volatile("s_waitcnt lgkmcnt(0)" ::: "memory");
        __builtin_amdgcn_s_barrier();
    }
    // epilogue: stage C into LDS (reuse As; safe after final barrier), then
    // 128B-coalesced node-major stores
    _Float16* Cs = As;                  // 128 x 72 pad
#pragma unroll
    for (int rt = 0; rt < 4; ++rt)
#pragma unroll
        for (int ct = 0; ct < 2; ++ct) {
            int cl2 = c0 + ct * 16 + (lane & 15);
            int nl = r0 + rt * 16 + ((lane >> 4) << 2);
#pragma unroll
            for (int q = 0; q < 4; ++q)
                Cs[(nl + q) * 72 + cl2] = (_Float16)(acc[rt][ct][q] * AINV);
        }
    __syncthreads();
#pragma unroll
    for (int pass = 0; pass < 4; ++pass) {
        int row = pass * 32 + (tid >> 3);
        int col8 = (tid & 7) * 8;
        *(f16x8*)(Yn + (long)(row_g + row) * NCP + col_g + col8) =
            *(const f16x8*)&Cs[row * 72 + col8];
    }
}

// ---------------- gate apply: split-K over 8 waves (512 thr), LDS reduce ----------------
__global__ __launch_bounds__(512) void k_apply_gate(const float* __restrict__ src,
        const _Float16* __restrict__ h, const _Float16* __restrict__ Y1,
        const _Float16* __restrict__ Y2, const _Float16* __restrict__ GwT,
        const float* __restrict__ Gb, int t,
        _Float16* __restrict__ z, _Float16* __restrict__ r, _Float16* __restrict__ XT,
        const _Float16* __restrict__ zp) {
    int n = blockIdx.x, tid = threadIdx.x, wid = tid >> 6, lane = tid & 63;
    int wq = wid & 3, kseg = wid >> 2;          // 4 o-quadrants x 2 K-segments
    __shared__ __align__(16) _Float16 xg[16][256];   // padded to 256: ks=7 dummy reads zeros
    __shared__ float red[4][64][8];
    const _Float16* Wp = GwT + (long)n * (NKC * 128 * 8);
    int cl = lane & 15, q = lane >> 4, k8 = q * 8;
    int o0 = wq * 32 + cl, o1 = o0 + 16;
    int base = kseg * 4;
    f16x8 bfr0[4], bfr1[4];
#pragma unroll
    for (int j = 0; j < 4; ++j) {
        int ks = base + j;
        bool valid = (ks * 4 + q) < NKC;
        const _Float16* p0 = valid ? Wp + (long)((ks * 4 + q) * 128 + o0) * 8 : zp + cl * 8;
        const _Float16* p1 = valid ? Wp + (long)((ks * 4 + q) * 128 + o1) * 8 : zp + cl * 8 + 128;
        bfr0[j] = *(const f16x8*)p0;
        bfr1[j] = *(const f16x8*)p1;
    }
    _Float16* xf = &xg[0][0];
    for (int idx = tid; idx < 16 * 256; idx += 512) xf[idx] = (_Float16)0.f;
    __syncthreads();
    const _Float16* y1p = Y1 + (long)n * NCP;
    const _Float16* y2p = Y2 + (long)n * NCP;
    for (int idx = tid; idx < 16 * KI; idx += 512) {
        int b = idx / KI, kk = idx % KI;
        int k = kk / CC, i = kk % CC;
        int c = b * CC + i;
        float ih = (i == 0) ? src[((long)b * T_ + t) * N_ + n]
                            : (float)h[((long)b * N_ + n) * DH + (i - 1)];
        float val;
        if (k == 0)      val = ih;
        else if (k == 1) val = (float)y1p[c];
        else             val = 2.f * (float)y2p[c] - ih;
        xg[b][kk] = (_Float16)val;
    }
    __syncthreads();
    f32x4 acc0 = {}, acc1 = {};
#pragma unroll
    for (int j = 0; j < 4; ++j) {
        int ks = base + j;
        f16x8 af = *(const f16x8*)&xg[cl][ks * 32 + k8];
        acc0 = __builtin_amdgcn_mfma_f32_16x16x32_f16(af, bfr0[j], acc0, 0, 0, 0);
        acc1 = __builtin_amdgcn_mfma_f32_16x16x32_f16(af, bfr1[j], acc1, 0, 0, 0);
    }
    if (kseg == 1) {
#pragma unroll
        for (int qq = 0; qq < 4; ++qq) {
            red[wq][lane][qq] = acc0[qq];
            red[wq][lane][4 + qq] = acc1[qq];
        }
    }
    __syncthreads();
    if (kseg == 0) {
#pragma unroll
        for (int qq = 0; qq < 4; ++qq) {
            acc0[qq] += red[wq][lane][qq];
            acc1[qq] += red[wq][lane][4 + qq];
        }
#pragma unroll
        for (int tl = 0; tl < 2; ++tl) {
            f32x4 acc = tl ? acc1 : acc0;
            int o = wq * 32 + tl * 16 + cl;
            float bias = Gb[(long)n * 128 + o];
#pragma unroll
            for (int qq = 0; qq < 4; ++qq) {
                int b = q * 4 + qq;
                float sv = 1.f / (1.f + __expf(-(acc[qq] + bias)));
                long base2 = ((long)b * N_ + n) * DH;
                if (o < 64) {
                    z[base2 + o] = (_Float16)sv;
                    XT[(long)(b * CC + 1 + o) * N_ + n] = (_Float16)(sv * (float)h[base2 + o]);
                } else {
                    r[base2 + (o - 64)] = (_Float16)sv;
                }
            }
        }
    }
}

// ---------------- update apply: split-K over 8 waves (512 thr), LDS reduce ----------------
__global__ __launch_bounds__(512) void k_apply_update(const float* __restrict__ src,
        _Float16* __restrict__ h, const _Float16* __restrict__ Y1,
        const _Float16* __restrict__ Y2, const _Float16* __restrict__ UwT,
        const float* __restrict__ Ub, const _Float16* __restrict__ z,
        const _Float16* __restrict__ rb, int t, _Float16* __restrict__ states,
        _Float16* __restrict__ XT, const _Float16* __restrict__ zp) {
    int n = blockIdx.x, tid = threadIdx.x, wid = tid >> 6, lane = tid & 63;
    int wq = wid & 3, kseg = wid >> 2;
    __shared__ __align__(16) _Float16 xg[16][256];
    __shared__ float red[4][64][4];
    const _Float16* Wp = UwT + (long)n * (NKC * 64 * 8);
    int cl = lane & 15, q = lane >> 4, k8 = q * 8;
    int o0 = wq * 16 + cl;
    int base = kseg * 4;
    f16x8 bfr[4];
#pragma unroll
    for (int j = 0; j < 4; ++j) {
        int ks = base + j;
        bool valid = (ks * 4 + q) < NKC;
        const _Float16* p0 = valid ? Wp + (long)((ks * 4 + q) * 64 + o0) * 8 : zp + cl * 8;
        bfr[j] = *(const f16x8*)p0;
    }
    _Float16* xf = &xg[0][0];
    for (int idx = tid; idx < 16 * 256; idx += 512) xf[idx] = (_Float16)0.f;
    __syncthreads();
    const _Float16* y1p = Y1 + (long)n * NCP;
    const _Float16* y2p = Y2 + (long)n * NCP;
    for (int idx = tid; idx < 16 * KI; idx += 512) {
        int b = idx / KI, kk = idx % KI;
        int k = kk / CC, i = kk % CC;
        int c = b * CC + i;
        float ih;
        if (i == 0) ih = src[((long)b * T_ + t) * N_ + n];
        else {
            long base2 = ((long)b * N_ + n) * DH + (i - 1);
            ih = (float)h[base2] * (float)z[base2];
        }
        float val;
        if (k == 0)      val = ih;
        else if (k == 1) val = (float)y1p[c];
        else             val = 2.f * (float)y2p[c] - ih;
        xg[b][kk] = (_Float16)val;
    }
    __syncthreads();
    f32x4 acc0 = {};
#pragma unroll
    for (int j = 0; j < 4; ++j) {
        int ks = base + j;
        f16x8 af = *(const f16x8*)&xg[cl][ks * 32 + k8];
        acc0 = __builtin_amdgcn_mfma_f32_16x16x32_f16(af, bfr[j], acc0, 0, 0, 0);
    }
    if (kseg == 1) {
#pragma unroll
        for (int qq = 0; qq < 4; ++qq) red[wq][lane][qq] = acc0[qq];
    }
    __syncthreads();
    if (kseg == 0) {
#pragma unroll
        for (int qq = 0; qq < 4; ++qq) acc0[qq] += red[wq][lane][qq];
        int o = o0;
        float bias = Ub[(long)n * 64 + o];
#pragma unroll
        for (int qq = 0; qq < 4; ++qq) {
            int b = q * 4 + qq;
            long base2 = ((long)b * N_ + n) * DH + o;
            float hc = tanhf(acc0[qq] + bias);
            float rv = (float)rb[base2], hv = (float)h[base2];
            float hn = rv * hv + (1.f - rv) * hc;
            _Float16 hn16 = (_Float16)hn;
            h[base2] = hn16;
            states[(((long)b * T_ + t) * N_ + n) * DH + o] = hn16;
            XT[(long)(b * CC + 1 + o) * N_ + n] = hn16;
            if (o == 0 && t + 1 < T_)
                XT[(long)(b * CC) * N_ + n] = (_Float16)src[((long)b * T_ + t + 1) * N_ + n];
        }
    }
}

// ---------------- qkv projection (MFMA): KV for all t, Q at t=11 ----------------
__global__ __launch_bounds__(256) void k_qkv(const _Float16* __restrict__ st,
        const _Float16* __restrict__ Wi16, const float* __restrict__ bi,
        _Float16* __restrict__ KV, _Float16* __restrict__ Q) {
    int bt = blockIdx.x;
    int nck = blockIdx.y;
    int b = bt / 12, t = bt % 12;
    int tid = threadIdx.x, wid = tid >> 6, lane = tid & 63;
    __shared__ float pe[64];
    __shared__ __align__(16) _Float16 Xs[128][72];
    if (tid < 64) {
        int e = tid;
        float div = __powf(10000.f, -(float)(e & ~1) / 64.f);
        float ang = (float)t * div;
        pe[e] = (e & 1) ? __cosf(ang) : __sinf(ang);
    }
    __syncthreads();
    const _Float16* srcp = st + ((long)(b * T_ + t) * N_ + nck * 128) * DH;
#pragma unroll
    for (int u = 0; u < 4; ++u) {
        int idx = u * 256 + tid;
        int rr = idx >> 3, e0 = (idx & 7) * 8;
        f16x8 v = *(const f16x8*)(srcp + rr * DH + e0);
        f16x8 ov;
#pragma unroll
        for (int q = 0; q < 8; ++q) ov[q] = (_Float16)((float)v[q] + pe[e0 + q]);
        *(f16x8*)&Xs[rr][e0] = ov;
    }
    __syncthreads();
    int cl = lane & 15, ks8 = (lane >> 4) * 8;
    f16x8 bfrag[3][2];
    float bias[3];
#pragma unroll
    for (int j = 0; j < 3; ++j) {
        int c = (wid * 3 + j) * 16 + cl;
#pragma unroll
        for (int ks = 0; ks < 2; ++ks)
            bfrag[j][ks] = *(const f16x8*)(Wi16 + c * 64 + ks * 32 + ks8);
        bias[j] = bi[c];
    }
    f32x4 acc[8][3] = {};
#pragma unroll
    for (int rt = 0; rt < 8; ++rt) {
#pragma unroll
        for (int ks = 0; ks < 2; ++ks) {
            f16x8 af = *(const f16x8*)&Xs[rt * 16 + cl][ks * 32 + ks8];
#pragma unroll
            for (int j = 0; j < 3; ++j)
                acc[rt][j] = __builtin_amdgcn_mfma_f32_16x16x32_f16(af, bfrag[j][ks], acc[rt][j], 0, 0, 0);
        }
    }
    int rowq = (lane >> 4) * 4;
#pragma unroll
    for (int rt = 0; rt < 8; ++rt)
#pragma unroll
        for (int j = 0; j < 3; ++j) {
            int c = (wid * 3 + j) * 16 + cl;
#pragma unroll
            for (int q = 0; q < 4; ++q) {
                int n = nck * 128 + rt * 16 + rowq + q;
                float val = acc[rt][j][q] + bias[j];
                if (c >= 64)
                    KV[(((long)b * N_ + n) * T_ + t) * 128 + (c - 64)] = (_Float16)val;
                else if (t == 11)
                    Q[((long)b * N_ + n) * 64 + c] = (_Float16)val;
            }
        }
}

// ---------------- attention + out-proj: 16 pairs/block, 16 threads/pair ----------------
__global__ __launch_bounds__(256) void k_attn2(const _Float16* __restrict__ KV,
        const _Float16* __restrict__ Q, const _Float16* __restrict__ Wo16,
        const float* __restrict__ bo, float* __restrict__ o1) {
    __shared__ _Float16 kvs[16 * 1544];
    __shared__ float qs[16][64];
    __shared__ float Wos[64][64];
    __shared__ float outb[16][64];
    __shared__ float bos[64];
    int tid = threadIdx.x;
    long pair0 = (long)blockIdx.x * 16;
#pragma unroll
    for (int u = 0; u < 12; ++u) {
        int idx = u * 256 + tid;
        int p = idx / 192, off8 = (idx % 192) * 8;
        *(f16x8*)&kvs[p * 1544 + off8] = *(const f16x8*)(KV + (pair0 + p) * 1536 + off8);
    }
    if (tid < 64) bos[tid] = bo[tid];
    for (int idx = tid; idx < 1024; idx += 256) {
        int p = idx >> 6, j = idx & 63;
        qs[p][j] = (float)Q[(pair0 + p) * 64 + j];
    }
    for (int idx = tid; idx < 4096; idx += 256) {
        int c = idx >> 6, j = idx & 63;
        Wos[c][j] = (float)Wo16[j * 64 + c];
    }
    __syncthreads();
    int p = tid >> 4, i = tid & 15;
    int h = i >> 2, sg = i & 3;
    const _Float16* kvp = &kvs[p * 1544];
    float att3[3], mx = -1e30f;
#pragma unroll
    for (int j = 0; j < 3; ++j) {
        int s = sg + 4 * j;
        float sc = 0.f;
#pragma unroll
        for (int d = 0; d < 16; ++d)
            sc = fmaf(qs[p][h * 16 + d], (float)kvp[s * 128 + h * 16 + d], sc);
        att3[j] = sc * 0.25f;
        mx = fmaxf(mx, att3[j]);
    }
    mx = fmaxf(mx, __shfl_xor(mx, 1));
    mx = fmaxf(mx, __shfl_xor(mx, 2));
    float se = 0.f;
#pragma unroll
    for (int j = 0; j < 3; ++j) { att3[j] = __expf(att3[j] - mx); se += att3[j]; }
    se += __shfl_xor(se, 1);
    se += __shfl_xor(se, 2);
    float inv = 1.f / se;
#pragma unroll
    for (int j = 0; j < 3; ++j) att3[j] *= inv;
    int c0 = i * 4;
    float out4[4] = {0.f, 0.f, 0.f, 0.f};
#pragma unroll
    for (int m = 0; m < 4; ++m) {
        float a0 = __shfl_xor(att3[0], m);
        float a1 = __shfl_xor(att3[1], m);
        float a2 = __shfl_xor(att3[2], m);
        int sb = sg ^ m;
        float aj[3] = {a0, a1, a2};
#pragma unroll
        for (int j = 0; j < 3; ++j) {
            int s = sb + 4 * j;
            f16x4 vv = *(const f16x4*)&kvp[s * 128 + 64 + c0];
#pragma unroll
            for (int q = 0; q < 4; ++q) out4[q] = fmaf(aj[j], (float)vv[q], out4[q]);
        }
    }
    *(float4*)&outb[p][c0] = *(float4*)out4;
    __syncthreads();
    float res[4];
#pragma unroll
    for (int q = 0; q < 4; ++q) res[q] = bos[c0 + q];
    for (int c = 0; c < 64; ++c) {
        float oc = outb[p][c];
        float4 wv = *(const float4*)&Wos[c][c0];
        res[0] = fmaf(oc, wv.x, res[0]);
        res[1] = fmaf(oc, wv.y, res[1]);
        res[2] = fmaf(oc, wv.z, res[2]);
        res[3] = fmaf(oc, wv.w, res[3]);
    }
    *(float4*)&o1[(pair0 + p) * 64 + c0] = make_float4(res[0], res[1], res[2], res[3]);
}

// ---------------- output head ----------------
__global__ __launch_bounds__(256) void k_final(const float* __restrict__ o1,
        const _Float16* __restrict__ hT, const float* __restrict__ cw,
        const float* __restrict__ convw, const float* __restrict__ convb,
        float* __restrict__ out) {
    __shared__ float Ws[12 * 3 * 64];
    __shared__ float cbs[12];
    int tid = threadIdx.x;
    for (int idx = tid; idx < 12 * 3 * 64; idx += 256) Ws[idx] = convw[idx];
    if (tid < 12) cbs[tid] = convb[tid];
    __syncthreads();
    float c0 = cw[0], c1 = cw[1], c2 = cw[2];
    int g = tid >> 6, j = tid & 63;
    int bn = blockIdx.x * 4 + g;
    int b = bn >> 11, n = bn & 2047;
    float x1 = o1[(long)bn * DH + j];
    float x3 = (float)hT[(long)bn * DH + j];
    float myout = 0.f;
#pragma unroll
    for (int oc = 0; oc < 12; ++oc) {
        float p = x1 * c0 * Ws[(oc * 3 + 0) * 64 + j]
                + x3 * (c1 * Ws[(oc * 3 + 1) * 64 + j] + c2 * Ws[(oc * 3 + 2) * 64 + j]);
        p += __shfl_xor(p, 1); p += __shfl_xor(p, 2); p += __shfl_xor(p, 4);
        p += __shfl_xor(p, 8); p += __shfl_xor(p, 16); p += __shfl_xor(p, 32);
        if (j == oc) myout = p + cbs[oc];
    }
    if (j < 12) out[((long)b * 12 + j) * N_ + n] = myout;
}

extern "C" void kernel_launch(void* const* d_in, const int* in_sizes, int n_in,
                              void* d_out, int out_size, void* d_ws, size_t ws_size,
                              hipStream_t stream) {
    const float* src    = (const float*)d_in[0];
    const float* emb    = (const float*)d_in[2];
    const float* gate_w = (const float*)d_in[3];
    const float* gate_b = (const float*)d_in[4];
    const float* upd_w  = (const float*)d_in[5];
    const float* upd_b  = (const float*)d_in[6];
    const float* a_in_w = (const float*)d_in[7];
    const float* a_in_b = (const float*)d_in[8];
    const float* a_out_w= (const float*)d_in[9];
    const float* a_out_b= (const float*)d_in[10];
    const float* chan_w = (const float*)d_in[11];
    const float* conv_w = (const float*)d_in[12];
    const float* conv_b = (const float*)d_in[13];
    float* out = (float*)d_out;

    char* ws = (char*)d_ws;
    size_t off = 0;
    auto alloc = [&](size_t bytes) { char* p = ws + off; off += (bytes + 255) & ~size_t(255); return p; };
    _Float16* A    = (_Float16*)alloc((size_t)N_ * N_ * 2);
    _Float16* A2   = (_Float16*)alloc((size_t)N_ * N_ * 2);
    _Float16* GwT  = (_Float16*)alloc((size_t)N_ * NKC * 128 * 8 * 2);   // 104.9 MB
    float*  Gb     = (float*) alloc((size_t)N_ * 128 * 4);
    _Float16* UwT  = (_Float16*)alloc((size_t)N_ * NKC * 64 * 8 * 2);    // 52.4 MB
    float*  Ub     = (float*) alloc((size_t)N_ * 64 * 4);
    _Float16* XT   = (_Float16*)alloc((size_t)NCP * N_ * 2);
    _Float16* Y1   = (_Float16*)alloc((size_t)N_ * NCP * 2);   // node-major [n][c]
    _Float16* Y2   = (_Float16*)alloc((size_t)N_ * NCP * 2);   // node-major [n][c]
    _Float16* h    = (_Float16*)alloc((size_t)B_ * N_ * DH * 2);
    _Float16* zbuf = (_Float16*)alloc((size_t)B_ * N_ * DH * 2);
    _Float16* rbuf = (_Float16*)alloc((size_t)B_ * N_ * DH * 2);
    _Float16* stt  = (_Float16*)alloc((size_t)B_ * T_ * N_ * DH * 2);
    _Float16* Wi16 = (_Float16*)alloc(192 * 64 * 2);
    _Float16* Wo16 = (_Float16*)alloc(64 * 64 * 2);
    _Float16* zp   = (_Float16*)alloc(512);
    if (off > ws_size) return;   // ~252 MB total

    // transient/dead-region aliases
    _Float16* AT = stt;                            // 8.4 MB scratch (stt unwritten at setup)
    _Float16* KV = GwT;                            // 100.7 MB into GwT's 104.9 MB
    _Float16* Qb = UwT;                            // 4.2 MB at UwT start
    float*    o1 = (float*)((char*)UwT + (8u << 20)); // 8.4 MB at UwT+8MB

    hipMemsetAsync(h, 0, (size_t)B_ * N_ * DH * 2, stream);
    hipMemsetAsync(XT, 0, (size_t)NCP * N_ * 2, stream);
    hipMemsetAsync(zp, 0, 512, stream);
    k_compA<<<N_, 256, 0, stream>>>(emb, A);
    dim3 tgrid(32, 32);
    k_transp<<<tgrid, 256, 0, stream>>>(A, AT);
    k_gemm<<<tgrid, 256, 0, stream>>>(AT, A, A2);   // A2 = (1024*A^2), Aop=AT BT=A
    k_build<<<816, 256, 0, stream>>>(emb, gate_w, gate_b, upd_w, upd_b, GwT, Gb, UwT, Ub);
    k_wcvt<<<48, 256, 0, stream>>>(a_in_w, a_out_w, Wi16, Wo16);
    k_initx<<<128, 256, 0, stream>>>(src, XT);

    dim3 ggrid(16, 17, 2);
    for (int t = 0; t < T_; ++t) {
        k_gemm2<<<ggrid, 256, 0, stream>>>(A, A2, XT, Y1, Y2);
        k_apply_gate<<<N_, 512, 0, stream>>>(src, h, Y1, Y2, GwT, Gb, t, zbuf, rbuf, XT, zp);
        k_gemm2<<<ggrid, 256, 0, stream>>>(A, A2, XT, Y1, Y2);
        k_apply_update<<<N_, 512, 0, stream>>>(src, h, Y1, Y2, UwT, Ub, zbuf, rbuf, t, stt, XT, zp);
    }
    dim3 qgrid(192, 16);
    k_qkv<<<qgrid, 256, 0, stream>>>(stt, Wi16, a_in_b, KV, Qb);
    k_attn2<<<2048, 256, 0, stream>>>(KV, Qb, Wo16, a_out_b, o1);
    k_final<<<8192, 256, 0, stream>>>(o1, h, chan_w, conv_w, conv_b, out);
}

// Round 21
// 1933.578 us; speedup vs baseline: 1.3210x; 1.0013x over previous
//
#include <hip/hip_runtime.h>
#include <hip/hip_bf16.h>

typedef _Float16 f16x8 __attribute__((ext_vector_type(8)));
typedef _Float16 f16x4 __attribute__((ext_vector_type(4)));
typedef float f32x4 __attribute__((ext_vector_type(4)));
typedef unsigned short us8 __attribute__((ext_vector_type(8)));
typedef unsigned short us4 __attribute__((ext_vector_type(4)));

#define N_ 2048
#define B_ 16
#define T_ 12
#define DH 64
#define CC 65      // DIN + DOUT
#define NC 1040    // B_*CC
#define NCP 1088   // padded col count (17*64)
#define KI 195     // K*CC
#define NKC 25     // kk-chunks of 8 (200 slots, kk>=195 zero)
#define EDIM 10
#define ASCALE 1024.0f
#define AINV (1.0f / 1024.0f)

// ---------------- A = softmax(relu(E E^T)) rowwise, f16 scaled by 1024 ----------------
__global__ __launch_bounds__(256) void k_compA(const float* __restrict__ emb,
                                               _Float16* __restrict__ A) {
    int n = blockIdx.x, tid = threadIdx.x;
    float en[EDIM];
#pragma unroll
    for (int d = 0; d < EDIM; ++d) en[d] = emb[n * EDIM + d];
    float v[8], mx = -1e30f;
#pragma unroll
    for (int j = 0; j < 8; ++j) {
        int m = tid + j * 256;
        float acc = 0.f;
#pragma unroll
        for (int d = 0; d < EDIM; ++d) acc = fmaf(en[d], emb[m * EDIM + d], acc);
        acc = fmaxf(acc, 0.f);
        v[j] = acc; mx = fmaxf(mx, acc);
    }
    __shared__ float red[256];
    red[tid] = mx; __syncthreads();
    for (int s = 128; s > 0; s >>= 1) { if (tid < s) red[tid] = fmaxf(red[tid], red[tid + s]); __syncthreads(); }
    mx = red[0]; __syncthreads();
    float se = 0.f;
#pragma unroll
    for (int j = 0; j < 8; ++j) { v[j] = __expf(v[j] - mx); se += v[j]; }
    red[tid] = se; __syncthreads();
    for (int s = 128; s > 0; s >>= 1) { if (tid < s) red[tid] += red[tid + s]; __syncthreads(); }
    float inv = ASCALE / red[0];
#pragma unroll
    for (int j = 0; j < 8; ++j) A[(long)n * N_ + tid + j * 256] = (_Float16)(v[j] * inv);
}

// ---------------- transpose A -> AT (64x64 LDS tiles) ----------------
__global__ __launch_bounds__(256) void k_transp(const _Float16* __restrict__ A,
                                                _Float16* __restrict__ AT) {
    __shared__ _Float16 tile[64][72];
    int bx = blockIdx.x, by = blockIdx.y;
    int tid = threadIdx.x;
    int r8 = tid >> 3, c8 = (tid & 7) * 8;
#pragma unroll
    for (int p = 0; p < 2; ++p) {
        int r = p * 32 + r8;
        *(f16x8*)&tile[r][c8] = *(const f16x8*)(A + (long)(by * 64 + r) * N_ + bx * 64 + c8);
    }
    __syncthreads();
#pragma unroll
    for (int p = 0; p < 2; ++p) {
        int r = p * 32 + r8;
        f16x8 v;
#pragma unroll
        for (int q = 0; q < 8; ++q) v[q] = tile[c8 + q][r];
        *(f16x8*)(AT + (long)(bx * 64 + r) * N_ + by * 64 + c8) = v;
    }
}

// ---------------- per-node GRU weights, MFMA-fragment order, o-major ----------------
// blocks [0,800): gate (kkc=bid>>5, nch=bid&31, 64 nodes each)
// blocks [800,1600): update; [1600,1616): biases
__global__ __launch_bounds__(256) void k_build(const float* __restrict__ emb,
        const float* __restrict__ gw, const float* __restrict__ gb,
        const float* __restrict__ uw, const float* __restrict__ ub,
        _Float16* __restrict__ GwT, float* __restrict__ Gb,
        _Float16* __restrict__ UwT, float* __restrict__ Ub) {
    int bid = blockIdx.x;
    int tid = threadIdx.x;
    if (bid < 1600) {
        __shared__ float embs[64][EDIM];
        int isupd = bid >= 800;
        int b2 = isupd ? bid - 800 : bid;
        int kkc = b2 >> 5, nch = b2 & 31;
        for (int idx = tid; idx < 64 * EDIM; idx += 256)
            embs[idx / EDIM][idx % EDIM] = emb[(nch * 64 + idx / EDIM) * EDIM + idx % EDIM];
        __syncthreads();
        if (!isupd) {
            int o = tid >> 1, jh = (tid & 1) * 4;
            float w[EDIM][4];
#pragma unroll
            for (int d = 0; d < EDIM; ++d)
#pragma unroll
                for (int jj = 0; jj < 4; ++jj) {
                    int kk = kkc * 8 + jh + jj;
                    w[d][jj] = (kk < KI) ? gw[(long)d * (KI * 128) + (long)kk * 128 + o] : 0.f;
                }
            for (int i = 0; i < 64; ++i) {
                int n = nch * 64 + i;
                float a0 = 0.f, a1 = 0.f, a2 = 0.f, a3 = 0.f;
#pragma unroll
                for (int d = 0; d < EDIM; ++d) {
                    float ed = embs[i][d];
                    a0 = fmaf(ed, w[d][0], a0); a1 = fmaf(ed, w[d][1], a1);
                    a2 = fmaf(ed, w[d][2], a2); a3 = fmaf(ed, w[d][3], a3);
                }
                us4 pk;
                pk[0] = __builtin_bit_cast(unsigned short, (_Float16)a0);
                pk[1] = __builtin_bit_cast(unsigned short, (_Float16)a1);
                pk[2] = __builtin_bit_cast(unsigned short, (_Float16)a2);
                pk[3] = __builtin_bit_cast(unsigned short, (_Float16)a3);
                *(us4*)(GwT + ((long)n * NKC + kkc) * 1024 + o * 8 + jh) = pk;
            }
        } else {
            int sub = tid >> 7, o = (tid >> 1) & 63, jh = (tid & 1) * 4;
            float w[EDIM][4];
#pragma unroll
            for (int d = 0; d < EDIM; ++d)
#pragma unroll
                for (int jj = 0; jj < 4; ++jj) {
                    int kk = kkc * 8 + jh + jj;
                    w[d][jj] = (kk < KI) ? uw[(long)d * (KI * 64) + (long)kk * 64 + o] : 0.f;
                }
            for (int i = 0; i < 32; ++i) {
                int il = i * 2 + sub;
                int n = nch * 64 + il;
                float a0 = 0.f, a1 = 0.f, a2 = 0.f, a3 = 0.f;
#pragma unroll
                for (int d = 0; d < EDIM; ++d) {
                    float ed = embs[il][d];
                    a0 = fmaf(ed, w[d][0], a0); a1 = fmaf(ed, w[d][1], a1);
                    a2 = fmaf(ed, w[d][2], a2); a3 = fmaf(ed, w[d][3], a3);
                }
                us4 pk;
                pk[0] = __builtin_bit_cast(unsigned short, (_Float16)a0);
                pk[1] = __builtin_bit_cast(unsigned short, (_Float16)a1);
                pk[2] = __builtin_bit_cast(unsigned short, (_Float16)a2);
                pk[3] = __builtin_bit_cast(unsigned short, (_Float16)a3);
                *(us4*)(UwT + ((long)n * NKC + kkc) * 512 + o * 8 + jh) = pk;
            }
        }
    } else {
        int bb = bid - 1600;
        const int CHUNK = (2048 * 128 + 2048 * 64) / 16;   // 24576
        for (int idx = bb * CHUNK + tid; idx < (bb + 1) * CHUNK; idx += 256) {
            if (idx < 2048 * 128) {
                int n = idx >> 7, o = idx & 127;
                float a = 0.f;
#pragma unroll
                for (int d = 0; d < EDIM; ++d) a = fmaf(emb[n * EDIM + d], gb[d * 128 + o], a);
                Gb[idx] = a;
            } else {
                int i2 = idx - 2048 * 128;
                int n = i2 >> 6, o = i2 & 63;
                float a = 0.f;
#pragma unroll
                for (int d = 0; d < EDIM; ++d) a = fmaf(emb[n * EDIM + d], ub[d * 64 + o], a);
                Ub[i2] = a;
            }
        }
    }
}

// ---------------- tiny: f16 copies of attn weights ----------------
__global__ __launch_bounds__(256) void k_wcvt(const float* __restrict__ Wi,
        const float* __restrict__ Wo, _Float16* __restrict__ Wi16,
        _Float16* __restrict__ Wo16) {
    int idx = blockIdx.x * 256 + threadIdx.x;
    if (idx < 192 * 64) Wi16[idx] = (_Float16)Wi[idx];
    if (idx < 64 * 64) Wo16[idx] = (_Float16)Wo[idx];
}

// ---------------- tiny: XT x-row for t=0 ----------------
__global__ __launch_bounds__(256) void k_initx(const float* __restrict__ src,
        _Float16* __restrict__ XT) {
    int idx = blockIdx.x * 256 + threadIdx.x;   // b*2048+n
    int b = idx >> 11, n = idx & 2047;
    XT[((long)b * CC) * N_ + n] = (_Float16)src[((long)b * T_) * N_ + n];
}

// ---------------- GEMM core (c-major epilogue, for A2 precompute) ----------------
__device__ __forceinline__ f16x8 lds_frag(const _Float16* base, int r, int kb) {
    int byt = r * 128 + ((kb * 2) ^ ((r & 7) << 4));
    return *(const f16x8*)((const char*)base + byt);
}

__global__ __launch_bounds__(256) void k_gemm(const _Float16* __restrict__ Aop,
        const _Float16* __restrict__ BT, _Float16* __restrict__ DT) {
    __shared__ __align__(16) _Float16 As[3 * 4096];
    __shared__ __align__(16) _Float16 Bs[3 * 4096];
    int bm = blockIdx.x, bc = blockIdx.y, tid = threadIdx.x;
    int wid = tid >> 6, lane = tid & 63;
    int row_g = bm * 64, col_g = bc * 64;
    int r0 = (wid & 1) * 32, c0 = (wid >> 1) * 32;
    int lr8 = lane >> 3;
    int lsw = 8 * ((lane & 7) ^ lr8);
    long aoff[2], boff[2];
    int ldo[2];
#pragma unroll
    for (int i = 0; i < 2; ++i) {
        aoff[i] = (long)(row_g + wid * 16 + i * 8 + lr8) * N_ + lsw;
        boff[i] = (long)(col_g + wid * 16 + i * 8 + lr8) * N_ + lsw;
        ldo[i] = (wid * 16 + i * 8) * 64;
    }
    auto stage = [&](int buf, int kt) {
        int k0 = kt * 64;
#pragma unroll
        for (int i = 0; i < 2; ++i)
            __builtin_amdgcn_global_load_lds(
                (const __attribute__((address_space(1))) void*)(Aop + aoff[i] + k0),
                (__attribute__((address_space(3))) void*)&As[buf * 4096 + ldo[i]], 16, 0, 0);
#pragma unroll
        for (int i = 0; i < 2; ++i)
            __builtin_amdgcn_global_load_lds(
                (const __attribute__((address_space(1))) void*)(BT + boff[i] + k0),
                (__attribute__((address_space(3))) void*)&Bs[buf * 4096 + ldo[i]], 16, 0, 0);
    };
    f32x4 acc[2][2] = {};
    const int NT = 32;
    stage(0, 0); stage(1, 1);
    int buf = 0;
    for (int kt = 0; kt < NT; ++kt) {
        if (kt + 2 < NT) { stage((buf + 2) % 3, kt + 2); asm volatile("s_waitcnt vmcnt(8)" ::: "memory"); }
        else if (kt + 1 < NT) { asm volatile("s_waitcnt vmcnt(4)" ::: "memory"); }
        else { asm volatile("s_waitcnt vmcnt(0)" ::: "memory"); }
        __builtin_amdgcn_s_barrier();
        const _Float16* Ab = As + buf * 4096;
        const _Float16* Bb = Bs + buf * 4096;
#pragma unroll
        for (int kk = 0; kk < 64; kk += 32) {
            int kb = kk + (lane >> 4) * 8;
            f16x8 af0 = lds_frag(Ab, r0 + (lane & 15), kb);
            f16x8 af1 = lds_frag(Ab, r0 + 16 + (lane & 15), kb);
            f16x8 bf0 = lds_frag(Bb, c0 + (lane & 15), kb);
            f16x8 bf1 = lds_frag(Bb, c0 + 16 + (lane & 15), kb);
            acc[0][0] = __builtin_amdgcn_mfma_f32_16x16x32_f16(af0, bf0, acc[0][0], 0, 0, 0);
            acc[0][1] = __builtin_amdgcn_mfma_f32_16x16x32_f16(af0, bf1, acc[0][1], 0, 0, 0);
            acc[1][0] = __builtin_amdgcn_mfma_f32_16x16x32_f16(af1, bf0, acc[1][0], 0, 0, 0);
            acc[1][1] = __builtin_amdgcn_mfma_f32_16x16x32_f16(af1, bf1, acc[1][1], 0, 0, 0);
        }
        asm volatile("s_waitcnt lgkmcnt(0)" ::: "memory");
        __builtin_amdgcn_s_barrier();
        buf = (buf + 1) % 3;
    }
#pragma unroll
    for (int rt = 0; rt < 2; ++rt)
#pragma unroll
        for (int ct = 0; ct < 2; ++ct) {
            int cg = col_g + c0 + ct * 16 + (lane & 15);
            int ng = row_g + r0 + rt * 16 + ((lane >> 4) << 2);
            us4 pk;
#pragma unroll
            for (int q = 0; q < 4; ++q) pk[q] = __builtin_bit_cast(unsigned short, (_Float16)(acc[rt][ct][q] * AINV));
            *(us4*)(DT + (long)cg * N_ + ng) = pk;
        }
}

// fused dual dispatch, 128-ROW tile (z: 0=A->Y1, 1=A2->Y2), node-major epilogue
__global__ __launch_bounds__(256) void k_gemm2(const _Float16* __restrict__ A,
        const _Float16* __restrict__ A2, const _Float16* __restrict__ BT,
        _Float16* __restrict__ Y1, _Float16* __restrict__ Y2) {
    __shared__ __align__(16) _Float16 As[2 * 8192];
    __shared__ __align__(16) _Float16 Bs[2 * 4096];
    const _Float16* Aop = blockIdx.z ? A2 : A;
    _Float16* Yn = blockIdx.z ? Y2 : Y1;
    int bm = blockIdx.x, bc = blockIdx.y, tid = threadIdx.x;
    int wid = tid >> 6, lane = tid & 63;
    int row_g = bm * 128, col_g = bc * 64;
    int r0 = (wid & 1) * 64, c0 = (wid >> 1) * 32;
    int lr8 = lane >> 3;
    int lsw = 8 * ((lane & 7) ^ lr8);
    long aoff[4], boff[2];
    int lao[4], lbo[2];
#pragma unroll
    for (int i = 0; i < 4; ++i) {
        aoff[i] = (long)(row_g + wid * 32 + i * 8 + lr8) * N_ + lsw;
        lao[i] = (wid * 32 + i * 8) * 64;
    }
#pragma unroll
    for (int i = 0; i < 2; ++i) {
        boff[i] = (long)(col_g + wid * 16 + i * 8 + lr8) * N_ + lsw;
        lbo[i] = (wid * 16 + i * 8) * 64;
    }
    auto stage = [&](int buf, int kt) {
        int k0 = kt * 64;
#pragma unroll
        for (int i = 0; i < 4; ++i)
            __builtin_amdgcn_global_load_lds(
                (const __attribute__((address_space(1))) void*)(Aop + aoff[i] + k0),
                (__attribute__((address_space(3))) void*)&As[buf * 8192 + lao[i]], 16, 0, 0);
#pragma unroll
        for (int i = 0; i < 2; ++i)
            __builtin_amdgcn_global_load_lds(
                (const __attribute__((address_space(1))) void*)(BT + boff[i] + k0),
                (__attribute__((address_space(3))) void*)&Bs[buf * 4096 + lbo[i]], 16, 0, 0);
    };
    f32x4 acc[4][2] = {};
    const int NT = 32;
    stage(0, 0);
    for (int kt = 0; kt < NT; ++kt) {
        int buf = kt & 1;
        if (kt + 1 < NT) {
            stage(buf ^ 1, kt + 1);
            asm volatile("s_waitcnt vmcnt(6)" ::: "memory");
        } else {
            asm volatile("s_waitcnt vmcnt(0)" ::: "memory");
        }
        __builtin_amdgcn_s_barrier();
        const _Float16* Ab = As + buf * 8192;
        const _Float16* Bb = Bs + buf * 4096;
#pragma unroll
        for (int kk = 0; kk < 64; kk += 32) {
            int kb = kk + (lane >> 4) * 8;
            f16x8 bf0 = lds_frag(Bb, c0 + (lane & 15), kb);
            f16x8 bf1 = lds_frag(Bb, c0 + 16 + (lane & 15), kb);
#pragma unroll
            for (int rt = 0; rt < 4; ++rt) {
                f16x8 af = lds_frag(Ab, r0 + rt * 16 + (lane & 15), kb);
                acc[rt][0] = __builtin_amdgcn_mfma_f32_16x16x32_f16(af, bf0, acc[rt][0], 0, 0, 0);
                acc[rt][1] = __builtin_amdgcn_mfma_f32_16x16x32_f16(af, bf1, acc[rt][1], 0, 0, 0);
            }
        }
        asm volatile("s_waitcnt lgkmcnt(0)" ::: "memory");
        __builtin_amdgcn_s_barrier();
    }
    _Float16* Cs = As;
#pragma unroll
    for (int rt = 0; rt < 4; ++rt)
#pragma unroll
        for (int ct = 0; ct < 2; ++ct) {
            int cl2 = c0 + ct * 16 + (lane & 15);
            int nl = r0 + rt * 16 + ((lane >> 4) << 2);
#pragma unroll
            for (int q = 0; q < 4; ++q)
                Cs[(nl + q) * 72 + cl2] = (_Float16)(acc[rt][ct][q] * AINV);
        }
    __syncthreads();
#pragma unroll
    for (int pass = 0; pass < 4; ++pass) {
        int row = pass * 32 + (tid >> 3);
        int col8 = (tid & 7) * 8;
        *(f16x8*)(Yn + (long)(row_g + row) * NCP + col_g + col8) =
            *(const f16x8*)&Cs[row * 72 + col8];
    }
}

// ---------------- gate apply: split-K over 8 waves (512 thr), LDS reduce ----------------
__global__ __launch_bounds__(512) void k_apply_gate(const float* __restrict__ src,
        const _Float16* __restrict__ h, const _Float16* __restrict__ Y1,
        const _Float16* __restrict__ Y2, const _Float16* __restrict__ GwT,
        const float* __restrict__ Gb, int t,
        _Float16* __restrict__ z, _Float16* __restrict__ r, _Float16* __restrict__ XT,
        const _Float16* __restrict__ zp) {
    int n = blockIdx.x, tid = threadIdx.x, wid = tid >> 6, lane = tid & 63;
    int wq = wid & 3, kseg = wid >> 2;
    __shared__ __align__(16) _Float16 xg[16][256];
    __shared__ float red[4][64][8];
    const _Float16* Wp = GwT + (long)n * (NKC * 128 * 8);
    int cl = lane & 15, q = lane >> 4, k8 = q * 8;
    int o0 = wq * 32 + cl, o1 = o0 + 16;
    int base = kseg * 4;
    f16x8 bfr0[4], bfr1[4];
#pragma unroll
    for (int j = 0; j < 4; ++j) {
        int ks = base + j;
        bool valid = (ks * 4 + q) < NKC;
        const _Float16* p0 = valid ? Wp + (long)((ks * 4 + q) * 128 + o0) * 8 : zp + cl * 8;
        const _Float16* p1 = valid ? Wp + (long)((ks * 4 + q) * 128 + o1) * 8 : zp + cl * 8 + 128;
        bfr0[j] = *(const f16x8*)p0;
        bfr1[j] = *(const f16x8*)p1;
    }
    _Float16* xf = &xg[0][0];
    for (int idx = tid; idx < 16 * 256; idx += 512) xf[idx] = (_Float16)0.f;
    __syncthreads();
    const _Float16* y1p = Y1 + (long)n * NCP;
    const _Float16* y2p = Y2 + (long)n * NCP;
    for (int idx = tid; idx < 16 * KI; idx += 512) {
        int b = idx / KI, kk = idx % KI;
        int k = kk / CC, i = kk % CC;
        int c = b * CC + i;
        float ih = (i == 0) ? src[((long)b * T_ + t) * N_ + n]
                            : (float)h[((long)b * N_ + n) * DH + (i - 1)];
        float val;
        if (k == 0)      val = ih;
        else if (k == 1) val = (float)y1p[c];
        else             val = 2.f * (float)y2p[c] - ih;
        xg[b][kk] = (_Float16)val;
    }
    __syncthreads();
    f32x4 acc0 = {}, acc1 = {};
#pragma unroll
    for (int j = 0; j < 4; ++j) {
        int ks = base + j;
        f16x8 af = *(const f16x8*)&xg[cl][ks * 32 + k8];
        acc0 = __builtin_amdgcn_mfma_f32_16x16x32_f16(af, bfr0[j], acc0, 0, 0, 0);
        acc1 = __builtin_amdgcn_mfma_f32_16x16x32_f16(af, bfr1[j], acc1, 0, 0, 0);
    }
    if (kseg == 1) {
#pragma unroll
        for (int qq = 0; qq < 4; ++qq) {
            red[wq][lane][qq] = acc0[qq];
            red[wq][lane][4 + qq] = acc1[qq];
        }
    }
    __syncthreads();
    if (kseg == 0) {
#pragma unroll
        for (int qq = 0; qq < 4; ++qq) {
            acc0[qq] += red[wq][lane][qq];
            acc1[qq] += red[wq][lane][4 + qq];
        }
#pragma unroll
        for (int tl = 0; tl < 2; ++tl) {
            f32x4 acc = tl ? acc1 : acc0;
            int o = wq * 32 + tl * 16 + cl;
            float bias = Gb[(long)n * 128 + o];
#pragma unroll
            for (int qq = 0; qq < 4; ++qq) {
                int b = q * 4 + qq;
                float sv = 1.f / (1.f + __expf(-(acc[qq] + bias)));
                long base2 = ((long)b * N_ + n) * DH;
                if (o < 64) {
                    z[base2 + o] = (_Float16)sv;
                    XT[(long)(b * CC + 1 + o) * N_ + n] = (_Float16)(sv * (float)h[base2 + o]);
                } else {
                    r[base2 + (o - 64)] = (_Float16)sv;
                }
            }
        }
    }
}

// ---------------- update apply: split-K over 8 waves (512 thr), LDS reduce ----------------
__global__ __launch_bounds__(512) void k_apply_update(const float* __restrict__ src,
        _Float16* __restrict__ h, const _Float16* __restrict__ Y1,
        const _Float16* __restrict__ Y2, const _Float16* __restrict__ UwT,
        const float* __restrict__ Ub, const _Float16* __restrict__ z,
        const _Float16* __restrict__ rb, int t, _Float16* __restrict__ states,
        _Float16* __restrict__ XT, const _Float16* __restrict__ zp) {
    int n = blockIdx.x, tid = threadIdx.x, wid = tid >> 6, lane = tid & 63;
    int wq = wid & 3, kseg = wid >> 2;
    __shared__ __align__(16) _Float16 xg[16][256];
    __shared__ float red[4][64][4];
    const _Float16* Wp = UwT + (long)n * (NKC * 64 * 8);
    int cl = lane & 15, q = lane >> 4, k8 = q * 8;
    int o0 = wq * 16 + cl;
    int base = kseg * 4;
    f16x8 bfr[4];
#pragma unroll
    for (int j = 0; j < 4; ++j) {
        int ks = base + j;
        bool valid = (ks * 4 + q) < NKC;
        const _Float16* p0 = valid ? Wp + (long)((ks * 4 + q) * 64 + o0) * 8 : zp + cl * 8;
        bfr[j] = *(const f16x8*)p0;
    }
    _Float16* xf = &xg[0][0];
    for (int idx = tid; idx < 16 * 256; idx += 512) xf[idx] = (_Float16)0.f;
    __syncthreads();
    const _Float16* y1p = Y1 + (long)n * NCP;
    const _Float16* y2p = Y2 + (long)n * NCP;
    for (int idx = tid; idx < 16 * KI; idx += 512) {
        int b = idx / KI, kk = idx % KI;
        int k = kk / CC, i = kk % CC;
        int c = b * CC + i;
        float ih;
        if (i == 0) ih = src[((long)b * T_ + t) * N_ + n];
        else {
            long base2 = ((long)b * N_ + n) * DH + (i - 1);
            ih = (float)h[base2] * (float)z[base2];
        }
        float val;
        if (k == 0)      val = ih;
        else if (k == 1) val = (float)y1p[c];
        else             val = 2.f * (float)y2p[c] - ih;
        xg[b][kk] = (_Float16)val;
    }
    __syncthreads();
    f32x4 acc0 = {};
#pragma unroll
    for (int j = 0; j < 4; ++j) {
        int ks = base + j;
        f16x8 af = *(const f16x8*)&xg[cl][ks * 32 + k8];
        acc0 = __builtin_amdgcn_mfma_f32_16x16x32_f16(af, bfr[j], acc0, 0, 0, 0);
    }
    if (kseg == 1) {
#pragma unroll
        for (int qq = 0; qq < 4; ++qq) red[wq][lane][qq] = acc0[qq];
    }
    __syncthreads();
    if (kseg == 0) {
#pragma unroll
        for (int qq = 0; qq < 4; ++qq) acc0[qq] += red[wq][lane][qq];
        int o = o0;
        float bias = Ub[(long)n * 64 + o];
#pragma unroll
        for (int qq = 0; qq < 4; ++qq) {
            int b = q * 4 + qq;
            long base2 = ((long)b * N_ + n) * DH + o;
            float hc = tanhf(acc0[qq] + bias);
            float rv = (float)rb[base2], hv = (float)h[base2];
            float hn = rv * hv + (1.f - rv) * hc;
            _Float16 hn16 = (_Float16)hn;
            h[base2] = hn16;
            states[(((long)b * T_ + t) * N_ + n) * DH + o] = hn16;
            XT[(long)(b * CC + 1 + o) * N_ + n] = hn16;
            if (o == 0 && t + 1 < T_)
                XT[(long)(b * CC) * N_ + n] = (_Float16)src[((long)b * T_ + t + 1) * N_ + n];
        }
    }
}

// ---------------- qkv projection (MFMA): KV for all t, Q at t=11 ----------------
__global__ __launch_bounds__(256) void k_qkv(const _Float16* __restrict__ st,
        const _Float16* __restrict__ Wi16, const float* __restrict__ bi,
        _Float16* __restrict__ KV, _Float16* __restrict__ Q) {
    int bt = blockIdx.x;
    int nck = blockIdx.y;
    int b = bt / 12, t = bt % 12;
    int tid = threadIdx.x, wid = tid >> 6, lane = tid & 63;
    __shared__ float pe[64];
    __shared__ __align__(16) _Float16 Xs[128][72];
    if (tid < 64) {
        int e = tid;
        float div = __powf(10000.f, -(float)(e & ~1) / 64.f);
        float ang = (float)t * div;
        pe[e] = (e & 1) ? __cosf(ang) : __sinf(ang);
    }
    __syncthreads();
    const _Float16* srcp = st + ((long)(b * T_ + t) * N_ + nck * 128) * DH;
#pragma unroll
    for (int u = 0; u < 4; ++u) {
        int idx = u * 256 + tid;
        int rr = idx >> 3, e0 = (idx & 7) * 8;
        f16x8 v = *(const f16x8*)(srcp + rr * DH + e0);
        f16x8 ov;
#pragma unroll
        for (int q = 0; q < 8; ++q) ov[q] = (_Float16)((float)v[q] + pe[e0 + q]);
        *(f16x8*)&Xs[rr][e0] = ov;
    }
    __syncthreads();
    int cl = lane & 15, ks8 = (lane >> 4) * 8;
    f16x8 bfrag[3][2];
    float bias[3];
#pragma unroll
    for (int j = 0; j < 3; ++j) {
        int c = (wid * 3 + j) * 16 + cl;
#pragma unroll
        for (int ks = 0; ks < 2; ++ks)
            bfrag[j][ks] = *(const f16x8*)(Wi16 + c * 64 + ks * 32 + ks8);
        bias[j] = bi[c];
    }
    f32x4 acc[8][3] = {};
#pragma unroll
    for (int rt = 0; rt < 8; ++rt) {
#pragma unroll
        for (int ks = 0; ks < 2; ++ks) {
            f16x8 af = *(const f16x8*)&Xs[rt * 16 + cl][ks * 32 + ks8];
#pragma unroll
            for (int j = 0; j < 3; ++j)
                acc[rt][j] = __builtin_amdgcn_mfma_f32_16x16x32_f16(af, bfrag[j][ks], acc[rt][j], 0, 0, 0);
        }
    }
    int rowq = (lane >> 4) * 4;
#pragma unroll
    for (int rt = 0; rt < 8; ++rt)
#pragma unroll
        for (int j = 0; j < 3; ++j) {
            int c = (wid * 3 + j) * 16 + cl;
#pragma unroll
            for (int q = 0; q < 4; ++q) {
                int n = nck * 128 + rt * 16 + rowq + q;
                float val = acc[rt][j][q] + bias[j];
                if (c >= 64)
                    KV[(((long)b * N_ + n) * T_ + t) * 128 + (c - 64)] = (_Float16)val;
                else if (t == 11)
                    Q[((long)b * N_ + n) * 64 + c] = (_Float16)val;
            }
        }
}

// ---------------- attention + out-proj: 16 pairs/block, 16 threads/pair ----------------
__global__ __launch_bounds__(256) void k_attn2(const _Float16* __restrict__ KV,
        const _Float16* __restrict__ Q, const _Float16* __restrict__ Wo16,
        const float* __restrict__ bo, float* __restrict__ o1) {
    __shared__ _Float16 kvs[16 * 1544];
    __shared__ float qs[16][64];
    __shared__ float Wos[64][64];
    __shared__ float outb[16][64];
    __shared__ float bos[64];
    int tid = threadIdx.x;
    long pair0 = (long)blockIdx.x * 16;
#pragma unroll
    for (int u = 0; u < 12; ++u) {
        int idx = u * 256 + tid;
        int p = idx / 192, off8 = (idx % 192) * 8;
        *(f16x8*)&kvs[p * 1544 + off8] = *(const f16x8*)(KV + (pair0 + p) * 1536 + off8);
    }
    if (tid < 64) bos[tid] = bo[tid];
    for (int idx = tid; idx < 1024; idx += 256) {
        int p = idx >> 6, j = idx & 63;
        qs[p][j] = (float)Q[(pair0 + p) * 64 + j];
    }
    for (int idx = tid; idx < 4096; idx += 256) {
        int c = idx >> 6, j = idx & 63;
        Wos[c][j] = (float)Wo16[j * 64 + c];
    }
    __syncthreads();
    int p = tid >> 4, i = tid & 15;
    int h = i >> 2, sg = i & 3;
    const _Float16* kvp = &kvs[p * 1544];
    float att3[3], mx = -1e30f;
#pragma unroll
    for (int j = 0; j < 3; ++j) {
        int s = sg + 4 * j;
        float sc = 0.f;
#pragma unroll
        for (int d = 0; d < 16; ++d)
            sc = fmaf(qs[p][h * 16 + d], (float)kvp[s * 128 + h * 16 + d], sc);
        att3[j] = sc * 0.25f;
        mx = fmaxf(mx, att3[j]);
    }
    mx = fmaxf(mx, __shfl_xor(mx, 1));
    mx = fmaxf(mx, __shfl_xor(mx, 2));
    float se = 0.f;
#pragma unroll
    for (int j = 0; j < 3; ++j) { att3[j] = __expf(att3[j] - mx); se += att3[j]; }
    se += __shfl_xor(se, 1);
    se += __shfl_xor(se, 2);
    float inv = 1.f / se;
#pragma unroll
    for (int j = 0; j < 3; ++j) att3[j] *= inv;
    int c0 = i * 4;
    float out4[4] = {0.f, 0.f, 0.f, 0.f};
#pragma unroll
    for (int m = 0; m < 4; ++m) {
        float a0 = __shfl_xor(att3[0], m);
        float a1 = __shfl_xor(att3[1], m);
        float a2 = __shfl_xor(att3[2], m);
        int sb = sg ^ m;
        float aj[3] = {a0, a1, a2};
#pragma unroll
        for (int j = 0; j < 3; ++j) {
            int s = sb + 4 * j;
            f16x4 vv = *(const f16x4*)&kvp[s * 128 + 64 + c0];
#pragma unroll
            for (int q = 0; q < 4; ++q) out4[q] = fmaf(aj[j], (float)vv[q], out4[q]);
        }
    }
    *(float4*)&outb[p][c0] = *(float4*)out4;
    __syncthreads();
    float res[4];
#pragma unroll
    for (int q = 0; q < 4; ++q) res[q] = bos[c0 + q];
    for (int c = 0; c < 64; ++c) {
        float oc = outb[p][c];
        float4 wv = *(const float4*)&Wos[c][c0];
        res[0] = fmaf(oc, wv.x, res[0]);
        res[1] = fmaf(oc, wv.y, res[1]);
        res[2] = fmaf(oc, wv.z, res[2]);
        res[3] = fmaf(oc, wv.w, res[3]);
    }
    *(float4*)&o1[(pair0 + p) * 64 + c0] = make_float4(res[0], res[1], res[2], res[3]);
}

// ---------------- output head ----------------
__global__ __launch_bounds__(256) void k_final(const float* __restrict__ o1,
        const _Float16* __restrict__ hT, const float* __restrict__ cw,
        const float* __restrict__ convw, const float* __restrict__ convb,
        float* __restrict__ out) {
    __shared__ float Ws[12 * 3 * 64];
    __shared__ float cbs[12];
    int tid = threadIdx.x;
    for (int idx = tid; idx < 12 * 3 * 64; idx += 256) Ws[idx] = convw[idx];
    if (tid < 12) cbs[tid] = convb[tid];
    __syncthreads();
    float c0 = cw[0], c1 = cw[1], c2 = cw[2];
    int g = tid >> 6, j = tid & 63;
    int bn = blockIdx.x * 4 + g;
    int b = bn >> 11, n = bn & 2047;
    float x1 = o1[(long)bn * DH + j];
    float x3 = (float)hT[(long)bn * DH + j];
    float myout = 0.f;
#pragma unroll
    for (int oc = 0; oc < 12; ++oc) {
        float p = x1 * c0 * Ws[(oc * 3 + 0) * 64 + j]
                + x3 * (c1 * Ws[(oc * 3 + 1) * 64 + j] + c2 * Ws[(oc * 3 + 2) * 64 + j]);
        p += __shfl_xor(p, 1); p += __shfl_xor(p, 2); p += __shfl_xor(p, 4);
        p += __shfl_xor(p, 8); p += __shfl_xor(p, 16); p += __shfl_xor(p, 32);
        if (j == oc) myout = p + cbs[oc];
    }
    if (j < 12) out[((long)b * 12 + j) * N_ + n] = myout;
}

extern "C" void kernel_launch(void* const* d_in, const int* in_sizes, int n_in,
                              void* d_out, int out_size, void* d_ws, size_t ws_size,
                              hipStream_t stream) {
    const float* src    = (const float*)d_in[0];
    const float* emb    = (const float*)d_in[2];
    const float* gate_w = (const float*)d_in[3];
    const float* gate_b = (const float*)d_in[4];
    const float* upd_w  = (const float*)d_in[5];
    const float* upd_b  = (const float*)d_in[6];
    const float* a_in_w = (const float*)d_in[7];
    const float* a_in_b = (const float*)d_in[8];
    const float* a_out_w= (const float*)d_in[9];
    const float* a_out_b= (const float*)d_in[10];
    const float* chan_w = (const float*)d_in[11];
    const float* conv_w = (const float*)d_in[12];
    const float* conv_b = (const float*)d_in[13];
    float* out = (float*)d_out;

    char* ws = (char*)d_ws;
    size_t off = 0;
    auto alloc = [&](size_t bytes) { char* p = ws + off; off += (bytes + 255) & ~size_t(255); return p; };
    _Float16* A    = (_Float16*)alloc((size_t)N_ * N_ * 2);
    _Float16* A2   = (_Float16*)alloc((size_t)N_ * N_ * 2);
    _Float16* GwT  = (_Float16*)alloc((size_t)N_ * NKC * 128 * 8 * 2);   // 104.9 MB
    float*  Gb     = (float*) alloc((size_t)N_ * 128 * 4);
    _Float16* UwT  = (_Float16*)alloc((size_t)N_ * NKC * 64 * 8 * 2);    // 52.4 MB
    float*  Ub     = (float*) alloc((size_t)N_ * 64 * 4);
    _Float16* XT   = (_Float16*)alloc((size_t)NCP * N_ * 2);
    _Float16* Y1   = (_Float16*)alloc((size_t)N_ * NCP * 2);   // node-major [n][c]
    _Float16* Y2   = (_Float16*)alloc((size_t)N_ * NCP * 2);   // node-major [n][c]
    _Float16* h    = (_Float16*)alloc((size_t)B_ * N_ * DH * 2);
    _Float16* zbuf = (_Float16*)alloc((size_t)B_ * N_ * DH * 2);
    _Float16* rbuf = (_Float16*)alloc((size_t)B_ * N_ * DH * 2);
    _Float16* stt  = (_Float16*)alloc((size_t)B_ * T_ * N_ * DH * 2);
    _Float16* Wi16 = (_Float16*)alloc(192 * 64 * 2);
    _Float16* Wo16 = (_Float16*)alloc(64 * 64 * 2);
    _Float16* zp   = (_Float16*)alloc(512);
    if (off > ws_size) return;   // ~252 MB total

    // transient/dead-region aliases
    _Float16* AT = stt;                            // 8.4 MB scratch (stt unwritten at setup)
    _Float16* KV = GwT;                            // 100.7 MB into GwT's 104.9 MB
    _Float16* Qb = UwT;                            // 4.2 MB at UwT start
    float*    o1 = (float*)((char*)UwT + (8u << 20)); // 8.4 MB at UwT+8MB

    hipMemsetAsync(h, 0, (size_t)B_ * N_ * DH * 2, stream);
    hipMemsetAsync(XT, 0, (size_t)NCP * N_ * 2, stream);
    hipMemsetAsync(zp, 0, 512, stream);
    k_compA<<<N_, 256, 0, stream>>>(emb, A);
    dim3 tgrid(32, 32);
    k_transp<<<tgrid, 256, 0, stream>>>(A, AT);
    k_gemm<<<tgrid, 256, 0, stream>>>(AT, A, A2);   // A2 = (1024*A^2), Aop=AT BT=A
    k_build<<<1616, 256, 0, stream>>>(emb, gate_w, gate_b, upd_w, upd_b, GwT, Gb, UwT, Ub);
    k_wcvt<<<48, 256, 0, stream>>>(a_in_w, a_out_w, Wi16, Wo16);
    k_initx<<<128, 256, 0, stream>>>(src, XT);

    dim3 ggrid(16, 17, 2);
    for (int t = 0; t < T_; ++t) {
        k_gemm2<<<ggrid, 256, 0, stream>>>(A, A2, XT, Y1, Y2);
        k_apply_gate<<<N_, 512, 0, stream>>>(src, h, Y1, Y2, GwT, Gb, t, zbuf, rbuf, XT, zp);
        k_gemm2<<<ggrid, 256, 0, stream>>>(A, A2, XT, Y1, Y2);
        k_apply_update<<<N_, 512, 0, stream>>>(src, h, Y1, Y2, UwT, Ub, zbuf, rbuf, t, stt, XT, zp);
    }
    dim3 qgrid(192, 16);
    k_qkv<<<qgrid, 256, 0, stream>>>(stt, Wi16, a_in_b, KV, Qb);
    k_attn2<<<2048, 256, 0, stream>>>(KV, Qb, Wo16, a_out_b, o1);
    k_final<<<8192, 256, 0, stream>>>(o1, h, chan_w, conv_w, conv_b, out);
}